// Round 4
// baseline (1021.548 us; speedup 1.0000x reference)
//
#include <hip/hip_runtime.h>
#include <hip/hip_bf16.h>

#define NN 20000
#define NE 320000
#define NT 2048            // filter LUT entries over len in [0, 1.7321]

typedef _Float16 h2f __attribute__((ext_vector_type(2)));

__device__ __forceinline__ h2f u2h(unsigned int u){
  union { unsigned int u; h2f h; } v; v.u = u; return v.h;
}
__device__ __forceinline__ unsigned int h2u(h2f h){
  union { h2f h; unsigned int u; } v; v.h = h; return v.u;
}
__device__ __forceinline__ unsigned int pack2(float a, float b){
  h2f h; h.x = (_Float16)a; h.y = (_Float16)b;
  union { h2f h; unsigned int u; } v; v.h = h; return v.u;
}
__device__ __forceinline__ unsigned short f16b(float a){
  union { _Float16 h; unsigned short u; } v; v.h = (_Float16)a; return v.u;
}
__device__ __forceinline__ float dot2(unsigned int w, h2f x, float acc){
#if __has_builtin(__builtin_amdgcn_fdot2)
  return __builtin_amdgcn_fdot2(u2h(w), x, acc, false);
#else
  h2f c = u2h(w);
  return acc + (float)(c.x) * (float)(x.x) + (float)(c.y) * (float)(x.y);
#endif
}
// packed f16 lerp: a + t*(b-a)
__device__ __forceinline__ unsigned int lerp2(unsigned int a, unsigned int b, h2f t){
  h2f ha = u2h(a), hb = u2h(b);
  return h2u(ha + t * (hb - ha));
}

// jax.nn.gelu default (approximate=True): 0.5x(1+tanh(t)) == x*sigmoid(2t)
__device__ __forceinline__ float geluf(float x){
  float t = 0.7978845608028654f * x * (1.0f + 0.044715f * x * x);
  return x / (1.0f + __expf(-2.0f * t));
}

// ---------------- weight transpose/copy (fp32 -> fp32 in ws) ----------------
struct TEnt { const float* src; float* dst; int R; int C; int trans; };
struct TTab { TEnt e[16]; };

__global__ void convw(TTab t){
  TEnt en = t.e[blockIdx.x];
  int n = en.R * en.C;
  for (int i = threadIdx.x; i < n; i += blockDim.x){
    float v = en.src[i];
    if (en.trans){
      int r = i / en.C, c = i - r * en.C;
      en.dst[c * en.R + r] = v;          // dst[C][R]
    } else {
      en.dst[i] = v;
    }
  }
}

// ---------------- pack fp32 [R][C] -> f16-pair uints [C][R/2] ---------------
struct PEnt { const float* src; unsigned int* dst; int R; int C; };
struct PTab { PEnt e[10]; };

__global__ void packw(PTab t){
  PEnt en = t.e[blockIdx.x];
  int half = en.R >> 1;
  int n = en.C * half;
  for (int i = threadIdx.x; i < n; i += blockDim.x){
    int c = i / half, rp = i - c * half;
    float a = en.src[(2*rp)     * en.C + c];
    float b = en.src[(2*rp + 1) * en.C + c];
    en.dst[i] = pack2(a, b);
  }
}

// ---------------- filter LUT build ------------------------------------------
__device__ __forceinline__ void lut_basis(int ent, float* b){
  float len = fmaxf((float)ent * (1.7321f / (float)(NT - 1)), 1e-6f);
  float sc = 3.1622776601683795f / fmaxf(len, 1e-6f);  // sqrt(2/MAXR)*sqrt(B)/r
#pragma unroll
  for (int k = 0; k < 10; k++)
    b[k] = sinf((float)(k + 1) * 1.5707963267948966f * len) * sc;
}

__global__ __launch_bounds__(384) void build_lut(
    const float* __restrict__ fABw1 /*[L][2][10][64]*/,
    const float* __restrict__ fABw2 /*[L][2][64][96]*/,
    const float* __restrict__ fCw1  /*[L][10][64]*/,
    const float* __restrict__ fCw2  /*[L][64][192]*/,
    unsigned short* __restrict__ lutH)
{
  int ent = blockIdx.x & (NT - 1);
  int layer = blockIdx.x >> 11;       // NT = 2048
  float b[10];
  lut_basis(ent, b);
  __shared__ float h[192];
  int t = threadIdx.x;
  if (t < 192){
    int f = t >> 6, l = t & 63;       // f: 0=A, 1=B, 2=C
    const float* w1 = (f < 2) ? (fABw1 + (layer*2 + f) * 640)
                              : (fCw1 + layer * 640);
    float a = 0.f;
#pragma unroll
    for (int k = 0; k < 10; k++) a += b[k] * w1[k*64 + l];
    h[t] = geluf(a);
  }
  __syncthreads();
  float a = 0.f;
  if (t < 192){
    int f = t / 96, j = t - 96 * f;
    const float* w2 = fABw2 + (layer*2 + f) * 6144;
    for (int l = 0; l < 64; l++) a += h[f*64 + l] * w2[l*96 + j];
  } else {
    int j = t - 192;
    const float* w2 = fCw2 + layer * 12288;
    for (int l = 0; l < 64; l++) a += h[128 + l] * w2[l*192 + j];
  }
  lutH[((long)(layer * NT + ent)) * 384 + t] = f16b(a);
}

// init LUT row: f16 halves [W0 32 | W1 32] = 64 h = 128B
__global__ __launch_bounds__(64) void build_lut01(
    const float* __restrict__ f01w1 /*[2][10][64]*/,
    const float* __restrict__ f01w2 /*[2][64][32]*/,
    unsigned short* __restrict__ lutH)
{
  int ent = blockIdx.x, t = threadIdx.x;
  int p = t >> 5, jj = t & 31;
  float b[10];
  lut_basis(ent, b);
  const float* w1 = f01w1 + p * 640;
  const float* w2 = f01w2 + p * 2048;
  float W = 0.f;
  for (int l = 0; l < 64; l++){
    float a = 0.f;
#pragma unroll
    for (int k = 0; k < 10; k++) a += b[k] * w1[k*64 + l];
    W += geluf(a) * w2[l*32 + jj];
  }
  lutH[(long)ent * 64 + t] = f16b(W);
}

// ---------------- CSR build (dst-sorted edge order + src-slot map) ----------
__global__ void count_k(const int* __restrict__ esrc, const int* __restrict__ edst,
                        int* __restrict__ cntd, int* __restrict__ cnts){
  int e = blockIdx.x * 256 + threadIdx.x;
  if (e >= NE) return;
  atomicAdd(cntd + edst[e], 1);
  atomicAdd(cnts + esrc[e], 1);
}

__global__ __launch_bounds__(1024) void prefix_k(const int* __restrict__ cnt,
                                                 int* __restrict__ off, int* __restrict__ cur,
                                                 int total){
  __shared__ int part[1024];
  int t = threadIdx.x;
  int base = t * 20;
  int s = 0;
  for (int i = 0; i < 20; i++){ int idx = base + i; if (idx < NN) s += cnt[idx]; }
  part[t] = s; __syncthreads();
  for (int d = 1; d < 1024; d <<= 1){
    int v = (t >= d) ? part[t - d] : 0;
    __syncthreads();
    part[t] += v;
    __syncthreads();
  }
  int run = (t == 0) ? 0 : part[t - 1];
  for (int i = 0; i < 20; i++){
    int idx = base + i;
    if (idx < NN){ off[idx] = run; cur[idx] = run; run += cnt[idx]; }
  }
  if (t == 0) off[NN] = total;
}

// p = dst-sorted slot of edge e; q = src-sorted slot; qpos[p] = q (bijection)
__global__ void fill_comb(const int* __restrict__ esrc, const int* __restrict__ edst,
                          int* __restrict__ curd, int* __restrict__ curs,
                          int* __restrict__ srcS, int* __restrict__ dstS,
                          int* __restrict__ qpos){
  int e = blockIdx.x * 256 + threadIdx.x;
  if (e >= NE) return;
  int s = esrc[e], d = edst[e];
  int p = atomicAdd(curd + d, 1);
  srcS[p] = s; dstS[p] = d;
  int q = atomicAdd(curs + s, 1);
  qpos[p] = q;
}

// ---------------- node init: xn[:,0:32] = mlp2(embed[z]), zero rest ---------
__global__ __launch_bounds__(256) void node_init(
    const int* __restrict__ az, const float* __restrict__ embedF,
    const float* __restrict__ w1T /*[32][8]*/, const float* __restrict__ w2T /*[32][32]*/,
    float* __restrict__ xn)
{
  int n = blockIdx.x * 256 + threadIdx.x;
  if (n >= NN) return;
  int z = az[n];
  float ee[8];
#pragma unroll
  for (int k = 0; k < 8; k++) ee[k] = embedF[z * 8 + k];
  float hid[32];
#pragma unroll
  for (int l = 0; l < 32; l++){
    float a = 0.f;
#pragma unroll
    for (int k = 0; k < 8; k++) a += ee[k] * w1T[l * 8 + k];
    hid[l] = geluf(a);
  }
  float* row = xn + (long)n * 96;
#pragma unroll
  for (int j = 0; j < 32; j++){
    float a = 0.f;
#pragma unroll
    for (int l = 0; l < 32; l++) a += hid[l] * w2T[j * 32 + l];
    row[j] = a;
  }
#pragma unroll
  for (int j = 32; j < 96; j++) row[j] = 0.f;
}

// ---------------- edge init: p-row (dst side) + q-row (src side) ------------
// p-row[0:32]=+div/16, [32:64]=ave/16 ; q-row[0:32]=-div/16, [32:64]=ave/16
__global__ __launch_bounds__(256) void edge_init(
    const float* __restrict__ pos, const int* __restrict__ srcS,
    const int* __restrict__ dstS, const int* __restrict__ qpos,
    float* __restrict__ els,
    unsigned short* __restrict__ pbuf0, unsigned short* __restrict__ qbuf0,
    const float* __restrict__ w1T /*dl1w1T [32][4]*/, const float* __restrict__ w2T /*[32][32]*/,
    const unsigned int* __restrict__ lut01)
{
  int p = blockIdx.x * 256 + threadIdx.x;
  if (p >= NE) return;
  int s = srcS[p], d = dstS[p];
  float x = pos[s*3+0] - pos[d*3+0];
  float y = pos[s*3+1] - pos[d*3+1];
  float z = pos[s*3+2] - pos[d*3+2];
  float L = sqrtf(x*x + y*y + z*z + 1e-12f);
  float iv = 1.0f / fmaxf(L, 1e-6f);
  els[p] = L;

  float u = L - 2.0f;   // 2*(len/MAXR - 1), MAXR=2
  float cut = 0.5f * (1.0f - cosf(3.14159265358979323f * u));
  cut = (u > 0.0f) ? 0.0f : cut;
  cut = (u < -1.0f) ? 1.0f : cut;
  float xe0 = cut, cc = cut * 1.7320508075688772f * iv;
  float xe1 = cc*x, xe2 = cc*y, xe3 = cc*z;
  float hid[32];
#pragma unroll
  for (int l = 0; l < 32; l++){
    float a = xe0*w1T[l*4+0] + xe1*w1T[l*4+1] + xe2*w1T[l*4+2] + xe3*w1T[l*4+3];
    hid[l] = geluf(a);
  }
  float xeh[32];
#pragma unroll
  for (int j = 0; j < 32; j++){
    float a = 0.f;
#pragma unroll
    for (int l = 0; l < 32; l++) a += hid[l] * w2T[j*32 + l];
    xeh[j] = a;
  }
  float tt = fminf(L * ((float)(NT-1) / 1.7321f), (float)(NT-1) - 0.001f);
  int i0 = (int)tt; float tfv = tt - (float)i0;
  h2f tf2; tf2.x = (_Float16)tfv; tf2.y = tf2.x;
  h2f h05; h05.x = (_Float16)0.5f; h05.y = h05.x;
  const unsigned int* rA = lut01 + i0 * 32;
  const unsigned int* rB = rA + 32;

  unsigned int xp[16];
#pragma unroll
  for (int jp = 0; jp < 16; jp++)
    xp[jp] = pack2(xeh[2*jp] * 0.0625f, xeh[2*jp+1] * 0.0625f);

  unsigned int du[16], au[16];
#pragma unroll
  for (int q = 0; q < 4; q++){
    uint4 a = ((const uint4*)rA)[q];
    uint4 b = ((const uint4*)rB)[q];
    du[4*q+0] = h2u(u2h(lerp2(a.x, b.x, tf2)) * u2h(xp[4*q+0]));
    du[4*q+1] = h2u(u2h(lerp2(a.y, b.y, tf2)) * u2h(xp[4*q+1]));
    du[4*q+2] = h2u(u2h(lerp2(a.z, b.z, tf2)) * u2h(xp[4*q+2]));
    du[4*q+3] = h2u(u2h(lerp2(a.w, b.w, tf2)) * u2h(xp[4*q+3]));
  }
#pragma unroll
  for (int q = 0; q < 4; q++){
    uint4 a = ((const uint4*)(rA + 16))[q];
    uint4 b = ((const uint4*)(rB + 16))[q];
    au[4*q+0] = h2u(u2h(lerp2(a.x, b.x, tf2)) * u2h(xp[4*q+0]) * h05);
    au[4*q+1] = h2u(u2h(lerp2(a.y, b.y, tf2)) * u2h(xp[4*q+1]) * h05);
    au[4*q+2] = h2u(u2h(lerp2(a.z, b.z, tf2)) * u2h(xp[4*q+2]) * h05);
    au[4*q+3] = h2u(u2h(lerp2(a.w, b.w, tf2)) * u2h(xp[4*q+3]) * h05);
  }
  unsigned short* prow = pbuf0 + (long)p * 64;
  unsigned short* qrow = qbuf0 + (long)qpos[p] * 64;
#pragma unroll
  for (int q = 0; q < 4; q++){
    ((uint4*)prow)[q]     = ((uint4*)du)[q];
    ((uint4*)(prow+32))[q] = ((uint4*)au)[q];
  }
  unsigned int nd[16];
#pragma unroll
  for (int i = 0; i < 16; i++) nd[i] = du[i] ^ 0x80008000u;  // negate packed f16
#pragma unroll
  for (int q = 0; q < 4; q++){
    ((uint4*)qrow)[q]      = ((uint4*)nd)[q];
    ((uint4*)(qrow+32))[q] = ((uint4*)au)[q];
  }
}

// 4 nodes per 256-thread block; both roles stream contiguous sorted rows
__global__ __launch_bounds__(256) void gather_init(
    const int* __restrict__ doff, const int* __restrict__ soff,
    const unsigned short* __restrict__ pbuf0, const unsigned short* __restrict__ qbuf0,
    float* __restrict__ xn)
{
  int n = blockIdx.x * 4 + (threadIdx.x >> 6);
  int c = threadIdx.x & 63;
  if (n >= NN) return;
  const _Float16* ph = (const _Float16*)pbuf0;
  const _Float16* qh = (const _Float16*)qbuf0;
  float acc = 0.f;
  int d1 = doff[n+1];
  for (int p = doff[n]; p < d1; p++) acc += (float)ph[(long)p * 64 + c];
  int s1 = soff[n+1];
  for (int q = soff[n]; q < s1; q++) acc += (float)qh[(long)q * 64 + c];
  xn[(long)n * 96 + 32 + c] += 16.f * acc;   // undo 1/16 msg scale
}

// ---------------- pack xn f32 -> xnh f16 pairs ------------------------------
__global__ void pack_xnh(const float* __restrict__ xn, unsigned int* __restrict__ xnh){
  int i = blockIdx.x * 256 + threadIdx.x;
  if (i < NN * 48) xnh[i] = pack2(xn[2*i], xn[2*i+1]);
}

// helper: build packed g fragments for one edge, one jc chunk
__device__ __forceinline__ void mkg(uint4 aA, uint4 bA, uint4 aB, uint4 bB,
                                    uint4 xsu, uint4 xdu, h2f tf,
                                    h2f* gpA, h2f* gpB, h2f c32h, h2f c64h){
  unsigned int wA0=lerp2(aA.x,bA.x,tf), wA1=lerp2(aA.y,bA.y,tf),
               wA2=lerp2(aA.z,bA.z,tf), wA3=lerp2(aA.w,bA.w,tf);
  unsigned int wB0=lerp2(aB.x,bB.x,tf), wB1=lerp2(aB.y,bB.y,tf),
               wB2=lerp2(aB.z,bB.z,tf), wB3=lerp2(aB.w,bB.w,tf);
  h2f s0=u2h(xsu.x), s1=u2h(xsu.y), s2=u2h(xsu.z), s3=u2h(xsu.w);
  h2f d0=u2h(xdu.x), d1=u2h(xdu.y), d2=u2h(xdu.z), d3=u2h(xdu.w);
  gpA[0]=u2h(wA0)*((d0-s0)*c32h); gpB[0]=u2h(wB0)*((d0+s0)*c64h);
  gpA[1]=u2h(wA1)*((d1-s1)*c32h); gpB[1]=u2h(wB1)*((d1+s1)*c64h);
  gpA[2]=u2h(wA2)*((d2-s2)*c32h); gpB[2]=u2h(wB2)*((d2+s2)*c64h);
  gpA[3]=u2h(wA3)*((d3-s3)*c32h); gpB[3]=u2h(wB3)*((d3+s3)*c64h);
}

// ---------------- conv layer: 2 edges/thread, LDS weights amortized ---------
// p-row (dst side, 96 h) -> pbuf[p]; q-row (src side, 96 h) -> qbuf[qpos[p]]
// stored value = true/64 (undone in gather_layer)
// pk layout per layer (uints): dw1T[32][96] @0, dw2[192][16] @3072 (6144 total)
// lut row per entry (uints):   WaPairs[48] | WbPairs[48] | WcPairs[96] (192)
__global__ __launch_bounds__(256, 4) void layer_k(
    const int* __restrict__ srcS, const int* __restrict__ dstS,
    const int* __restrict__ qpos, const float* __restrict__ els,
    const unsigned int* __restrict__ xnh,
    unsigned short* __restrict__ pbuf, unsigned short* __restrict__ qbuf,
    const unsigned int* __restrict__ lut, const unsigned int* __restrict__ pk)
{
  __shared__ uint4 lw4[1536];          // 24 KB: dw1T + dw2
  unsigned int* lw = (unsigned int*)lw4;
  int t = threadIdx.x;
  {
    const uint4* s4 = (const uint4*)pk;
    for (int i = t; i < 1536; i += 256) lw4[i] = s4[i];
  }
  __syncthreads();
  int p0 = blockIdx.x * 512 + 2 * t;   // edges p0, p0+1 (NE even)
  if (p0 >= NE) return;

  const unsigned int* dw1T = lw;          // [32][96]
  const unsigned int* dw2  = lw + 3072;   // [192][16]

  int s0 = srcS[p0],   d0 = dstS[p0],   qq0 = qpos[p0];
  int s1 = srcS[p0+1], d1 = dstS[p0+1], qq1 = qpos[p0+1];
  float L0 = els[p0], L1 = els[p0+1];
  float t0 = fminf(L0 * ((float)(NT-1) / 1.7321f), (float)(NT-1) - 0.001f);
  float t1 = fminf(L1 * ((float)(NT-1) / 1.7321f), (float)(NT-1) - 0.001f);
  int i00 = (int)t0; float tf0v = t0 - (float)i00;
  int i01 = (int)t1; float tf1v = t1 - (float)i01;
  h2f tf0; tf0.x = (_Float16)tf0v; tf0.y = tf0.x;
  h2f tf1; tf1.x = (_Float16)tf1v; tf1.y = tf1.x;
  const unsigned int* rA0 = lut + (long)i00 * 192; const unsigned int* rB0 = rA0 + 192;
  const unsigned int* rA1 = lut + (long)i01 * 192; const unsigned int* rB1 = rA1 + 192;
  const unsigned int* xs0 = xnh + s0 * 48; const unsigned int* xd0 = xnh + d0 * 48;
  const unsigned int* xs1 = xnh + s1 * 48; const unsigned int* xd1 = xnh + d1 * 48;
  h2f c32h; c32h.x = (_Float16)0.03125f;  c32h.y = c32h.x;
  h2f c64h; c64h.x = (_Float16)0.015625f; c64h.y = c64h.x;

  float hd0[32], hd1[32];
#pragma unroll
  for (int l = 0; l < 32; l++){ hd0[l] = 0.f; hd1[l] = 0.f; }

  // ---- merged A(grad)/B(ave) pass; weights (LDS) shared by both edges ------
  for (int jc = 0; jc < 96; jc += 8){
    int jh = jc >> 1;
    uint4 xsu0 = *(const uint4*)(xs0 + jh);
    uint4 xdu0 = *(const uint4*)(xd0 + jh);
    uint4 xsu1 = *(const uint4*)(xs1 + jh);
    uint4 xdu1 = *(const uint4*)(xd1 + jh);
    uint4 aA0 = *(const uint4*)(rA0 + jh);
    uint4 bA0 = *(const uint4*)(rB0 + jh);
    uint4 aB0 = *(const uint4*)(rA0 + 48 + jh);
    uint4 bB0 = *(const uint4*)(rB0 + 48 + jh);
    uint4 aA1 = *(const uint4*)(rA1 + jh);
    uint4 bA1 = *(const uint4*)(rB1 + jh);
    uint4 aB1 = *(const uint4*)(rA1 + 48 + jh);
    uint4 bB1 = *(const uint4*)(rB1 + 48 + jh);
    h2f gpA0[4], gpB0[4], gpA1[4], gpB1[4];
    mkg(aA0, bA0, aB0, bB0, xsu0, xdu0, tf0, gpA0, gpB0, c32h, c64h);
    mkg(aA1, bA1, aB1, bB1, xsu1, xdu1, tf1, gpA1, gpB1, c32h, c64h);
#pragma unroll
    for (int l = 0; l < 32; l++){
      uint4 w1 = *(const uint4*)(dw1T + l*96 + jh);
      uint4 w2 = *(const uint4*)(dw1T + l*96 + 48 + jh);
      float a0 = hd0[l], a1 = hd1[l];
      a0 = dot2(w1.x, gpA0[0], a0); a0 = dot2(w1.y, gpA0[1], a0);
      a0 = dot2(w1.z, gpA0[2], a0); a0 = dot2(w1.w, gpA0[3], a0);
      a0 = dot2(w2.x, gpB0[0], a0); a0 = dot2(w2.y, gpB0[1], a0);
      a0 = dot2(w2.z, gpB0[2], a0); a0 = dot2(w2.w, gpB0[3], a0);
      a1 = dot2(w1.x, gpA1[0], a1); a1 = dot2(w1.y, gpA1[1], a1);
      a1 = dot2(w1.z, gpA1[2], a1); a1 = dot2(w1.w, gpA1[3], a1);
      a1 = dot2(w2.x, gpB1[0], a1); a1 = dot2(w2.y, gpB1[1], a1);
      a1 = dot2(w2.z, gpB1[2], a1); a1 = dot2(w2.w, gpB1[3], a1);
      hd0[l] = a0; hd1[l] = a1;
    }
  }

  // ---- hd gelu (undo 1/32), pack at 1/64 for output dots ----
  h2f hdp0[16], hdp1[16];
#pragma unroll
  for (int lp = 0; lp < 16; lp++){
    h2f r0, r1;
    r0.x = (_Float16)(geluf(32.f*hd0[2*lp])   * 0.015625f);
    r0.y = (_Float16)(geluf(32.f*hd0[2*lp+1]) * 0.015625f);
    r1.x = (_Float16)(geluf(32.f*hd1[2*lp])   * 0.015625f);
    r1.y = (_Float16)(geluf(32.f*hd1[2*lp+1]) * 0.015625f);
    hdp0[lp] = r0; hdp1[lp] = r1;
  }

  // ---- output: dv = Wc[j]*dd1, av = 0.5*Wc[96+j]*dd2; rows at true/64 ------
  unsigned int* prow0 = (unsigned int*)(pbuf + (long)p0 * 96);
  unsigned int* prow1 = (unsigned int*)(pbuf + (long)(p0+1) * 96);
  unsigned int* qrow0 = (unsigned int*)(qbuf + (long)qq0 * 96);
  unsigned int* qrow1 = (unsigned int*)(qbuf + (long)qq1 * 96);
  for (int c0 = 0; c0 < 96; c0 += 32){
#pragma unroll
    for (int q4 = 0; q4 < 4; q4++){
      int cb = 96 + (c0 >> 1) + 4*q4;
      uint4 a1_0 = *(const uint4*)(rA0 + cb);
      uint4 b1_0 = *(const uint4*)(rB0 + cb);
      uint4 a2_0 = *(const uint4*)(rA0 + cb + 48);
      uint4 b2_0 = *(const uint4*)(rB0 + cb + 48);
      uint4 a1_1 = *(const uint4*)(rA1 + cb);
      uint4 b1_1 = *(const uint4*)(rB1 + cb);
      uint4 a2_1 = *(const uint4*)(rA1 + cb + 48);
      uint4 b2_1 = *(const uint4*)(rB1 + cb + 48);
      unsigned int c1_0[4] = {lerp2(a1_0.x,b1_0.x,tf0), lerp2(a1_0.y,b1_0.y,tf0),
                              lerp2(a1_0.z,b1_0.z,tf0), lerp2(a1_0.w,b1_0.w,tf0)};
      unsigned int c2_0[4] = {lerp2(a2_0.x,b2_0.x,tf0), lerp2(a2_0.y,b2_0.y,tf0),
                              lerp2(a2_0.z,b2_0.z,tf0), lerp2(a2_0.w,b2_0.w,tf0)};
      unsigned int c1_1[4] = {lerp2(a1_1.x,b1_1.x,tf1), lerp2(a1_1.y,b1_1.y,tf1),
                              lerp2(a1_1.z,b1_1.z,tf1), lerp2(a1_1.w,b1_1.w,tf1)};
      unsigned int c2_1[4] = {lerp2(a2_1.x,b2_1.x,tf1), lerp2(a2_1.y,b2_1.y,tf1),
                              lerp2(a2_1.z,b2_1.z,tf1), lerp2(a2_1.w,b2_1.w,tf1)};
      unsigned int pu0[4], qu0[4], pu1[4], qu1[4];
#pragma unroll
      for (int r4 = 0; r4 < 4; r4++){
        int jp = 4*q4 + r4;
        h2f c1h0 = u2h(c1_0[r4]); h2f c2h0 = u2h(c2_0[r4]);
        h2f c1h1 = u2h(c1_1[r4]); h2f c2h1 = u2h(c2_1[r4]);
        float pv0[2], qv0[2], pv1[2], qv1[2];
#pragma unroll
        for (int w = 0; w < 2; w++){
          int j = c0 + 2*jp + w;
          const uint4* r1 = (const uint4*)(dw2 + j*16);
          const uint4* r2 = (const uint4*)(dw2 + (96+j)*16);
          float d1_0 = 0.f, d2_0 = 0.f, d1_1 = 0.f, d2_1 = 0.f;
#pragma unroll
          for (int q = 0; q < 4; q++){
            uint4 wa = r1[q], wb = r2[q];
            d1_0 = dot2(wa.x, hdp0[4*q+0], d1_0); d1_0 = dot2(wa.y, hdp0[4*q+1], d1_0);
            d1_0 = dot2(wa.z, hdp0[4*q+2], d1_0); d1_0 = dot2(wa.w, hdp0[4*q+3], d1_0);
            d2_0 = dot2(wb.x, hdp0[4*q+0], d2_0); d2_0 = dot2(wb.y, hdp0[4*q+1], d2_0);
            d2_0 = dot2(wb.z, hdp0[4*q+2], d2_0); d2_0 = dot2(wb.w, hdp0[4*q+3], d2_0);
            d1_1 = dot2(wa.x, hdp1[4*q+0], d1_1); d1_1 = dot2(wa.y, hdp1[4*q+1], d1_1);
            d1_1 = dot2(wa.z, hdp1[4*q+2], d1_1); d1_1 = dot2(wa.w, hdp1[4*q+3], d1_1);
            d2_1 = dot2(wb.x, hdp1[4*q+0], d2_1); d2_1 = dot2(wb.y, hdp1[4*q+1], d2_1);
            d2_1 = dot2(wb.z, hdp1[4*q+2], d2_1); d2_1 = dot2(wb.w, hdp1[4*q+3], d2_1);
          }
          float c1v0 = w ? (float)c1h0.y : (float)c1h0.x;
          float c2v0 = w ? (float)c2h0.y : (float)c2h0.x;
          float c1v1 = w ? (float)c1h1.y : (float)c1h1.x;
          float c2v1 = w ? (float)c2h1.y : (float)c2h1.x;
          float dv0 = c1v0 * d1_0, av0 = 0.5f * c2v0 * d2_0;
          float dv1 = c1v1 * d1_1, av1 = 0.5f * c2v1 * d2_1;
          pv0[w] = dv0 + av0; qv0[w] = av0 - dv0;
          pv1[w] = dv1 + av1; qv1[w] = av1 - dv1;
        }
        pu0[r4] = pack2(pv0[0], pv0[1]); qu0[r4] = pack2(qv0[0], qv0[1]);
        pu1[r4] = pack2(pv1[0], pv1[1]); qu1[r4] = pack2(qv1[0], qv1[1]);
      }
      int uo = (c0 >> 1) + 4*q4;
      *(uint4*)(prow0 + uo) = *(uint4*)pu0;
      *(uint4*)(qrow0 + uo) = *(uint4*)qu0;
      *(uint4*)(prow1 + uo) = *(uint4*)pu1;
      *(uint4*)(qrow1 + uo) = *(uint4*)qu1;
    }
  }
}

// 5 nodes per 512-thread block; both roles stream contiguous rows
__global__ __launch_bounds__(512) void gather_layer(
    const int* __restrict__ doff, const int* __restrict__ soff,
    const unsigned short* __restrict__ pbuf, const unsigned short* __restrict__ qbuf,
    float* __restrict__ delta)
{
  int g = threadIdx.x / 96;
  int c = threadIdx.x - 96 * g;
  if (g >= 5) return;
  int n = blockIdx.x * 5 + g;
  if (n >= NN) return;
  const _Float16* ph = (const _Float16*)pbuf;
  const _Float16* qh = (const _Float16*)qbuf;
  float acc = 0.f;
  int d1 = doff[n+1];
  for (int p = doff[n]; p < d1; p++) acc += (float)ph[(long)p * 96 + c];
  int s1 = soff[n+1];
  for (int q = soff[n]; q < s1; q++) acc += (float)qh[(long)q * 96 + c];
  delta[(long)n * 96 + c] += 64.f * acc;   // undo 1/64 msg scale
}

// ---------------- xn -= h*delta; re-zero delta; refresh xnh -----------------
__global__ void node_upd(float* __restrict__ xn, float* __restrict__ delta,
                         unsigned int* __restrict__ xnh){
  int i = blockIdx.x * 256 + threadIdx.x;
  if (i >= NN * 48) return;
  float x0 = xn[2*i]   - 0.1f * delta[2*i];
  float x1 = xn[2*i+1] - 0.1f * delta[2*i+1];
  xn[2*i] = x0; xn[2*i+1] = x1;
  delta[2*i] = 0.f; delta[2*i+1] = 0.f;
  xnh[i] = pack2(x0, x1);
}

// ---------------- column sum over nodes -------------------------------------
__global__ void colsum(const float* __restrict__ xn, float* __restrict__ nodesum){
  int col = threadIdx.x % 96;
  int seg = threadIdx.x / 96;
  int stripe = blockIdx.x * 2 + seg;   // 0..399
  float acc = 0.f;
  for (int n = stripe; n < NN; n += 400) acc += xn[(long)n * 96 + col];
  unsafeAtomicAdd(nodesum + col, acc);
}

// ---------------- project to 16 outputs, scale, fp32 store ------------------
__global__ void project(const float* __restrict__ nodesum, const float* __restrict__ siT,
                        float* __restrict__ out){
  int j = threadIdx.x;
  if (j < 16){
    float a = 0.f;
#pragma unroll
    for (int c = 0; c < 96; c++) a += nodesum[c] * siT[j*96 + c];
    out[j] = a * 0.007071067811865475f;   // 1/sqrt(20000)
  }
}

// ---------------- host side -------------------------------------------------
extern "C" void kernel_launch(void* const* d_in, const int* in_sizes, int n_in,
                              void* d_out, int out_size, void* d_ws, size_t ws_size,
                              hipStream_t stream){
  const float* pos  = (const float*)d_in[0];
  const int* atom_z = (const int*)d_in[1];
  const int* esrc   = (const int*)d_in[2];
  const int* edst   = (const int*)d_in[3];

  float* ws      = (float*)d_ws;
  float* xn      = ws;                  // 1,920,000
  float* delta   = ws + 1920000;        // 1,920,000
  float* nodesum = ws + 3840000;        // 96
  float* WB      = ws + 3840096;        // 4,128 fp32 weights
  unsigned int* pk    = (unsigned int*)(ws + 3844224);  // 12,288
  unsigned int* lutL  = (unsigned int*)(ws + 3856512);  // 786,432 (3 MB)
  unsigned int* lut01 = (unsigned int*)(ws + 4642944);  // 65,536
  unsigned int* xnh   = (unsigned int*)(ws + 4708480);  // 960,000 (f16 rows)
  float* els    = ws + 5668480;                 // 320,000 edge lengths
  int*   cntd   = (int*)(ws + 5988480);         // 20,000
  int*   curd   = cntd + 20000;                 // 20,000
  int*   doff   = curd + 20000;                 // 20,004
  int*   cnts   = doff + 20004;                 // 20,000
  int*   curs   = cnts + 20000;                 // 20,000
  int*   soff   = curs + 20000;                 // 20,004
  int*   srcS   = soff + 20004;                 // 320,000
  int*   dstS   = srcS + 320000;                // 320,000
  int*   qpos   = dstS + 320000;                // 320,000 -> end 7,068,488
  // message buffers (64B-aligned bases); ws >= 151 MB confirmed by round-3
  // WRITE_SIZE (full 123 MB single-dispatch message write)
  unsigned short* pbufL = (unsigned short*)(ws + 7068496);   // NE*96 h (30.7MB)
  unsigned short* qbufL = (unsigned short*)(ws + 22428496);  // NE*96 h (30.7MB)
  unsigned short* pbuf0 = (unsigned short*)(ws + 7068496);   // NE*64 h (alias)
  unsigned short* qbuf0 = (unsigned short*)(ws + 17308496);  // NE*64 h (alias)

  float* embedF = WB + 0;        // 160
  float* dl0w1T = WB + 160;      // 256   [32][8]
  float* dl0w2T = WB + 416;      // 1024  [32][32]
  float* dl1w1T = WB + 1440;     // 128   [32][4]
  float* dl1w2T = WB + 1568;     // 1024  [32][32]
  float* siT    = WB + 2592;     // 1536  [16][96]

  hipMemsetAsync(cntd, 0, 20000 * 4, stream);
  hipMemsetAsync(cnts, 0, 20000 * 4, stream);
  hipMemsetAsync(delta, 0, (size_t)NN * 96 * 4, stream);
  hipMemsetAsync(nodesum, 0, 96 * 4, stream);

  TTab tb;
  int ti = 0;
  auto add = [&](const void* s, float* dst, int R, int C, int tr){
    tb.e[ti].src = (const float*)s; tb.e[ti].dst = dst;
    tb.e[ti].R = R; tb.e[ti].C = C; tb.e[ti].trans = tr; ti++;
  };
  add(d_in[4],  embedF, 20, 8, 0);
  add(d_in[5],  dl0w1T, 8, 32, 1);
  add(d_in[6],  dl0w2T, 32, 32, 1);
  add(d_in[7],  dl1w1T, 4, 32, 1);
  add(d_in[8],  dl1w2T, 32, 32, 1);
  add(d_in[17], siT, 96, 16, 1);

  PTab pt;
  int pi = 0;
  auto padd = [&](const void* s, unsigned int* dst, int R, int C){
    pt.e[pi].src = (const float*)s; pt.e[pi].dst = dst;
    pt.e[pi].R = R; pt.e[pi].C = C; pi++;
  };
  for (int i = 0; i < 2; i++){
    padd((const float*)d_in[15] + i*6144, pk + i*6144 + 0,    192, 32);  // dw1T [32][96]
    padd((const float*)d_in[16] + i*6144, pk + i*6144 + 3072, 32, 192);  // dw2  [192][16]
  }

  convw<<<6, 256, 0, stream>>>(tb);
  packw<<<4, 256, 0, stream>>>(pt);
  build_lut<<<2*NT, 384, 0, stream>>>((const float*)d_in[11], (const float*)d_in[12],
                                      (const float*)d_in[13], (const float*)d_in[14],
                                      (unsigned short*)lutL);
  build_lut01<<<NT, 64, 0, stream>>>((const float*)d_in[9], (const float*)d_in[10],
                                     (unsigned short*)lut01);
  count_k<<<(NE + 255)/256, 256, 0, stream>>>(esrc, edst, cntd, cnts);
  prefix_k<<<1, 1024, 0, stream>>>(cntd, doff, curd, NE);
  prefix_k<<<1, 1024, 0, stream>>>(cnts, soff, curs, NE);
  fill_comb<<<(NE + 255)/256, 256, 0, stream>>>(esrc, edst, curd, curs, srcS, dstS, qpos);
  node_init<<<(NN + 255)/256, 256, 0, stream>>>(atom_z, embedF, dl0w1T, dl0w2T, xn);

  edge_init<<<(NE + 255)/256, 256, 0, stream>>>(
      pos, srcS, dstS, qpos, els, pbuf0, qbuf0, dl1w1T, dl1w2T, lut01);
  gather_init<<<(NN + 3)/4, 256, 0, stream>>>(doff, soff, pbuf0, qbuf0, xn);
  pack_xnh<<<(NN*48 + 255)/256, 256, 0, stream>>>(xn, xnh);

  for (int i = 0; i < 2; i++){
    layer_k<<<NE/512, 256, 0, stream>>>(
        srcS, dstS, qpos, els, xnh, pbufL, qbufL,
        lutL + (long)i * NT * 192, pk + i*6144);
    gather_layer<<<(NN + 4)/5, 512, 0, stream>>>(doff, soff, pbufL, qbufL, delta);
    node_upd<<<(NN*48 + 255)/256, 256, 0, stream>>>(xn, delta, xnh);
  }
  colsum<<<200, 192, 0, stream>>>(xn, nodesum);
  project<<<1, 64, 0, stream>>>(nodesum, siT, (float*)d_out);
}

// Round 5
// 936.497 us; speedup vs baseline: 1.0908x; 1.0908x over previous
//
#include <hip/hip_runtime.h>
#include <hip/hip_bf16.h>

#define NN 20000
#define NE 320000
#define NT 2048            // filter LUT entries over len in [0, 1.7321]

typedef _Float16 h2f __attribute__((ext_vector_type(2)));

__device__ __forceinline__ h2f u2h(unsigned int u){
  union { unsigned int u; h2f h; } v; v.u = u; return v.h;
}
__device__ __forceinline__ unsigned int h2u(h2f h){
  union { h2f h; unsigned int u; } v; v.h = h; return v.u;
}
__device__ __forceinline__ unsigned int pack2(float a, float b){
  h2f h; h.x = (_Float16)a; h.y = (_Float16)b;
  union { h2f h; unsigned int u; } v; v.h = h; return v.u;
}
__device__ __forceinline__ unsigned short f16b(float a){
  union { _Float16 h; unsigned short u; } v; v.h = (_Float16)a; return v.u;
}
__device__ __forceinline__ float dot2(unsigned int w, h2f x, float acc){
#if __has_builtin(__builtin_amdgcn_fdot2)
  return __builtin_amdgcn_fdot2(u2h(w), x, acc, false);
#else
  h2f c = u2h(w);
  return acc + (float)(c.x) * (float)(x.x) + (float)(c.y) * (float)(x.y);
#endif
}
// packed f16 lerp: a + t*(b-a)
__device__ __forceinline__ unsigned int lerp2(unsigned int a, unsigned int b, h2f t){
  h2f ha = u2h(a), hb = u2h(b);
  return h2u(ha + t * (hb - ha));
}

// jax.nn.gelu default (approximate=True): 0.5x(1+tanh(t)) == x*sigmoid(2t)
__device__ __forceinline__ float geluf(float x){
  float t = 0.7978845608028654f * x * (1.0f + 0.044715f * x * x);
  return x / (1.0f + __expf(-2.0f * t));
}

struct TEnt { const float* src; float* dst; int R; int C; int trans; };
struct TTab { TEnt e[8]; };
struct PEnt { const float* src; unsigned int* dst; int R; int C; };
struct PTab { PEnt e[4]; };

__device__ __forceinline__ void lut_basis(int ent, float* b){
  float len = fmaxf((float)ent * (1.7321f / (float)(NT - 1)), 1e-6f);
  float sc = 3.1622776601683795f / fmaxf(len, 1e-6f);  // sqrt(2/MAXR)*sqrt(B)/r
#pragma unroll
  for (int k = 0; k < 10; k++)
    b[k] = sinf((float)(k + 1) * 1.5707963267948966f * len) * sc;
}

// ---------------- merged weight prep: convw + packw + both LUTs -------------
// blocks: [0,6) convw, [6,10) packw, [10,10+2*NT) layer LUT, rest init LUT
__global__ __launch_bounds__(384) void prep_k(
    TTab tb, PTab pt,
    const float* __restrict__ fABw1, const float* __restrict__ fABw2,
    const float* __restrict__ fCw1,  const float* __restrict__ fCw2,
    unsigned short* __restrict__ lutH,
    const float* __restrict__ f01w1, const float* __restrict__ f01w2,
    unsigned short* __restrict__ lut01H)
{
  int b = blockIdx.x;
  int t = threadIdx.x;
  if (b < 6){
    TEnt en = tb.e[b];
    int n = en.R * en.C;
    for (int i = t; i < n; i += 384){
      float v = en.src[i];
      if (en.trans){
        int r = i / en.C, c = i - r * en.C;
        en.dst[c * en.R + r] = v;
      } else {
        en.dst[i] = v;
      }
    }
    return;
  }
  if (b < 10){
    PEnt en = pt.e[b - 6];
    int half = en.R >> 1;
    int n = en.C * half;
    for (int i = t; i < n; i += 384){
      int c = i / half, rp = i - c * half;
      float a = en.src[(2*rp)     * en.C + c];
      float bb = en.src[(2*rp + 1) * en.C + c];
      en.dst[i] = pack2(a, bb);
    }
    return;
  }
  if (b < 10 + 2*NT){
    int bb = b - 10;
    int ent = bb & (NT - 1);
    int layer = bb >> 11;       // NT = 2048
    float bas[10];
    lut_basis(ent, bas);
    __shared__ float h[192];
    if (t < 192){
      int f = t >> 6, l = t & 63;       // f: 0=A, 1=B, 2=C
      const float* w1 = (f < 2) ? (fABw1 + (layer*2 + f) * 640)
                                : (fCw1 + layer * 640);
      float a = 0.f;
#pragma unroll
      for (int k = 0; k < 10; k++) a += bas[k] * w1[k*64 + l];
      h[t] = geluf(a);
    }
    __syncthreads();
    float a = 0.f;
    if (t < 192){
      int f = t / 96, j = t - 96 * f;
      const float* w2 = fABw2 + (layer*2 + f) * 6144;
      for (int l = 0; l < 64; l++) a += h[f*64 + l] * w2[l*96 + j];
    } else {
      int j = t - 192;
      const float* w2 = fCw2 + layer * 12288;
      for (int l = 0; l < 64; l++) a += h[128 + l] * w2[l*192 + j];
    }
    lutH[((long)(layer * NT + ent)) * 384 + t] = f16b(a);
    return;
  }
  // init LUT: 6 entries per block (384 = 6*64 threads)
  int blk = b - 10 - 2*NT;
  int ent = blk * 6 + (t >> 6);
  if (ent >= NT) return;
  int tl = t & 63;
  int p = tl >> 5, jj = tl & 31;
  float bas[10];
  lut_basis(ent, bas);
  const float* w1 = f01w1 + p * 640;
  const float* w2 = f01w2 + p * 2048;
  float W = 0.f;
  for (int l = 0; l < 64; l++){
    float a = 0.f;
#pragma unroll
    for (int k = 0; k < 10; k++) a += bas[k] * w1[k*64 + l];
    W += geluf(a) * w2[l*32 + jj];
  }
  lut01H[(long)ent * 64 + tl] = f16b(W);
}

// ---------------- merged: edge degree count + node init ---------------------
__global__ __launch_bounds__(256) void countnode_k(
    const int* __restrict__ esrc, const int* __restrict__ edst,
    int* __restrict__ cntd, int* __restrict__ cnts,
    const int* __restrict__ az, const float* __restrict__ embedF,
    const float* __restrict__ w1T /*[32][8]*/, const float* __restrict__ w2T /*[32][32]*/,
    float* __restrict__ xn)
{
  if (blockIdx.x < NE/256){
    int e = blockIdx.x * 256 + threadIdx.x;
    atomicAdd(cntd + edst[e], 1);
    atomicAdd(cnts + esrc[e], 1);
    return;
  }
  int n = (blockIdx.x - NE/256) * 256 + threadIdx.x;
  if (n >= NN) return;
  int z = az[n];
  float ee[8];
#pragma unroll
  for (int k = 0; k < 8; k++) ee[k] = embedF[z * 8 + k];
  float hid[32];
#pragma unroll
  for (int l = 0; l < 32; l++){
    float a = 0.f;
#pragma unroll
    for (int k = 0; k < 8; k++) a += ee[k] * w1T[l * 8 + k];
    hid[l] = geluf(a);
  }
  float* row = xn + (long)n * 96;
#pragma unroll
  for (int j = 0; j < 32; j++){
    float a = 0.f;
#pragma unroll
    for (int l = 0; l < 32; l++) a += hid[l] * w2T[j * 32 + l];
    row[j] = a;
  }
#pragma unroll
  for (int j = 32; j < 96; j++) row[j] = 0.f;
}

// ---------------- both prefix sums in one launch ----------------------------
__global__ __launch_bounds__(1024) void prefix_k(
    const int* __restrict__ cntd, int* __restrict__ doff, int* __restrict__ curd,
    const int* __restrict__ cnts, int* __restrict__ soff, int* __restrict__ curs)
{
  const int* cnt = blockIdx.x ? cnts : cntd;
  int* off = blockIdx.x ? soff : doff;
  int* cur = blockIdx.x ? curs : curd;
  __shared__ int part[1024];
  int t = threadIdx.x;
  int base = t * 20;
  int s = 0;
  for (int i = 0; i < 20; i++){ int idx = base + i; if (idx < NN) s += cnt[idx]; }
  part[t] = s; __syncthreads();
  for (int d = 1; d < 1024; d <<= 1){
    int v = (t >= d) ? part[t - d] : 0;
    __syncthreads();
    part[t] += v;
    __syncthreads();
  }
  int run = (t == 0) ? 0 : part[t - 1];
  for (int i = 0; i < 20; i++){
    int idx = base + i;
    if (idx < NN){ off[idx] = run; cur[idx] = run; run += cnt[idx]; }
  }
  if (t == 0) off[NN] = NE;
}

// p = dst-sorted slot of edge e; q = src-sorted slot; qpos[p]=q, sinc[q]=p
__global__ void fill_comb(const int* __restrict__ esrc, const int* __restrict__ edst,
                          int* __restrict__ curd, int* __restrict__ curs,
                          int* __restrict__ srcS, int* __restrict__ dstS,
                          int* __restrict__ qpos, int* __restrict__ sinc){
  int e = blockIdx.x * 256 + threadIdx.x;
  if (e >= NE) return;
  int s = esrc[e], d = edst[e];
  int p = atomicAdd(curd + d, 1);
  srcS[p] = s; dstS[p] = d;
  int q = atomicAdd(curs + s, 1);
  qpos[p] = q;
  sinc[q] = p;
}

// ---------------- edge init: p-row (dst side) + scattered q-row (src side) --
// rows are 64 halves = 128B = one full cache line -> scatter is full-line
__global__ __launch_bounds__(256) void edge_init(
    const float* __restrict__ pos, const int* __restrict__ srcS,
    const int* __restrict__ dstS, const int* __restrict__ qpos,
    float* __restrict__ els,
    unsigned short* __restrict__ pbuf0, unsigned short* __restrict__ qbuf0,
    const float* __restrict__ w1T /*dl1w1T [32][4]*/, const float* __restrict__ w2T /*[32][32]*/,
    const unsigned int* __restrict__ lut01)
{
  int p = blockIdx.x * 256 + threadIdx.x;
  if (p >= NE) return;
  int s = srcS[p], d = dstS[p];
  float x = pos[s*3+0] - pos[d*3+0];
  float y = pos[s*3+1] - pos[d*3+1];
  float z = pos[s*3+2] - pos[d*3+2];
  float L = sqrtf(x*x + y*y + z*z + 1e-12f);
  float iv = 1.0f / fmaxf(L, 1e-6f);
  els[p] = L;

  float u = L - 2.0f;   // 2*(len/MAXR - 1), MAXR=2
  float cut = 0.5f * (1.0f - cosf(3.14159265358979323f * u));
  cut = (u > 0.0f) ? 0.0f : cut;
  cut = (u < -1.0f) ? 1.0f : cut;
  float xe0 = cut, cc = cut * 1.7320508075688772f * iv;
  float xe1 = cc*x, xe2 = cc*y, xe3 = cc*z;
  float hid[32];
#pragma unroll
  for (int l = 0; l < 32; l++){
    float a = xe0*w1T[l*4+0] + xe1*w1T[l*4+1] + xe2*w1T[l*4+2] + xe3*w1T[l*4+3];
    hid[l] = geluf(a);
  }
  float xeh[32];
#pragma unroll
  for (int j = 0; j < 32; j++){
    float a = 0.f;
#pragma unroll
    for (int l = 0; l < 32; l++) a += hid[l] * w2T[j*32 + l];
    xeh[j] = a;
  }
  float tt = fminf(L * ((float)(NT-1) / 1.7321f), (float)(NT-1) - 0.001f);
  int i0 = (int)tt; float tfv = tt - (float)i0;
  h2f tf2; tf2.x = (_Float16)tfv; tf2.y = tf2.x;
  h2f h05; h05.x = (_Float16)0.5f; h05.y = h05.x;
  const unsigned int* rA = lut01 + i0 * 32;
  const unsigned int* rB = rA + 32;

  unsigned int xp[16];
#pragma unroll
  for (int jp = 0; jp < 16; jp++)
    xp[jp] = pack2(xeh[2*jp] * 0.0625f, xeh[2*jp+1] * 0.0625f);

  unsigned int du[16], au[16];
#pragma unroll
  for (int q = 0; q < 4; q++){
    uint4 a = ((const uint4*)rA)[q];
    uint4 b = ((const uint4*)rB)[q];
    du[4*q+0] = h2u(u2h(lerp2(a.x, b.x, tf2)) * u2h(xp[4*q+0]));
    du[4*q+1] = h2u(u2h(lerp2(a.y, b.y, tf2)) * u2h(xp[4*q+1]));
    du[4*q+2] = h2u(u2h(lerp2(a.z, b.z, tf2)) * u2h(xp[4*q+2]));
    du[4*q+3] = h2u(u2h(lerp2(a.w, b.w, tf2)) * u2h(xp[4*q+3]));
  }
#pragma unroll
  for (int q = 0; q < 4; q++){
    uint4 a = ((const uint4*)(rA + 16))[q];
    uint4 b = ((const uint4*)(rB + 16))[q];
    au[4*q+0] = h2u(u2h(lerp2(a.x, b.x, tf2)) * u2h(xp[4*q+0]) * h05);
    au[4*q+1] = h2u(u2h(lerp2(a.y, b.y, tf2)) * u2h(xp[4*q+1]) * h05);
    au[4*q+2] = h2u(u2h(lerp2(a.z, b.z, tf2)) * u2h(xp[4*q+2]) * h05);
    au[4*q+3] = h2u(u2h(lerp2(a.w, b.w, tf2)) * u2h(xp[4*q+3]) * h05);
  }
  unsigned short* prow = pbuf0 + (long)p * 64;
  unsigned short* qrow = qbuf0 + (long)qpos[p] * 64;
#pragma unroll
  for (int q = 0; q < 4; q++){
    ((uint4*)prow)[q]      = ((uint4*)du)[q];
    ((uint4*)(prow+32))[q] = ((uint4*)au)[q];
  }
  unsigned int nd[16];
#pragma unroll
  for (int i = 0; i < 16; i++) nd[i] = du[i] ^ 0x80008000u;  // negate packed f16
#pragma unroll
  for (int q = 0; q < 4; q++){
    ((uint4*)qrow)[q]      = ((uint4*)nd)[q];
    ((uint4*)(qrow+32))[q] = ((uint4*)au)[q];
  }
}

// 4 nodes (4 waves) per 256-thread block; both roles stream contiguous rows;
// also packs the node's xnh f16 row (fused former pack_xnh)
__global__ __launch_bounds__(256) void gather_init(
    const int* __restrict__ doff, const int* __restrict__ soff,
    const unsigned short* __restrict__ pbuf0, const unsigned short* __restrict__ qbuf0,
    float* __restrict__ xn, unsigned int* __restrict__ xnh)
{
  int n = blockIdx.x * 4 + (threadIdx.x >> 6);
  int c = threadIdx.x & 63;          // lane == c
  if (n >= NN) return;
  const _Float16* ph = (const _Float16*)pbuf0;
  const _Float16* qh = (const _Float16*)qbuf0;
  float acc = 0.f;
  int d1 = doff[n+1];
  for (int p = doff[n]; p < d1; p++) acc += (float)ph[(long)p * 64 + c];
  int s1 = soff[n+1];
  for (int q = soff[n]; q < s1; q++) acc += (float)qh[(long)q * 64 + c];
  float v = 16.f * acc;              // cols 32..95 (cols were zero)
  xn[(long)n * 96 + 32 + c] = v;
  float other = __shfl_xor(v, 1);
  if (!(c & 1)) xnh[n * 48 + 16 + (c >> 1)] = pack2(v, other);
  if (c < 16){
    float a = xn[(long)n * 96 + 2*c];
    float b = xn[(long)n * 96 + 2*c + 1];
    xnh[n * 48 + c] = pack2(a, b);
  }
}

// ---------------- conv layer: 1 edge/thread, scalar global weights ----------
// p-row (dst, 96 h) -> pbuf[p]; q-row (src, 96 h) -> qbuf[p] (both contiguous)
// stored value = true/64 (undone in gather_upd)
// pk layout per layer (uints): dw1T[32][96] @0, dw2[192][16] @3072 (6144 total)
// lut row per entry (uints):   WaPairs[48] | WbPairs[48] | WcPairs[96] (192)
__global__ __launch_bounds__(256, 4) void layer_k(
    const int* __restrict__ srcS, const int* __restrict__ dstS,
    const float* __restrict__ els, const unsigned int* __restrict__ xnh,
    unsigned short* __restrict__ pbuf, unsigned short* __restrict__ qbuf,
    const unsigned int* __restrict__ lut, const unsigned int* __restrict__ pk)
{
  int p = blockIdx.x * 256 + threadIdx.x;
  if (p >= NE) return;

  const unsigned int* dw1T = pk;          // [32][96]  (wave-uniform -> s_load)
  const unsigned int* dw2  = pk + 3072;   // [192][16]

  int s = srcS[p], d = dstS[p];
  float L = els[p];
  float tt = fminf(L * ((float)(NT-1) / 1.7321f), (float)(NT-1) - 0.001f);
  int i0 = (int)tt; float tfv = tt - (float)i0;
  h2f tf2; tf2.x = (_Float16)tfv; tf2.y = tf2.x;
  const unsigned int* rA = lut + (long)i0 * 192;
  const unsigned int* rB = rA + 192;

  const unsigned int* xsh = xnh + s * 48;   // f16 row, 192B
  const unsigned int* xdh = xnh + d * 48;   // sorted: shared across ~16 lanes
  h2f c32; c32.x = (_Float16)0.03125f;  c32.y = c32.x;
  h2f c64; c64.x = (_Float16)0.015625f; c64.y = c64.x;

  float hd[32];
#pragma unroll
  for (int l = 0; l < 32; l++) hd[l] = 0.f;

  // ---- merged A(grad)/B(ave) pass: hd += dw1T^T @ [Wa*(xd-xs); Wb*(xd+xs)/2]
  for (int jc = 0; jc < 96; jc += 8){
    int jh = jc >> 1;
    uint4 xsu = *(const uint4*)(xsh + jh);
    uint4 xdu = *(const uint4*)(xdh + jh);
    uint4 aA = *(const uint4*)(rA + jh);
    uint4 bA = *(const uint4*)(rB + jh);
    uint4 aB = *(const uint4*)(rA + 48 + jh);
    uint4 bB = *(const uint4*)(rB + 48 + jh);
    unsigned int xsa[4] = {xsu.x, xsu.y, xsu.z, xsu.w};
    unsigned int xda[4] = {xdu.x, xdu.y, xdu.z, xdu.w};
    unsigned int wA[4] = {lerp2(aA.x,bA.x,tf2), lerp2(aA.y,bA.y,tf2),
                          lerp2(aA.z,bA.z,tf2), lerp2(aA.w,bA.w,tf2)};
    unsigned int wB[4] = {lerp2(aB.x,bB.x,tf2), lerp2(aB.y,bB.y,tf2),
                          lerp2(aB.z,bB.z,tf2), lerp2(aB.w,bB.w,tf2)};
    h2f gpA[4], gpB[4];
#pragma unroll
    for (int q = 0; q < 4; q++){
      h2f hs = u2h(xsa[q]), hdd = u2h(xda[q]);
      h2f dv2 = (hdd - hs) * c32;
      h2f av2 = (hdd + hs) * c64;
      gpA[q] = u2h(wA[q]) * dv2;
      gpB[q] = u2h(wB[q]) * av2;
    }
#pragma unroll
    for (int l = 0; l < 32; l++){
      uint4 w1 = *(const uint4*)(dw1T + l*96 + jh);
      uint4 w2 = *(const uint4*)(dw1T + l*96 + 48 + jh);
      float acc = hd[l];
      acc = dot2(w1.x, gpA[0], acc); acc = dot2(w1.y, gpA[1], acc);
      acc = dot2(w1.z, gpA[2], acc); acc = dot2(w1.w, gpA[3], acc);
      acc = dot2(w2.x, gpB[0], acc); acc = dot2(w2.y, gpB[1], acc);
      acc = dot2(w2.z, gpB[2], acc); acc = dot2(w2.w, gpB[3], acc);
      hd[l] = acc;
    }
  }

  // ---- hd gelu (undo 1/32), pack at 1/64 for output dots ----
  h2f hdp[16];
#pragma unroll
  for (int lp = 0; lp < 16; lp++){
    h2f r;
    r.x = (_Float16)(geluf(32.f*hd[2*lp])   * 0.015625f);
    r.y = (_Float16)(geluf(32.f*hd[2*lp+1]) * 0.015625f);
    hdp[lp] = r;
  }

  // ---- output: dv = Wc[j]*d1, av = 0.5*Wc[96+j]*d2; rows at true/64 --------
  unsigned int* prow = (unsigned int*)(pbuf + (long)p * 96);
  unsigned int* qrow = (unsigned int*)(qbuf + (long)p * 96);
  for (int c0 = 0; c0 < 96; c0 += 32){
    unsigned int pu[16], qu[16];
#pragma unroll
    for (int q4 = 0; q4 < 4; q4++){
      int cb = 96 + (c0 >> 1) + 4*q4;
      uint4 a1 = *(const uint4*)(rA + cb);
      uint4 b1 = *(const uint4*)(rB + cb);
      uint4 a2 = *(const uint4*)(rA + cb + 48);
      uint4 b2 = *(const uint4*)(rB + cb + 48);
      unsigned int c1l[4] = {lerp2(a1.x,b1.x,tf2), lerp2(a1.y,b1.y,tf2),
                             lerp2(a1.z,b1.z,tf2), lerp2(a1.w,b1.w,tf2)};
      unsigned int c2l[4] = {lerp2(a2.x,b2.x,tf2), lerp2(a2.y,b2.y,tf2),
                             lerp2(a2.z,b2.z,tf2), lerp2(a2.w,b2.w,tf2)};
#pragma unroll
      for (int r4 = 0; r4 < 4; r4++){
        int jp = 4*q4 + r4;
        h2f c1h = u2h(c1l[r4]);
        h2f c2h = u2h(c2l[r4]);
        float pv2[2], qv2[2];
#pragma unroll
        for (int w = 0; w < 2; w++){
          int j = c0 + 2*jp + w;
          float d1 = 0.f, d2 = 0.f;
          const uint4* r1 = (const uint4*)(dw2 + j*16);
          const uint4* r2 = (const uint4*)(dw2 + (96+j)*16);
#pragma unroll
          for (int q = 0; q < 4; q++){
            uint4 wa = r1[q], wb = r2[q];
            d1 = dot2(wa.x, hdp[4*q+0], d1); d1 = dot2(wa.y, hdp[4*q+1], d1);
            d1 = dot2(wa.z, hdp[4*q+2], d1); d1 = dot2(wa.w, hdp[4*q+3], d1);
            d2 = dot2(wb.x, hdp[4*q+0], d2); d2 = dot2(wb.y, hdp[4*q+1], d2);
            d2 = dot2(wb.z, hdp[4*q+2], d2); d2 = dot2(wb.w, hdp[4*q+3], d2);
          }
          float c1 = w ? (float)c1h.y : (float)c1h.x;
          float c2 = w ? (float)c2h.y : (float)c2h.x;
          float dv = c1 * d1;           // true/64
          float av = 0.5f * c2 * d2;    // true/64
          pv2[w] = dv + av;
          qv2[w] = av - dv;
        }
        pu[jp] = pack2(pv2[0], pv2[1]);
        qu[jp] = pack2(qv2[0], qv2[1]);
      }
    }
    int uo = c0 >> 1;
#pragma unroll
    for (int q = 0; q < 4; q++){
      *(uint4*)(prow + uo + 4*q) = ((uint4*)pu)[q];
      *(uint4*)(qrow + uo + 4*q) = ((uint4*)qu)[q];
    }
  }
}

// fused gather + node update + xnh repack; 5 nodes per 512-thread block
__global__ __launch_bounds__(512) void gather_upd(
    const int* __restrict__ doff, const int* __restrict__ soff,
    const int* __restrict__ sinc,
    const unsigned short* __restrict__ pbuf, const unsigned short* __restrict__ qbuf,
    float* __restrict__ xn, unsigned int* __restrict__ xnh)
{
  int g = threadIdx.x / 96;
  int c = threadIdx.x - 96 * g;
  if (g >= 5) return;
  int n = blockIdx.x * 5 + g;
  if (n >= NN) return;
  const _Float16* ph = (const _Float16*)pbuf;
  const _Float16* qh = (const _Float16*)qbuf;
  float acc = 0.f;
  int d1 = doff[n+1];
  for (int p = doff[n]; p < d1; p++) acc += (float)ph[(long)p * 96 + c];
  int s1 = soff[n+1];
  for (int ii = soff[n]; ii < s1; ii++){
    int p = sinc[ii];
    acc += (float)qh[(long)p * 96 + c];
  }
  long idx = (long)n * 96 + c;
  float x = xn[idx] - 6.4f * acc;     // 0.1 step * 64 msg scale
  xn[idx] = x;
  float other = __shfl_xor(x, 1);     // pair lanes are lane^1 (tid pairs even/odd)
  if (!(c & 1)) xnh[n * 48 + (c >> 1)] = pack2(x, other);
}

// ---------------- column sum over nodes -------------------------------------
__global__ void colsum(const float* __restrict__ xn, float* __restrict__ nodesum){
  int col = threadIdx.x % 96;
  int seg = threadIdx.x / 96;
  int stripe = blockIdx.x * 2 + seg;   // 0..399
  float acc = 0.f;
  for (int n = stripe; n < NN; n += 400) acc += xn[(long)n * 96 + col];
  unsafeAtomicAdd(nodesum + col, acc);
}

// ---------------- project to 16 outputs, scale, fp32 store ------------------
__global__ void project(const float* __restrict__ nodesum, const float* __restrict__ siT,
                        float* __restrict__ out){
  int j = threadIdx.x;
  if (j < 16){
    float a = 0.f;
#pragma unroll
    for (int c = 0; c < 96; c++) a += nodesum[c] * siT[j*96 + c];
    out[j] = a * 0.007071067811865475f;   // 1/sqrt(20000)
  }
}

// ---------------- host side -------------------------------------------------
extern "C" void kernel_launch(void* const* d_in, const int* in_sizes, int n_in,
                              void* d_out, int out_size, void* d_ws, size_t ws_size,
                              hipStream_t stream){
  const float* pos  = (const float*)d_in[0];
  const int* atom_z = (const int*)d_in[1];
  const int* esrc   = (const int*)d_in[2];
  const int* edst   = (const int*)d_in[3];

  float* ws      = (float*)d_ws;
  float* xn      = ws;                  // 1,920,000
  float* nodesum = ws + 1920000;        // 96
  float* WB      = ws + 1920096;        // 4,128 fp32 weights
  unsigned int* pk    = (unsigned int*)(ws + 1924224);  // 12,288
  unsigned int* lutL  = (unsigned int*)(ws + 1936512);  // 786,432 (3 MB)
  unsigned int* lut01 = (unsigned int*)(ws + 2722944);  // 65,536
  unsigned int* xnh   = (unsigned int*)(ws + 2788480);  // 960,000 (f16 rows)
  float* els    = ws + 3748480;                 // 320,000 edge lengths
  int*   cntd   = (int*)(ws + 4068480);         // 20,000
  int*   cnts   = cntd + 20000;                 // 20,000 (contiguous for 1 memset)
  int*   curd   = cnts + 20000;                 // 20,000
  int*   curs   = curd + 20000;                 // 20,000
  int*   doff   = curs + 20000;                 // 20,004
  int*   soff   = doff + 20004;                 // 20,004
  int*   srcS   = soff + 20004;                 // 320,000
  int*   dstS   = srcS + 320000;                // 320,000
  int*   qpos   = dstS + 320000;                // 320,000
  int*   sinc   = qpos + 320000;                // 320,000 -> end 5,468,488
  // message buffers; layout end = 5,468,496 + 2*15,360,000 = 36,188,496 floats
  // (144.8 MB <= round-4's verified 151.2 MB footprint)
  unsigned short* pbufL = (unsigned short*)(ws + 5468496);   // NE*96 halves
  unsigned short* qbufL = (unsigned short*)(ws + 20828496);  // NE*96 halves
  unsigned short* pbuf0 = (unsigned short*)(ws + 5468496);   // NE*64 halves (alias)
  unsigned short* qbuf0 = (unsigned short*)(ws + 15708496);  // NE*64 halves (alias)

  float* embedF = WB + 0;        // 160
  float* dl0w1T = WB + 160;      // 256   [32][8]
  float* dl0w2T = WB + 416;      // 1024  [32][32]
  float* dl1w1T = WB + 1440;     // 128   [32][4]
  float* dl1w2T = WB + 1568;     // 1024  [32][32]
  float* siT    = WB + 2592;     // 1536  [16][96]

  hipMemsetAsync(cntd, 0, 40000 * 4, stream);
  hipMemsetAsync(nodesum, 0, 96 * 4, stream);

  TTab tb;
  int ti = 0;
  auto add = [&](const void* s, float* dst, int R, int C, int tr){
    tb.e[ti].src = (const float*)s; tb.e[ti].dst = dst;
    tb.e[ti].R = R; tb.e[ti].C = C; tb.e[ti].trans = tr; ti++;
  };
  add(d_in[4],  embedF, 20, 8, 0);
  add(d_in[5],  dl0w1T, 8, 32, 1);
  add(d_in[6],  dl0w2T, 32, 32, 1);
  add(d_in[7],  dl1w1T, 4, 32, 1);
  add(d_in[8],  dl1w2T, 32, 32, 1);
  add(d_in[17], siT, 96, 16, 1);

  PTab pt;
  int pi = 0;
  auto padd = [&](const void* s, unsigned int* dst, int R, int C){
    pt.e[pi].src = (const float*)s; pt.e[pi].dst = dst;
    pt.e[pi].R = R; pt.e[pi].C = C; pi++;
  };
  for (int i = 0; i < 2; i++){
    padd((const float*)d_in[15] + i*6144, pk + i*6144 + 0,    192, 32);  // dw1T [32][96]
    padd((const float*)d_in[16] + i*6144, pk + i*6144 + 3072, 32, 192);  // dw2  [192][16]
  }

  // weight prep (convw+packw+both LUTs) in one launch
  prep_k<<<10 + 2*NT + (NT + 5)/6, 384, 0, stream>>>(
      tb, pt, (const float*)d_in[11], (const float*)d_in[12],
      (const float*)d_in[13], (const float*)d_in[14], (unsigned short*)lutL,
      (const float*)d_in[9], (const float*)d_in[10], (unsigned short*)lut01);
  // degree count + node init in one launch
  countnode_k<<<NE/256 + (NN + 255)/256, 256, 0, stream>>>(
      esrc, edst, cntd, cnts, atom_z, embedF, dl0w1T, dl0w2T, xn);
  prefix_k<<<2, 1024, 0, stream>>>(cntd, doff, curd, cnts, soff, curs);
  fill_comb<<<(NE + 255)/256, 256, 0, stream>>>(esrc, edst, curd, curs,
                                                srcS, dstS, qpos, sinc);
  edge_init<<<(NE + 255)/256, 256, 0, stream>>>(
      pos, srcS, dstS, qpos, els, pbuf0, qbuf0, dl1w1T, dl1w2T, lut01);
  gather_init<<<(NN + 3)/4, 256, 0, stream>>>(doff, soff, pbuf0, qbuf0, xn, xnh);

  for (int i = 0; i < 2; i++){
    layer_k<<<NE/256, 256, 0, stream>>>(
        srcS, dstS, els, xnh, pbufL, qbufL,
        lutL + (long)i * NT * 192, pk + i*6144);
    gather_upd<<<(NN + 4)/5, 512, 0, stream>>>(doff, soff, sinc, pbufL, qbufL,
                                               xn, xnh);
  }
  colsum<<<200, 192, 0, stream>>>(xn, nodesum);
  project<<<1, 64, 0, stream>>>(nodesum, siT, (float*)d_out);
}

// Round 10
// 890.426 us; speedup vs baseline: 1.1473x; 1.0517x over previous
//
#include <hip/hip_runtime.h>
#include <hip/hip_bf16.h>

#define NN 20000
#define NE 320000
#define NT 2048            // filter LUT entries over len in [0, 1.7321]

typedef _Float16 h2f __attribute__((ext_vector_type(2)));

__device__ __forceinline__ h2f u2h(unsigned int u){
  union { unsigned int u; h2f h; } v; v.u = u; return v.h;
}
__device__ __forceinline__ unsigned int h2u(h2f h){
  union { h2f h; unsigned int u; } v; v.h = h; return v.u;
}
__device__ __forceinline__ unsigned int pack2(float a, float b){
  h2f h; h.x = (_Float16)a; h.y = (_Float16)b;
  union { h2f h; unsigned int u; } v; v.h = h; return v.u;
}
__device__ __forceinline__ unsigned short f16b(float a){
  union { _Float16 h; unsigned short u; } v; v.h = (_Float16)a; return v.u;
}
__device__ __forceinline__ float dot2(unsigned int w, h2f x, float acc){
#if __has_builtin(__builtin_amdgcn_fdot2)
  return __builtin_amdgcn_fdot2(u2h(w), x, acc, false);
#else
  h2f c = u2h(w);
  return acc + (float)(c.x) * (float)(x.x) + (float)(c.y) * (float)(x.y);
#endif
}
// packed f16 lerp: a + t*(b-a)
__device__ __forceinline__ unsigned int lerp2(unsigned int a, unsigned int b, h2f t){
  h2f ha = u2h(a), hb = u2h(b);
  return h2u(ha + t * (hb - ha));
}

// jax.nn.gelu default (approximate=True): 0.5x(1+tanh(t)) == x*sigmoid(2t)
__device__ __forceinline__ float geluf(float x){
  float t = 0.7978845608028654f * x * (1.0f + 0.044715f * x * x);
  return x / (1.0f + __expf(-2.0f * t));
}

struct TEnt { const float* src; float* dst; int R; int C; int trans; };
struct TTab { TEnt e[8]; };
struct PEnt { const float* src; unsigned int* dst; int R; int C; };
struct PTab { PEnt e[4]; };

__device__ __forceinline__ void lut_basis(int ent, float* b){
  float len = fmaxf((float)ent * (1.7321f / (float)(NT - 1)), 1e-6f);
  float sc = 3.1622776601683795f / fmaxf(len, 1e-6f);  // sqrt(2/MAXR)*sqrt(B)/r
#pragma unroll
  for (int k = 0; k < 10; k++)
    b[k] = sinf((float)(k + 1) * 1.5707963267948966f * len) * sc;
}

// ---------------- merged weight prep ----------------------------------------
// blocks: [0,6) convw, 6 = f16-pair pack (pk), [7,7+2NT) layer LUT, rest init LUT
// pk per layer (uints): dw1T[32][96] @0, dw2[192][16] @3072 (6144 total)
__global__ __launch_bounds__(384) void prep_k(
    TTab tb, PTab pt,
    const float* __restrict__ fABw1, const float* __restrict__ fABw2,
    const float* __restrict__ fCw1,  const float* __restrict__ fCw2,
    unsigned short* __restrict__ lutH,
    const float* __restrict__ f01w1, const float* __restrict__ f01w2,
    unsigned short* __restrict__ lut01H)
{
  int b = blockIdx.x;
  int t = threadIdx.x;
  if (b < 6){
    TEnt en = tb.e[b];
    int n = en.R * en.C;
    for (int i = t; i < n; i += 384){
      float v = en.src[i];
      if (en.trans){
        int r = i / en.C, c = i - r * en.C;
        en.dst[c * en.R + r] = v;
      } else {
        en.dst[i] = v;
      }
    }
    return;
  }
  if (b == 6){
    // pack fp32 [R][C] -> f16-pair uints [C][R/2]; 4 entries x 3072 uints
    for (int i = t; i < 12288; i += 384){
      int entry = i / 3072, w = i - entry * 3072;
      PEnt en = pt.e[entry];
      int half = en.R >> 1;
      int c = w / half, rp = w - c * half;
      en.dst[w] = pack2(en.src[(2*rp) * en.C + c], en.src[(2*rp + 1) * en.C + c]);
    }
    return;
  }
  if (b < 7 + 2*NT){
    int bb = b - 7;
    int ent = bb & (NT - 1);
    int layer = bb >> 11;       // NT = 2048
    float bas[10];
    lut_basis(ent, bas);
    __shared__ float h[192];
    if (t < 192){
      int f = t >> 6, l = t & 63;       // f: 0=A, 1=B, 2=C
      const float* w1 = (f < 2) ? (fABw1 + (layer*2 + f) * 640)
                                : (fCw1 + layer * 640);
      float a = 0.f;
#pragma unroll
      for (int k = 0; k < 10; k++) a += bas[k] * w1[k*64 + l];
      h[t] = geluf(a);
    }
    __syncthreads();
    float a = 0.f;
    if (t < 192){
      int f = t / 96, j = t - 96 * f;
      const float* w2 = fABw2 + (layer*2 + f) * 6144;
      for (int l = 0; l < 64; l++) a += h[f*64 + l] * w2[l*96 + j];
    } else {
      int j = t - 192;
      const float* w2 = fCw2 + layer * 12288;
      for (int l = 0; l < 64; l++) a += h[128 + l] * w2[l*192 + j];
    }
    lutH[((long)(layer * NT + ent)) * 384 + t] = f16b(a);
    return;
  }
  // init LUT: 6 entries per block (384 = 6*64 threads)
  int blk = b - 7 - 2*NT;
  int ent = blk * 6 + (t >> 6);
  if (ent >= NT) return;
  int tl = t & 63;
  int p = tl >> 5, jj = tl & 31;
  float bas[10];
  lut_basis(ent, bas);
  const float* w1 = f01w1 + p * 640;
  const float* w2 = f01w2 + p * 2048;
  float W = 0.f;
  for (int l = 0; l < 64; l++){
    float a = 0.f;
#pragma unroll
    for (int k = 0; k < 10; k++) a += bas[k] * w1[k*64 + l];
    W += geluf(a) * w2[l*32 + jj];
  }
  lut01H[(long)ent * 64 + tl] = f16b(W);
}

// ---------------- merged: edge degree count + node init ---------------------
__global__ __launch_bounds__(256) void countnode_k(
    const int* __restrict__ esrc, const int* __restrict__ edst,
    int* __restrict__ cntd, int* __restrict__ cnts,
    const int* __restrict__ az, const float* __restrict__ embedF,
    const float* __restrict__ w1T /*[32][8]*/, const float* __restrict__ w2T /*[32][32]*/,
    float* __restrict__ xn)
{
  if (blockIdx.x < NE/256){
    int e = blockIdx.x * 256 + threadIdx.x;
    atomicAdd(cntd + edst[e], 1);
    atomicAdd(cnts + esrc[e], 1);
    return;
  }
  int n = (blockIdx.x - NE/256) * 256 + threadIdx.x;
  if (n >= NN) return;
  int z = az[n];
  float ee[8];
#pragma unroll
  for (int k = 0; k < 8; k++) ee[k] = embedF[z * 8 + k];
  float hid[32];
#pragma unroll
  for (int l = 0; l < 32; l++){
    float a = 0.f;
#pragma unroll
    for (int k = 0; k < 8; k++) a += ee[k] * w1T[l * 8 + k];
    hid[l] = geluf(a);
  }
  float* row = xn + (long)n * 96;
#pragma unroll
  for (int j = 0; j < 32; j++){
    float a = 0.f;
#pragma unroll
    for (int l = 0; l < 32; l++) a += hid[l] * w2T[j * 32 + l];
    row[j] = a;
  }
#pragma unroll
  for (int j = 32; j < 96; j++) row[j] = 0.f;
}

// ---------------- both prefix sums in one launch ----------------------------
__global__ __launch_bounds__(1024) void prefix_k(
    const int* __restrict__ cntd, int* __restrict__ doff, int* __restrict__ curd,
    const int* __restrict__ cnts, int* __restrict__ soff, int* __restrict__ curs)
{
  const int* cnt = blockIdx.x ? cnts : cntd;
  int* off = blockIdx.x ? soff : doff;
  int* cur = blockIdx.x ? curs : curd;
  __shared__ int part[1024];
  int t = threadIdx.x;
  int base = t * 20;
  int s = 0;
  for (int i = 0; i < 20; i++){ int idx = base + i; if (idx < NN) s += cnt[idx]; }
  part[t] = s; __syncthreads();
  for (int d = 1; d < 1024; d <<= 1){
    int v = (t >= d) ? part[t - d] : 0;
    __syncthreads();
    part[t] += v;
    __syncthreads();
  }
  int run = (t == 0) ? 0 : part[t - 1];
  for (int i = 0; i < 20; i++){
    int idx = base + i;
    if (idx < NN){ off[idx] = run; cur[idx] = run; run += cnt[idx]; }
  }
  if (t == 0) off[NN] = NE;
}

// p = dst-sorted slot of edge e; q = src-sorted slot; qpos[p]=q, sinc[q]=p
__global__ void fill_comb(const int* __restrict__ esrc, const int* __restrict__ edst,
                          int* __restrict__ curd, int* __restrict__ curs,
                          int* __restrict__ srcS, int* __restrict__ dstS,
                          int* __restrict__ qpos, int* __restrict__ sinc){
  int e = blockIdx.x * 256 + threadIdx.x;
  if (e >= NE) return;
  int s = esrc[e], d = edst[e];
  int p = atomicAdd(curd + d, 1);
  srcS[p] = s; dstS[p] = d;
  int q = atomicAdd(curs + s, 1);
  qpos[p] = q;
  sinc[q] = p;
}

// ---------------- edge init: p-row (dst side) + scattered q-row (src side) --
__global__ __launch_bounds__(256) void edge_init(
    const float* __restrict__ pos, const int* __restrict__ srcS,
    const int* __restrict__ dstS, const int* __restrict__ qpos,
    float* __restrict__ els,
    unsigned short* __restrict__ pbuf0, unsigned short* __restrict__ qbuf0,
    const float* __restrict__ w1T /*dl1w1T [32][4]*/, const float* __restrict__ w2T /*[32][32]*/,
    const unsigned int* __restrict__ lut01)
{
  int p = blockIdx.x * 256 + threadIdx.x;
  if (p >= NE) return;
  int s = srcS[p], d = dstS[p];
  float x = pos[s*3+0] - pos[d*3+0];
  float y = pos[s*3+1] - pos[d*3+1];
  float z = pos[s*3+2] - pos[d*3+2];
  float L = sqrtf(x*x + y*y + z*z + 1e-12f);
  float iv = 1.0f / fmaxf(L, 1e-6f);
  els[p] = L;

  float u = L - 2.0f;   // 2*(len/MAXR - 1), MAXR=2
  float cut = 0.5f * (1.0f - cosf(3.14159265358979323f * u));
  cut = (u > 0.0f) ? 0.0f : cut;
  cut = (u < -1.0f) ? 1.0f : cut;
  float xe0 = cut, cc = cut * 1.7320508075688772f * iv;
  float xe1 = cc*x, xe2 = cc*y, xe3 = cc*z;
  float hid[32];
#pragma unroll
  for (int l = 0; l < 32; l++){
    float a = xe0*w1T[l*4+0] + xe1*w1T[l*4+1] + xe2*w1T[l*4+2] + xe3*w1T[l*4+3];
    hid[l] = geluf(a);
  }
  float xeh[32];
#pragma unroll
  for (int j = 0; j < 32; j++){
    float a = 0.f;
#pragma unroll
    for (int l = 0; l < 32; l++) a += hid[l] * w2T[j*32 + l];
    xeh[j] = a;
  }
  float tt = fminf(L * ((float)(NT-1) / 1.7321f), (float)(NT-1) - 0.001f);
  int i0 = (int)tt; float tfv = tt - (float)i0;
  h2f tf2; tf2.x = (_Float16)tfv; tf2.y = tf2.x;
  h2f h05; h05.x = (_Float16)0.5f; h05.y = h05.x;
  const unsigned int* rA = lut01 + i0 * 32;
  const unsigned int* rB = rA + 32;

  unsigned int xp[16];
#pragma unroll
  for (int jp = 0; jp < 16; jp++)
    xp[jp] = pack2(xeh[2*jp] * 0.0625f, xeh[2*jp+1] * 0.0625f);

  unsigned int du[16], au[16];
#pragma unroll
  for (int q = 0; q < 4; q++){
    uint4 a = ((const uint4*)rA)[q];
    uint4 b = ((const uint4*)rB)[q];
    du[4*q+0] = h2u(u2h(lerp2(a.x, b.x, tf2)) * u2h(xp[4*q+0]));
    du[4*q+1] = h2u(u2h(lerp2(a.y, b.y, tf2)) * u2h(xp[4*q+1]));
    du[4*q+2] = h2u(u2h(lerp2(a.z, b.z, tf2)) * u2h(xp[4*q+2]));
    du[4*q+3] = h2u(u2h(lerp2(a.w, b.w, tf2)) * u2h(xp[4*q+3]));
  }
#pragma unroll
  for (int q = 0; q < 4; q++){
    uint4 a = ((const uint4*)(rA + 16))[q];
    uint4 b = ((const uint4*)(rB + 16))[q];
    au[4*q+0] = h2u(u2h(lerp2(a.x, b.x, tf2)) * u2h(xp[4*q+0]) * h05);
    au[4*q+1] = h2u(u2h(lerp2(a.y, b.y, tf2)) * u2h(xp[4*q+1]) * h05);
    au[4*q+2] = h2u(u2h(lerp2(a.z, b.z, tf2)) * u2h(xp[4*q+2]) * h05);
    au[4*q+3] = h2u(u2h(lerp2(a.w, b.w, tf2)) * u2h(xp[4*q+3]) * h05);
  }
  unsigned short* prow = pbuf0 + (long)p * 64;
  unsigned short* qrow = qbuf0 + (long)qpos[p] * 64;
#pragma unroll
  for (int q = 0; q < 4; q++){
    ((uint4*)prow)[q]      = ((uint4*)du)[q];
    ((uint4*)(prow+32))[q] = ((uint4*)au)[q];
  }
  unsigned int nd[16];
#pragma unroll
  for (int i = 0; i < 16; i++) nd[i] = du[i] ^ 0x80008000u;  // negate packed f16
#pragma unroll
  for (int q = 0; q < 4; q++){
    ((uint4*)qrow)[q]      = ((uint4*)nd)[q];
    ((uint4*)(qrow+32))[q] = ((uint4*)au)[q];
  }
}

// 4 nodes (4 waves) per 256-thread block; both roles stream contiguous rows;
// also packs the node's xnh f16 row
__global__ __launch_bounds__(256) void gather_init(
    const int* __restrict__ doff, const int* __restrict__ soff,
    const unsigned short* __restrict__ pbuf0, const unsigned short* __restrict__ qbuf0,
    float* __restrict__ xn, unsigned int* __restrict__ xnh)
{
  int n = blockIdx.x * 4 + (threadIdx.x >> 6);
  int c = threadIdx.x & 63;          // lane == c
  if (n >= NN) return;
  const _Float16* ph = (const _Float16*)pbuf0;
  const _Float16* qh = (const _Float16*)qbuf0;
  float acc = 0.f;
  int d1 = doff[n+1];
  for (int p = doff[n]; p < d1; p++) acc += (float)ph[(long)p * 64 + c];
  int s1 = soff[n+1];
  for (int q = soff[n]; q < s1; q++) acc += (float)qh[(long)q * 64 + c];
  float v = 16.f * acc;              // cols 32..95 (cols were zero)
  xn[(long)n * 96 + 32 + c] = v;
  float other = __shfl_xor(v, 1);
  if (!(c & 1)) xnh[n * 48 + 16 + (c >> 1)] = pack2(v, other);
  if (c < 16){
    float a = xn[(long)n * 96 + 2*c];
    float b = xn[(long)n * 96 + 2*c + 1];
    xnh[n * 48 + c] = pack2(a, b);
  }
}

// ---------------- conv layer: f16 node rows, LDS weights, LUT filters -------
// p-row (dst, 96 h) -> pbuf[p]; q-row (src, 96 h) -> qbuf[p] (both contiguous)
// stored value = true/64 (undone in gather_upd)
// pk layout per layer (uints): dw1T[32][96] @0, dw2[192][16] @3072 (6144 total)
// lut row per entry (uints):   WaPairs[48] | WbPairs[48] | WcPairs[96] (192)
__global__ __launch_bounds__(256, 4) void layer_k(
    const int* __restrict__ srcS, const int* __restrict__ dstS,
    const float* __restrict__ els, const unsigned int* __restrict__ xnh,
    unsigned short* __restrict__ pbuf, unsigned short* __restrict__ qbuf,
    const unsigned int* __restrict__ lut, const unsigned int* __restrict__ pk)
{
  __shared__ uint4 lw4[1536];          // 24 KB: dw1T + dw2
  unsigned int* lw = (unsigned int*)lw4;
  int t = threadIdx.x;
  {
    const uint4* s4 = (const uint4*)pk;
    for (int i = t; i < 1536; i += 256) lw4[i] = s4[i];
  }
  __syncthreads();
  int p = blockIdx.x * 256 + t;        // grid = NE/256 exact

  const unsigned int* dw1T = lw;          // [32][96]
  const unsigned int* dw2  = lw + 3072;   // [192][16]

  int s = srcS[p], d = dstS[p];
  float L = els[p];
  float tt = fminf(L * ((float)(NT-1) / 1.7321f), (float)(NT-1) - 0.001f);
  int i0 = (int)tt; float tfv = tt - (float)i0;
  h2f tf2; tf2.x = (_Float16)tfv; tf2.y = tf2.x;
  const unsigned int* rA = lut + (long)i0 * 192;
  const unsigned int* rB = rA + 192;

  const unsigned int* xsh = xnh + s * 48;   // f16 row, 192B
  const unsigned int* xdh = xnh + d * 48;   // sorted: shared across ~16 lanes
  h2f c32; c32.x = (_Float16)0.03125f;  c32.y = c32.x;
  h2f c64; c64.x = (_Float16)0.015625f; c64.y = c64.x;

  float hd[32];
#pragma unroll
  for (int l = 0; l < 32; l++) hd[l] = 0.f;

  // ---- merged A(grad)/B(ave) pass: hd += dw1T^T @ [Wa*(xd-xs); Wb*(xd+xs)/2]
  // g packed at 1/32 scale -> hd holds true/32
  for (int jc = 0; jc < 96; jc += 8){
    int jh = jc >> 1;
    uint4 xsu = *(const uint4*)(xsh + jh);
    uint4 xdu = *(const uint4*)(xdh + jh);
    uint4 aA = *(const uint4*)(rA + jh);
    uint4 bA = *(const uint4*)(rB + jh);
    uint4 aB = *(const uint4*)(rA + 48 + jh);
    uint4 bB = *(const uint4*)(rB + 48 + jh);
    unsigned int xsa[4] = {xsu.x, xsu.y, xsu.z, xsu.w};
    unsigned int xda[4] = {xdu.x, xdu.y, xdu.z, xdu.w};
    unsigned int wA[4] = {lerp2(aA.x,bA.x,tf2), lerp2(aA.y,bA.y,tf2),
                          lerp2(aA.z,bA.z,tf2), lerp2(aA.w,bA.w,tf2)};
    unsigned int wB[4] = {lerp2(aB.x,bB.x,tf2), lerp2(aB.y,bB.y,tf2),
                          lerp2(aB.z,bB.z,tf2), lerp2(aB.w,bB.w,tf2)};
    h2f gpA[4], gpB[4];
#pragma unroll
    for (int q = 0; q < 4; q++){
      h2f hs = u2h(xsa[q]), hdd = u2h(xda[q]);
      h2f dv2 = (hdd - hs) * c32;
      h2f av2 = (hdd + hs) * c64;
      gpA[q] = u2h(wA[q]) * dv2;
      gpB[q] = u2h(wB[q]) * av2;
    }
#pragma unroll
    for (int l = 0; l < 32; l++){
      uint4 w1 = *(const uint4*)(dw1T + l*96 + jh);
      uint4 w2 = *(const uint4*)(dw1T + l*96 + 48 + jh);
      float acc = hd[l];
      acc = dot2(w1.x, gpA[0], acc); acc = dot2(w1.y, gpA[1], acc);
      acc = dot2(w1.z, gpA[2], acc); acc = dot2(w1.w, gpA[3], acc);
      acc = dot2(w2.x, gpB[0], acc); acc = dot2(w2.y, gpB[1], acc);
      acc = dot2(w2.z, gpB[2], acc); acc = dot2(w2.w, gpB[3], acc);
      hd[l] = acc;
    }
  }

  // ---- hd gelu (undo 1/32), pack at 1/64 for output dots ----
  h2f hdp[16];
#pragma unroll
  for (int lp = 0; lp < 16; lp++){
    h2f r;
    r.x = (_Float16)(geluf(32.f*hd[2*lp])   * 0.015625f);
    r.y = (_Float16)(geluf(32.f*hd[2*lp+1]) * 0.015625f);
    hdp[lp] = r;
  }

  // ---- output: dv = Wc[j]*d1, av = 0.5*Wc[96+j]*d2; rows at true/64 --------
  unsigned int* prow = (unsigned int*)(pbuf + (long)p * 96);
  unsigned int* qrow = (unsigned int*)(qbuf + (long)p * 96);
  for (int c0 = 0; c0 < 96; c0 += 32){
    unsigned int pu[16], qu[16];
#pragma unroll
    for (int q4 = 0; q4 < 4; q4++){
      int cb = 96 + (c0 >> 1) + 4*q4;
      uint4 a1 = *(const uint4*)(rA + cb);
      uint4 b1 = *(const uint4*)(rB + cb);
      uint4 a2 = *(const uint4*)(rA + cb + 48);
      uint4 b2 = *(const uint4*)(rB + cb + 48);
      unsigned int c1l[4] = {lerp2(a1.x,b1.x,tf2), lerp2(a1.y,b1.y,tf2),
                             lerp2(a1.z,b1.z,tf2), lerp2(a1.w,b1.w,tf2)};
      unsigned int c2l[4] = {lerp2(a2.x,b2.x,tf2), lerp2(a2.y,b2.y,tf2),
                             lerp2(a2.z,b2.z,tf2), lerp2(a2.w,b2.w,tf2)};
#pragma unroll
      for (int r4 = 0; r4 < 4; r4++){
        int jp = 4*q4 + r4;
        h2f c1h = u2h(c1l[r4]);
        h2f c2h = u2h(c2l[r4]);
        float pv2[2], qv2[2];
#pragma unroll
        for (int w = 0; w < 2; w++){
          int j = c0 + 2*jp + w;
          float d1 = 0.f, d2 = 0.f;
          const uint4* r1 = (const uint4*)(dw2 + j*16);
          const uint4* r2 = (const uint4*)(dw2 + (96+j)*16);
#pragma unroll
          for (int q = 0; q < 4; q++){
            uint4 wa = r1[q], wb = r2[q];
            d1 = dot2(wa.x, hdp[4*q+0], d1); d1 = dot2(wa.y, hdp[4*q+1], d1);
            d1 = dot2(wa.z, hdp[4*q+2], d1); d1 = dot2(wa.w, hdp[4*q+3], d1);
            d2 = dot2(wb.x, hdp[4*q+0], d2); d2 = dot2(wb.y, hdp[4*q+1], d2);
            d2 = dot2(wb.z, hdp[4*q+2], d2); d2 = dot2(wb.w, hdp[4*q+3], d2);
          }
          float c1 = w ? (float)c1h.y : (float)c1h.x;
          float c2 = w ? (float)c2h.y : (float)c2h.x;
          float dv = c1 * d1;           // true/64
          float av = 0.5f * c2 * d2;    // true/64
          pv2[w] = dv + av;
          qv2[w] = av - dv;
        }
        pu[jp] = pack2(pv2[0], pv2[1]);
        qu[jp] = pack2(qv2[0], qv2[1]);
      }
    }
    int uo = c0 >> 1;
#pragma unroll
    for (int q = 0; q < 4; q++){
      *(uint4*)(prow + uo + 4*q) = ((uint4*)pu)[q];
      *(uint4*)(qrow + uo + 4*q) = ((uint4*)qu)[q];
    }
  }
}

// fused gather + node update + xnh repack; 5 nodes per 512-thread block
__global__ __launch_bounds__(512) void gather_upd(
    const int* __restrict__ doff, const int* __restrict__ soff,
    const int* __restrict__ sinc,
    const unsigned short* __restrict__ pbuf, const unsigned short* __restrict__ qbuf,
    float* __restrict__ xn, unsigned int* __restrict__ xnh)
{
  int g = threadIdx.x / 96;
  int c = threadIdx.x - 96 * g;
  if (g >= 5) return;
  int n = blockIdx.x * 5 + g;
  if (n >= NN) return;
  const _Float16* ph = (const _Float16*)pbuf;
  const _Float16* qh = (const _Float16*)qbuf;
  float acc = 0.f;
  int d1 = doff[n+1];
  for (int p = doff[n]; p < d1; p++) acc += (float)ph[(long)p * 96 + c];
  int s1 = soff[n+1];
  for (int ii = soff[n]; ii < s1; ii++){
    int p = sinc[ii];
    acc += (float)qh[(long)p * 96 + c];
  }
  long idx = (long)n * 96 + c;
  float x = xn[idx] - 6.4f * acc;     // 0.1 step * 64 msg scale
  xn[idx] = x;
  float other = __shfl_xor(x, 1);
  if (!(c & 1)) xnh[n * 48 + (c >> 1)] = pack2(x, other);
}

// ---------------- column sum over nodes -------------------------------------
__global__ void colsum(const float* __restrict__ xn, float* __restrict__ nodesum){
  int col = threadIdx.x % 96;
  int seg = threadIdx.x / 96;
  int stripe = blockIdx.x * 2 + seg;   // 0..399
  float acc = 0.f;
  for (int n = stripe; n < NN; n += 400) acc += xn[(long)n * 96 + col];
  unsafeAtomicAdd(nodesum + col, acc);
}

// ---------------- project to 16 outputs, scale, fp32 store ------------------
__global__ void project(const float* __restrict__ nodesum, const float* __restrict__ siT,
                        float* __restrict__ out){
  int j = threadIdx.x;
  if (j < 16){
    float a = 0.f;
#pragma unroll
    for (int c = 0; c < 96; c++) a += nodesum[c] * siT[j*96 + c];
    out[j] = a * 0.007071067811865475f;   // 1/sqrt(20000)
  }
}

// ---------------- host side -------------------------------------------------
extern "C" void kernel_launch(void* const* d_in, const int* in_sizes, int n_in,
                              void* d_out, int out_size, void* d_ws, size_t ws_size,
                              hipStream_t stream){
  const float* pos  = (const float*)d_in[0];
  const int* atom_z = (const int*)d_in[1];
  const int* esrc   = (const int*)d_in[2];
  const int* edst   = (const int*)d_in[3];

  float* ws      = (float*)d_ws;
  float* xn      = ws;                  // 1,920,000
  float* nodesum = ws + 1920000;        // 96
  float* WB      = ws + 1920096;        // 4,128 fp32 weights
  unsigned int* pk    = (unsigned int*)(ws + 1924224);  // 12,288
  unsigned int* lutL  = (unsigned int*)(ws + 1936512);  // 786,432 (3 MB)
  unsigned int* lut01 = (unsigned int*)(ws + 2722944);  // 65,536
  unsigned int* xnh   = (unsigned int*)(ws + 2788480);  // 960,000 (f16 rows)
  float* els    = ws + 3748480;                 // 320,000 edge lengths
  int*   cntd   = (int*)(ws + 4068480);         // 20,000
  int*   cnts   = cntd + 20000;                 // 20,000 (contiguous for 1 memset)
  int*   curd   = cnts + 20000;                 // 20,000
  int*   curs   = curd + 20000;                 // 20,000
  int*   doff   = curs + 20000;                 // 20,004
  int*   soff   = doff + 20004;                 // 20,004  -> ends 4,188,488
  int*   srcS   = soff + 20004;                 // 320,000 -> ends 4,508,488
  int*   dstS   = srcS + 320000;                // 320,000 -> ends 4,828,488
  int*   qpos   = dstS + 320000;                // 320,000 -> ends 5,148,488
  int*   sinc   = qpos + 320000;                // 320,000 -> ends 5,468,488
  // *** ROUND 8/9 VALUE-BUG FIX ***: pbufL/qbufL are NE*96 HALVES =
  // 15,360,000 FLOATS each (not 7.68M — halves/floats slip). r8/r9 put qbufL
  // at +13,148,496 -> q-rows aliased p-rows of edges p+160,000 -> identical
  // absmax in both rounds regardless of layer_k implementation.
  // Correct layout (floats):
  //   pbufL: [ 5,468,496 .. 20,828,496)   qbufL: [20,828,496 .. 36,188,496)
  //   pbuf0: [ 5,468,496 .. 15,708,496)   qbuf0: [15,708,496 .. 25,948,496)
  // (init aliases layer space CROSS-PHASE only; init-phase disjoint.)
  // end = 36,188,496 floats = 144.8 MB <= 151.2 MB proven ws (r3 WRITE_SIZE).
  unsigned short* pbufL = (unsigned short*)(ws + 5468496);
  unsigned short* qbufL = (unsigned short*)(ws + 20828496);
  unsigned short* pbuf0 = (unsigned short*)(ws + 5468496);
  unsigned short* qbuf0 = (unsigned short*)(ws + 15708496);

  float* embedF = WB + 0;        // 160
  float* dl0w1T = WB + 160;      // 256   [32][8]
  float* dl0w2T = WB + 416;      // 1024  [32][32]
  float* dl1w1T = WB + 1440;     // 128   [32][4]
  float* dl1w2T = WB + 1568;     // 1024  [32][32]
  float* siT    = WB + 2592;     // 1536  [16][96]

  hipMemsetAsync(cntd, 0, 40000 * 4, stream);
  hipMemsetAsync(nodesum, 0, 96 * 4, stream);

  TTab tb;
  int ti = 0;
  auto add = [&](const void* s, float* dst, int R, int C, int tr){
    tb.e[ti].src = (const float*)s; tb.e[ti].dst = dst;
    tb.e[ti].R = R; tb.e[ti].C = C; tb.e[ti].trans = tr; ti++;
  };
  add(d_in[4],  embedF, 20, 8, 0);
  add(d_in[5],  dl0w1T, 8, 32, 1);
  add(d_in[6],  dl0w2T, 32, 32, 1);
  add(d_in[7],  dl1w1T, 4, 32, 1);
  add(d_in[8],  dl1w2T, 32, 32, 1);
  add(d_in[17], siT, 96, 16, 1);

  PTab pt;
  int pi = 0;
  auto padd = [&](const void* s, unsigned int* dst, int R, int C){
    pt.e[pi].src = (const float*)s; pt.e[pi].dst = dst;
    pt.e[pi].R = R; pt.e[pi].C = C; pi++;
  };
  for (int i = 0; i < 2; i++){
    padd((const float*)d_in[15] + i*6144, pk + i*6144 + 0,    192, 32);  // dw1T [32][96]
    padd((const float*)d_in[16] + i*6144, pk + i*6144 + 3072, 32, 192);  // dw2  [192][16]
  }

  // weight prep (convw + pk pack + both LUTs) in one launch
  prep_k<<<7 + 2*NT + (NT + 5)/6, 384, 0, stream>>>(
      tb, pt, (const float*)d_in[11], (const float*)d_in[12],
      (const float*)d_in[13], (const float*)d_in[14], (unsigned short*)lutL,
      (const float*)d_in[9], (const float*)d_in[10], (unsigned short*)lut01);
  countnode_k<<<NE/256 + (NN + 255)/256, 256, 0, stream>>>(
      esrc, edst, cntd, cnts, atom_z, embedF, dl0w1T, dl0w2T, xn);
  prefix_k<<<2, 1024, 0, stream>>>(cntd, doff, curd, cnts, soff, curs);
  fill_comb<<<(NE + 255)/256, 256, 0, stream>>>(esrc, edst, curd, curs,
                                                srcS, dstS, qpos, sinc);
  edge_init<<<(NE + 255)/256, 256, 0, stream>>>(
      pos, srcS, dstS, qpos, els, pbuf0, qbuf0, dl1w1T, dl1w2T, lut01);
  gather_init<<<(NN + 3)/4, 256, 0, stream>>>(doff, soff, pbuf0, qbuf0, xn, xnh);

  for (int i = 0; i < 2; i++){
    layer_k<<<NE/256, 256, 0, stream>>>(
        srcS, dstS, els, xnh, pbufL, qbufL,
        lutL + (long)i * NT * 192, pk + i*6144);
    gather_upd<<<(NN + 4)/5, 512, 0, stream>>>(doff, soff, sinc, pbufL, qbufL,
                                               xn, xnh);
  }
  colsum<<<200, 192, 0, stream>>>(xn, nodesum);
  project<<<1, 64, 0, stream>>>(nodesum, siT, (float*)d_out);
}

// Round 11
// 848.158 us; speedup vs baseline: 1.2044x; 1.0498x over previous
//
#include <hip/hip_runtime.h>
#include <hip/hip_bf16.h>

#define NN 20000
#define NE 320000
#define NT 2048            // filter LUT entries over len in [0, 1.7321]

typedef _Float16 h2f __attribute__((ext_vector_type(2)));

__device__ __forceinline__ h2f u2h(unsigned int u){
  union { unsigned int u; h2f h; } v; v.u = u; return v.h;
}
__device__ __forceinline__ unsigned int h2u(h2f h){
  union { h2f h; unsigned int u; } v; v.h = h; return v.u;
}
__device__ __forceinline__ unsigned int pack2(float a, float b){
  h2f h; h.x = (_Float16)a; h.y = (_Float16)b;
  union { h2f h; unsigned int u; } v; v.h = h; return v.u;
}
__device__ __forceinline__ unsigned short f16b(float a){
  union { _Float16 h; unsigned short u; } v; v.h = (_Float16)a; return v.u;
}
__device__ __forceinline__ float dot2(unsigned int w, h2f x, float acc){
#if __has_builtin(__builtin_amdgcn_fdot2)
  return __builtin_amdgcn_fdot2(u2h(w), x, acc, false);
#else
  h2f c = u2h(w);
  return acc + (float)(c.x) * (float)(x.x) + (float)(c.y) * (float)(x.y);
#endif
}
// packed f16 lerp: a + t*(b-a)
__device__ __forceinline__ unsigned int lerp2(unsigned int a, unsigned int b, h2f t){
  h2f ha = u2h(a), hb = u2h(b);
  return h2u(ha + t * (hb - ha));
}

// jax.nn.gelu default (approximate=True): 0.5x(1+tanh(t)) == x*sigmoid(2t)
__device__ __forceinline__ float geluf(float x){
  float t = 0.7978845608028654f * x * (1.0f + 0.044715f * x * x);
  return x / (1.0f + __expf(-2.0f * t));
}

struct TEnt { const float* src; float* dst; int R; int C; int trans; };
struct TTab { TEnt e[8]; };
struct PEnt { const float* src; unsigned int* dst; int R; int C; };
struct PTab { PEnt e[4]; };

__device__ __forceinline__ void lut_basis(int ent, float* b){
  float len = fmaxf((float)ent * (1.7321f / (float)(NT - 1)), 1e-6f);
  float sc = 3.1622776601683795f / fmaxf(len, 1e-6f);  // sqrt(2/MAXR)*sqrt(B)/r
#pragma unroll
  for (int k = 0; k < 10; k++)
    b[k] = sinf((float)(k + 1) * 1.5707963267948966f * len) * sc;
}

// ---------------- merged weight prep ----------------------------------------
// blocks: [0,6) convw, 6 = f16-pair pack (pk), [7,7+2NT) layer LUT, rest init LUT
// pk per layer (uints): dw1T[32][96] @0, dw2[192][16] @3072 (6144 total)
__global__ __launch_bounds__(384) void prep_k(
    TTab tb, PTab pt,
    const float* __restrict__ fABw1, const float* __restrict__ fABw2,
    const float* __restrict__ fCw1,  const float* __restrict__ fCw2,
    unsigned short* __restrict__ lutH,
    const float* __restrict__ f01w1, const float* __restrict__ f01w2,
    unsigned short* __restrict__ lut01H)
{
  int b = blockIdx.x;
  int t = threadIdx.x;
  if (b < 6){
    TEnt en = tb.e[b];
    int n = en.R * en.C;
    for (int i = t; i < n; i += 384){
      float v = en.src[i];
      if (en.trans){
        int r = i / en.C, c = i - r * en.C;
        en.dst[c * en.R + r] = v;
      } else {
        en.dst[i] = v;
      }
    }
    return;
  }
  if (b == 6){
    // pack fp32 [R][C] -> f16-pair uints [C][R/2]; 4 entries x 3072 uints
    for (int i = t; i < 12288; i += 384){
      int entry = i / 3072, w = i - entry * 3072;
      PEnt en = pt.e[entry];
      int half = en.R >> 1;
      int c = w / half, rp = w - c * half;
      en.dst[w] = pack2(en.src[(2*rp) * en.C + c], en.src[(2*rp + 1) * en.C + c]);
    }
    return;
  }
  if (b < 7 + 2*NT){
    int bb = b - 7;
    int ent = bb & (NT - 1);
    int layer = bb >> 11;       // NT = 2048
    float bas[10];
    lut_basis(ent, bas);
    __shared__ float h[192];
    if (t < 192){
      int f = t >> 6, l = t & 63;       // f: 0=A, 1=B, 2=C
      const float* w1 = (f < 2) ? (fABw1 + (layer*2 + f) * 640)
                                : (fCw1 + layer * 640);
      float a = 0.f;
#pragma unroll
      for (int k = 0; k < 10; k++) a += bas[k] * w1[k*64 + l];
      h[t] = geluf(a);
    }
    __syncthreads();
    float a = 0.f;
    if (t < 192){
      int f = t / 96, j = t - 96 * f;
      const float* w2 = fABw2 + (layer*2 + f) * 6144;
      for (int l = 0; l < 64; l++) a += h[f*64 + l] * w2[l*96 + j];
    } else {
      int j = t - 192;
      const float* w2 = fCw2 + layer * 12288;
      for (int l = 0; l < 64; l++) a += h[128 + l] * w2[l*192 + j];
    }
    lutH[((long)(layer * NT + ent)) * 384 + t] = f16b(a);
    return;
  }
  // init LUT: 6 entries per block (384 = 6*64 threads)
  int blk = b - 7 - 2*NT;
  int ent = blk * 6 + (t >> 6);
  if (ent >= NT) return;
  int tl = t & 63;
  int p = tl >> 5, jj = tl & 31;
  float bas[10];
  lut_basis(ent, bas);
  const float* w1 = f01w1 + p * 640;
  const float* w2 = f01w2 + p * 2048;
  float W = 0.f;
  for (int l = 0; l < 64; l++){
    float a = 0.f;
#pragma unroll
    for (int k = 0; k < 10; k++) a += bas[k] * w1[k*64 + l];
    W += geluf(a) * w2[l*32 + jj];
  }
  lut01H[(long)ent * 64 + tl] = f16b(W);
}

// ---------------- merged: edge degree count + node init ---------------------
__global__ __launch_bounds__(256) void countnode_k(
    const int* __restrict__ esrc, const int* __restrict__ edst,
    int* __restrict__ cntd, int* __restrict__ cnts,
    const int* __restrict__ az, const float* __restrict__ embedF,
    const float* __restrict__ w1T /*[32][8]*/, const float* __restrict__ w2T /*[32][32]*/,
    float* __restrict__ xn)
{
  if (blockIdx.x < NE/256){
    int e = blockIdx.x * 256 + threadIdx.x;
    atomicAdd(cntd + edst[e], 1);
    atomicAdd(cnts + esrc[e], 1);
    return;
  }
  int n = (blockIdx.x - NE/256) * 256 + threadIdx.x;
  if (n >= NN) return;
  int z = az[n];
  float ee[8];
#pragma unroll
  for (int k = 0; k < 8; k++) ee[k] = embedF[z * 8 + k];
  float hid[32];
#pragma unroll
  for (int l = 0; l < 32; l++){
    float a = 0.f;
#pragma unroll
    for (int k = 0; k < 8; k++) a += ee[k] * w1T[l * 8 + k];
    hid[l] = geluf(a);
  }
  float* row = xn + (long)n * 96;
#pragma unroll
  for (int j = 0; j < 32; j++){
    float a = 0.f;
#pragma unroll
    for (int l = 0; l < 32; l++) a += hid[l] * w2T[j * 32 + l];
    row[j] = a;
  }
#pragma unroll
  for (int j = 32; j < 96; j++) row[j] = 0.f;
}

// ---------------- both prefix sums in one launch ----------------------------
__global__ __launch_bounds__(1024) void prefix_k(
    const int* __restrict__ cntd, int* __restrict__ doff, int* __restrict__ curd,
    const int* __restrict__ cnts, int* __restrict__ soff, int* __restrict__ curs)
{
  const int* cnt = blockIdx.x ? cnts : cntd;
  int* off = blockIdx.x ? soff : doff;
  int* cur = blockIdx.x ? curs : curd;
  __shared__ int part[1024];
  int t = threadIdx.x;
  int base = t * 20;
  int s = 0;
  for (int i = 0; i < 20; i++){ int idx = base + i; if (idx < NN) s += cnt[idx]; }
  part[t] = s; __syncthreads();
  for (int d = 1; d < 1024; d <<= 1){
    int v = (t >= d) ? part[t - d] : 0;
    __syncthreads();
    part[t] += v;
    __syncthreads();
  }
  int run = (t == 0) ? 0 : part[t - 1];
  for (int i = 0; i < 20; i++){
    int idx = base + i;
    if (idx < NN){ off[idx] = run; cur[idx] = run; run += cnt[idx]; }
  }
  if (t == 0) off[NN] = NE;
}

// p = dst-sorted slot of edge e; q = src-sorted slot; qpos[p]=q
__global__ void fill_comb(const int* __restrict__ esrc, const int* __restrict__ edst,
                          int* __restrict__ curd, int* __restrict__ curs,
                          int* __restrict__ srcS, int* __restrict__ dstS,
                          int* __restrict__ qpos){
  int e = blockIdx.x * 256 + threadIdx.x;
  if (e >= NE) return;
  int s = esrc[e], d = edst[e];
  int p = atomicAdd(curd + d, 1);
  srcS[p] = s; dstS[p] = d;
  int q = atomicAdd(curs + s, 1);
  qpos[p] = q;
}

// ---------------- edge init: p-row (dst side) + scattered q-row (src side) --
__global__ __launch_bounds__(256) void edge_init(
    const float* __restrict__ pos, const int* __restrict__ srcS,
    const int* __restrict__ dstS, const int* __restrict__ qpos,
    float* __restrict__ els,
    unsigned short* __restrict__ pbuf0, unsigned short* __restrict__ qbuf0,
    const float* __restrict__ w1T /*dl1w1T [32][4]*/, const float* __restrict__ w2T /*[32][32]*/,
    const unsigned int* __restrict__ lut01)
{
  int p = blockIdx.x * 256 + threadIdx.x;
  if (p >= NE) return;
  int s = srcS[p], d = dstS[p];
  float x = pos[s*3+0] - pos[d*3+0];
  float y = pos[s*3+1] - pos[d*3+1];
  float z = pos[s*3+2] - pos[d*3+2];
  float L = sqrtf(x*x + y*y + z*z + 1e-12f);
  float iv = 1.0f / fmaxf(L, 1e-6f);
  els[p] = L;

  float u = L - 2.0f;   // 2*(len/MAXR - 1), MAXR=2
  float cut = 0.5f * (1.0f - cosf(3.14159265358979323f * u));
  cut = (u > 0.0f) ? 0.0f : cut;
  cut = (u < -1.0f) ? 1.0f : cut;
  float xe0 = cut, cc = cut * 1.7320508075688772f * iv;
  float xe1 = cc*x, xe2 = cc*y, xe3 = cc*z;
  float hid[32];
#pragma unroll
  for (int l = 0; l < 32; l++){
    float a = xe0*w1T[l*4+0] + xe1*w1T[l*4+1] + xe2*w1T[l*4+2] + xe3*w1T[l*4+3];
    hid[l] = geluf(a);
  }
  float xeh[32];
#pragma unroll
  for (int j = 0; j < 32; j++){
    float a = 0.f;
#pragma unroll
    for (int l = 0; l < 32; l++) a += hid[l] * w2T[j*32 + l];
    xeh[j] = a;
  }
  float tt = fminf(L * ((float)(NT-1) / 1.7321f), (float)(NT-1) - 0.001f);
  int i0 = (int)tt; float tfv = tt - (float)i0;
  h2f tf2; tf2.x = (_Float16)tfv; tf2.y = tf2.x;
  h2f h05; h05.x = (_Float16)0.5f; h05.y = h05.x;
  const unsigned int* rA = lut01 + i0 * 32;
  const unsigned int* rB = rA + 32;

  unsigned int xp[16];
#pragma unroll
  for (int jp = 0; jp < 16; jp++)
    xp[jp] = pack2(xeh[2*jp] * 0.0625f, xeh[2*jp+1] * 0.0625f);

  unsigned int du[16], au[16];
#pragma unroll
  for (int q = 0; q < 4; q++){
    uint4 a = ((const uint4*)rA)[q];
    uint4 b = ((const uint4*)rB)[q];
    du[4*q+0] = h2u(u2h(lerp2(a.x, b.x, tf2)) * u2h(xp[4*q+0]));
    du[4*q+1] = h2u(u2h(lerp2(a.y, b.y, tf2)) * u2h(xp[4*q+1]));
    du[4*q+2] = h2u(u2h(lerp2(a.z, b.z, tf2)) * u2h(xp[4*q+2]));
    du[4*q+3] = h2u(u2h(lerp2(a.w, b.w, tf2)) * u2h(xp[4*q+3]));
  }
#pragma unroll
  for (int q = 0; q < 4; q++){
    uint4 a = ((const uint4*)(rA + 16))[q];
    uint4 b = ((const uint4*)(rB + 16))[q];
    au[4*q+0] = h2u(u2h(lerp2(a.x, b.x, tf2)) * u2h(xp[4*q+0]) * h05);
    au[4*q+1] = h2u(u2h(lerp2(a.y, b.y, tf2)) * u2h(xp[4*q+1]) * h05);
    au[4*q+2] = h2u(u2h(lerp2(a.z, b.z, tf2)) * u2h(xp[4*q+2]) * h05);
    au[4*q+3] = h2u(u2h(lerp2(a.w, b.w, tf2)) * u2h(xp[4*q+3]) * h05);
  }
  unsigned short* prow = pbuf0 + (long)p * 64;
  unsigned short* qrow = qbuf0 + (long)qpos[p] * 64;
#pragma unroll
  for (int q = 0; q < 4; q++){
    ((uint4*)prow)[q]      = ((uint4*)du)[q];
    ((uint4*)(prow+32))[q] = ((uint4*)au)[q];
  }
  unsigned int nd[16];
#pragma unroll
  for (int i = 0; i < 16; i++) nd[i] = du[i] ^ 0x80008000u;  // negate packed f16
#pragma unroll
  for (int q = 0; q < 4; q++){
    ((uint4*)qrow)[q]      = ((uint4*)nd)[q];
    ((uint4*)(qrow+32))[q] = ((uint4*)au)[q];
  }
}

// 4 nodes (4 waves) per 256-thread block; both roles stream contiguous rows;
// also packs the node's xnh f16 row
__global__ __launch_bounds__(256) void gather_init(
    const int* __restrict__ doff, const int* __restrict__ soff,
    const unsigned short* __restrict__ pbuf0, const unsigned short* __restrict__ qbuf0,
    float* __restrict__ xn, unsigned int* __restrict__ xnh)
{
  int n = blockIdx.x * 4 + (threadIdx.x >> 6);
  int c = threadIdx.x & 63;          // lane == c
  if (n >= NN) return;
  const _Float16* ph = (const _Float16*)pbuf0;
  const _Float16* qh = (const _Float16*)qbuf0;
  float acc = 0.f;
  int d1 = doff[n+1];
  for (int p = doff[n]; p < d1; p++) acc += (float)ph[(long)p * 64 + c];
  int s1 = soff[n+1];
  for (int q = soff[n]; q < s1; q++) acc += (float)qh[(long)q * 64 + c];
  float v = 16.f * acc;              // cols 32..95 (cols were zero)
  xn[(long)n * 96 + 32 + c] = v;
  float other = __shfl_xor(v, 1);
  if (!(c & 1)) xnh[n * 48 + 16 + (c >> 1)] = pack2(v, other);
  if (c < 16){
    float a = xn[(long)n * 96 + 2*c];
    float b = xn[(long)n * 96 + 2*c + 1];
    xnh[n * 48 + c] = pack2(a, b);
  }
}

// ---------------- conv layer: f16 node rows, LDS weights, LUT filters -------
// p-row (dst, 96 h) -> pbuf[p]; q-row (src, 96 h) -> qbuf[qpos[p]] (scattered
// write so BOTH gather sides stream contiguously — r11 change)
// stored value = true/64 (undone in gather_upd)
// pk layout per layer (uints): dw1T[32][96] @0, dw2[192][16] @3072 (6144 total)
// lut row per entry (uints):   WaPairs[48] | WbPairs[48] | WcPairs[96] (192)
__global__ __launch_bounds__(256, 4) void layer_k(
    const int* __restrict__ srcS, const int* __restrict__ dstS,
    const int* __restrict__ qpos,
    const float* __restrict__ els, const unsigned int* __restrict__ xnh,
    unsigned short* __restrict__ pbuf, unsigned short* __restrict__ qbuf,
    const unsigned int* __restrict__ lut, const unsigned int* __restrict__ pk)
{
  __shared__ uint4 lw4[1536];          // 24 KB: dw1T + dw2
  unsigned int* lw = (unsigned int*)lw4;
  int t = threadIdx.x;
  {
    const uint4* s4 = (const uint4*)pk;
    for (int i = t; i < 1536; i += 256) lw4[i] = s4[i];
  }
  __syncthreads();
  int p = blockIdx.x * 256 + t;        // grid = NE/256 exact

  const unsigned int* dw1T = lw;          // [32][96]
  const unsigned int* dw2  = lw + 3072;   // [192][16]

  int s = srcS[p], d = dstS[p];
  float L = els[p];
  float tt = fminf(L * ((float)(NT-1) / 1.7321f), (float)(NT-1) - 0.001f);
  int i0 = (int)tt; float tfv = tt - (float)i0;
  h2f tf2; tf2.x = (_Float16)tfv; tf2.y = tf2.x;
  const unsigned int* rA = lut + (long)i0 * 192;
  const unsigned int* rB = rA + 192;

  const unsigned int* xsh = xnh + s * 48;   // f16 row, 192B
  const unsigned int* xdh = xnh + d * 48;   // sorted: shared across ~16 lanes
  h2f c32; c32.x = (_Float16)0.03125f;  c32.y = c32.x;
  h2f c64; c64.x = (_Float16)0.015625f; c64.y = c64.x;

  float hd[32];
#pragma unroll
  for (int l = 0; l < 32; l++) hd[l] = 0.f;

  // ---- merged A(grad)/B(ave) pass: hd += dw1T^T @ [Wa*(xd-xs); Wb*(xd+xs)/2]
  // g packed at 1/32 scale -> hd holds true/32
  for (int jc = 0; jc < 96; jc += 8){
    int jh = jc >> 1;
    uint4 xsu = *(const uint4*)(xsh + jh);
    uint4 xdu = *(const uint4*)(xdh + jh);
    uint4 aA = *(const uint4*)(rA + jh);
    uint4 bA = *(const uint4*)(rB + jh);
    uint4 aB = *(const uint4*)(rA + 48 + jh);
    uint4 bB = *(const uint4*)(rB + 48 + jh);
    unsigned int xsa[4] = {xsu.x, xsu.y, xsu.z, xsu.w};
    unsigned int xda[4] = {xdu.x, xdu.y, xdu.z, xdu.w};
    unsigned int wA[4] = {lerp2(aA.x,bA.x,tf2), lerp2(aA.y,bA.y,tf2),
                          lerp2(aA.z,bA.z,tf2), lerp2(aA.w,bA.w,tf2)};
    unsigned int wB[4] = {lerp2(aB.x,bB.x,tf2), lerp2(aB.y,bB.y,tf2),
                          lerp2(aB.z,bB.z,tf2), lerp2(aB.w,bB.w,tf2)};
    h2f gpA[4], gpB[4];
#pragma unroll
    for (int q = 0; q < 4; q++){
      h2f hs = u2h(xsa[q]), hdd = u2h(xda[q]);
      h2f dv2 = (hdd - hs) * c32;
      h2f av2 = (hdd + hs) * c64;
      gpA[q] = u2h(wA[q]) * dv2;
      gpB[q] = u2h(wB[q]) * av2;
    }
#pragma unroll
    for (int l = 0; l < 32; l++){
      uint4 w1 = *(const uint4*)(dw1T + l*96 + jh);
      uint4 w2 = *(const uint4*)(dw1T + l*96 + 48 + jh);
      float acc = hd[l];
      acc = dot2(w1.x, gpA[0], acc); acc = dot2(w1.y, gpA[1], acc);
      acc = dot2(w1.z, gpA[2], acc); acc = dot2(w1.w, gpA[3], acc);
      acc = dot2(w2.x, gpB[0], acc); acc = dot2(w2.y, gpB[1], acc);
      acc = dot2(w2.z, gpB[2], acc); acc = dot2(w2.w, gpB[3], acc);
      hd[l] = acc;
    }
  }

  // ---- hd gelu (undo 1/32), pack at 1/64 for output dots ----
  h2f hdp[16];
#pragma unroll
  for (int lp = 0; lp < 16; lp++){
    h2f r;
    r.x = (_Float16)(geluf(32.f*hd[2*lp])   * 0.015625f);
    r.y = (_Float16)(geluf(32.f*hd[2*lp+1]) * 0.015625f);
    hdp[lp] = r;
  }

  // ---- output: dv = Wc[j]*d1, av = 0.5*Wc[96+j]*d2; rows at true/64 --------
  unsigned int* prow = (unsigned int*)(pbuf + (long)p * 96);
  unsigned int* qrow = (unsigned int*)(qbuf + (long)qpos[p] * 96);
  for (int c0 = 0; c0 < 96; c0 += 32){
    unsigned int pu[16], qu[16];
#pragma unroll
    for (int q4 = 0; q4 < 4; q4++){
      int cb = 96 + (c0 >> 1) + 4*q4;
      uint4 a1 = *(const uint4*)(rA + cb);
      uint4 b1 = *(const uint4*)(rB + cb);
      uint4 a2 = *(const uint4*)(rA + cb + 48);
      uint4 b2 = *(const uint4*)(rB + cb + 48);
      unsigned int c1l[4] = {lerp2(a1.x,b1.x,tf2), lerp2(a1.y,b1.y,tf2),
                             lerp2(a1.z,b1.z,tf2), lerp2(a1.w,b1.w,tf2)};
      unsigned int c2l[4] = {lerp2(a2.x,b2.x,tf2), lerp2(a2.y,b2.y,tf2),
                             lerp2(a2.z,b2.z,tf2), lerp2(a2.w,b2.w,tf2)};
#pragma unroll
      for (int r4 = 0; r4 < 4; r4++){
        int jp = 4*q4 + r4;
        h2f c1h = u2h(c1l[r4]);
        h2f c2h = u2h(c2l[r4]);
        float pv2[2], qv2[2];
#pragma unroll
        for (int w = 0; w < 2; w++){
          int j = c0 + 2*jp + w;
          float d1 = 0.f, d2 = 0.f;
          const uint4* r1 = (const uint4*)(dw2 + j*16);
          const uint4* r2 = (const uint4*)(dw2 + (96+j)*16);
#pragma unroll
          for (int q = 0; q < 4; q++){
            uint4 wa = r1[q], wb = r2[q];
            d1 = dot2(wa.x, hdp[4*q+0], d1); d1 = dot2(wa.y, hdp[4*q+1], d1);
            d1 = dot2(wa.z, hdp[4*q+2], d1); d1 = dot2(wa.w, hdp[4*q+3], d1);
            d2 = dot2(wb.x, hdp[4*q+0], d2); d2 = dot2(wb.y, hdp[4*q+1], d2);
            d2 = dot2(wb.z, hdp[4*q+2], d2); d2 = dot2(wb.w, hdp[4*q+3], d2);
          }
          float c1 = w ? (float)c1h.y : (float)c1h.x;
          float c2 = w ? (float)c2h.y : (float)c2h.x;
          float dv = c1 * d1;           // true/64
          float av = 0.5f * c2 * d2;    // true/64
          pv2[w] = dv + av;
          qv2[w] = av - dv;
        }
        pu[jp] = pack2(pv2[0], pv2[1]);
        qu[jp] = pack2(qv2[0], qv2[1]);
      }
    }
    int uo = c0 >> 1;
#pragma unroll
    for (int q = 0; q < 4; q++){
      *(uint4*)(prow + uo + 4*q) = ((uint4*)pu)[q];
      *(uint4*)(qrow + uo + 4*q) = ((uint4*)qu)[q];
    }
  }
}

// fused gather + node update + xnh repack; 5 nodes per 512-thread block
// BOTH roles now stream contiguous sorted rows (q scattered at write time)
__global__ __launch_bounds__(512) void gather_upd(
    const int* __restrict__ doff, const int* __restrict__ soff,
    const unsigned short* __restrict__ pbuf, const unsigned short* __restrict__ qbuf,
    float* __restrict__ xn, unsigned int* __restrict__ xnh)
{
  int g = threadIdx.x / 96;
  int c = threadIdx.x - 96 * g;
  if (g >= 5) return;
  int n = blockIdx.x * 5 + g;
  if (n >= NN) return;
  const _Float16* ph = (const _Float16*)pbuf;
  const _Float16* qh = (const _Float16*)qbuf;
  float acc = 0.f;
  int d1 = doff[n+1];
  for (int p = doff[n]; p < d1; p++) acc += (float)ph[(long)p * 96 + c];
  int s1 = soff[n+1];
  for (int q = soff[n]; q < s1; q++) acc += (float)qh[(long)q * 96 + c];
  long idx = (long)n * 96 + c;
  float x = xn[idx] - 6.4f * acc;     // 0.1 step * 64 msg scale
  xn[idx] = x;
  float other = __shfl_xor(x, 1);
  if (!(c & 1)) xnh[n * 48 + (c >> 1)] = pack2(x, other);
}

// ---------------- column sum over nodes -------------------------------------
__global__ void colsum(const float* __restrict__ xn, float* __restrict__ nodesum){
  int col = threadIdx.x % 96;
  int seg = threadIdx.x / 96;
  int stripe = blockIdx.x * 2 + seg;   // 0..399
  float acc = 0.f;
  for (int n = stripe; n < NN; n += 400) acc += xn[(long)n * 96 + col];
  unsafeAtomicAdd(nodesum + col, acc);
}

// ---------------- project to 16 outputs, scale, fp32 store ------------------
__global__ void project(const float* __restrict__ nodesum, const float* __restrict__ siT,
                        float* __restrict__ out){
  int j = threadIdx.x;
  if (j < 16){
    float a = 0.f;
#pragma unroll
    for (int c = 0; c < 96; c++) a += nodesum[c] * siT[j*96 + c];
    out[j] = a * 0.007071067811865475f;   // 1/sqrt(20000)
  }
}

// ---------------- host side -------------------------------------------------
extern "C" void kernel_launch(void* const* d_in, const int* in_sizes, int n_in,
                              void* d_out, int out_size, void* d_ws, size_t ws_size,
                              hipStream_t stream){
  const float* pos  = (const float*)d_in[0];
  const int* atom_z = (const int*)d_in[1];
  const int* esrc   = (const int*)d_in[2];
  const int* edst   = (const int*)d_in[3];

  float* ws      = (float*)d_ws;
  float* xn      = ws;                  // 1,920,000
  float* nodesum = ws + 1920000;        // 96
  float* WB      = ws + 1920096;        // 4,128 fp32 weights
  unsigned int* pk    = (unsigned int*)(ws + 1924224);  // 12,288
  unsigned int* lutL  = (unsigned int*)(ws + 1936512);  // 786,432 (3 MB)
  unsigned int* lut01 = (unsigned int*)(ws + 2722944);  // 65,536
  unsigned int* xnh   = (unsigned int*)(ws + 2788480);  // 960,000 (f16 rows)
  float* els    = ws + 3748480;                 // 320,000 edge lengths
  int*   cntd   = (int*)(ws + 4068480);         // 20,000
  int*   cnts   = cntd + 20000;                 // 20,000 (contiguous for 1 memset)
  int*   curd   = cnts + 20000;                 // 20,000
  int*   curs   = curd + 20000;                 // 20,000
  int*   doff   = curs + 20000;                 // 20,004
  int*   soff   = doff + 20004;                 // 20,004  -> ends 4,188,488
  int*   srcS   = soff + 20004;                 // 320,000 -> ends 4,508,488
  int*   dstS   = srcS + 320000;                // 320,000 -> ends 4,828,488
  int*   qpos   = dstS + 320000;                // 320,000 -> ends 5,148,488
  int*   sinc   = qpos + 320000;                // 320,000 -> ends 5,468,488 (UNUSED r11; kept for layout stability)
  (void)sinc;
  // layout identical to passing round 10:
  //   pbufL: [ 5,468,496 .. 20,828,496)   qbufL: [20,828,496 .. 36,188,496)
  //   pbuf0: [ 5,468,496 .. 15,708,496)   qbuf0: [15,708,496 .. 25,948,496)
  // (init aliases layer space CROSS-PHASE only; init-phase disjoint.)
  // end = 36,188,496 floats = 144.8 MB
  unsigned short* pbufL = (unsigned short*)(ws + 5468496);
  unsigned short* qbufL = (unsigned short*)(ws + 20828496);
  unsigned short* pbuf0 = (unsigned short*)(ws + 5468496);
  unsigned short* qbuf0 = (unsigned short*)(ws + 15708496);

  float* embedF = WB + 0;        // 160
  float* dl0w1T = WB + 160;      // 256   [32][8]
  float* dl0w2T = WB + 416;      // 1024  [32][32]
  float* dl1w1T = WB + 1440;     // 128   [32][4]
  float* dl1w2T = WB + 1568;     // 1024  [32][32]
  float* siT    = WB + 2592;     // 1536  [16][96]

  hipMemsetAsync(cntd, 0, 40000 * 4, stream);
  hipMemsetAsync(nodesum, 0, 96 * 4, stream);

  TTab tb;
  int ti = 0;
  auto add = [&](const void* s, float* dst, int R, int C, int tr){
    tb.e[ti].src = (const float*)s; tb.e[ti].dst = dst;
    tb.e[ti].R = R; tb.e[ti].C = C; tb.e[ti].trans = tr; ti++;
  };
  add(d_in[4],  embedF, 20, 8, 0);
  add(d_in[5],  dl0w1T, 8, 32, 1);
  add(d_in[6],  dl0w2T, 32, 32, 1);
  add(d_in[7],  dl1w1T, 4, 32, 1);
  add(d_in[8],  dl1w2T, 32, 32, 1);
  add(d_in[17], siT, 96, 16, 1);

  PTab pt;
  int pi = 0;
  auto padd = [&](const void* s, unsigned int* dst, int R, int C){
    pt.e[pi].src = (const float*)s; pt.e[pi].dst = dst;
    pt.e[pi].R = R; pt.e[pi].C = C; pi++;
  };
  for (int i = 0; i < 2; i++){
    padd((const float*)d_in[15] + i*6144, pk + i*6144 + 0,    192, 32);  // dw1T [32][96]
    padd((const float*)d_in[16] + i*6144, pk + i*6144 + 3072, 32, 192);  // dw2  [192][16]
  }

  // weight prep (convw + pk pack + both LUTs) in one launch
  prep_k<<<7 + 2*NT + (NT + 5)/6, 384, 0, stream>>>(
      tb, pt, (const float*)d_in[11], (const float*)d_in[12],
      (const float*)d_in[13], (const float*)d_in[14], (unsigned short*)lutL,
      (const float*)d_in[9], (const float*)d_in[10], (unsigned short*)lut01);
  countnode_k<<<NE/256 + (NN + 255)/256, 256, 0, stream>>>(
      esrc, edst, cntd, cnts, atom_z, embedF, dl0w1T, dl0w2T, xn);
  prefix_k<<<2, 1024, 0, stream>>>(cntd, doff, curd, cnts, soff, curs);
  fill_comb<<<(NE + 255)/256, 256, 0, stream>>>(esrc, edst, curd, curs,
                                                srcS, dstS, qpos);
  edge_init<<<(NE + 255)/256, 256, 0, stream>>>(
      pos, srcS, dstS, qpos, els, pbuf0, qbuf0, dl1w1T, dl1w2T, lut01);
  gather_init<<<(NN + 3)/4, 256, 0, stream>>>(doff, soff, pbuf0, qbuf0, xn, xnh);

  for (int i = 0; i < 2; i++){
    layer_k<<<NE/256, 256, 0, stream>>>(
        srcS, dstS, qpos, els, xnh, pbufL, qbufL,
        lutL + (long)i * NT * 192, pk + i*6144);
    gather_upd<<<(NN + 4)/5, 512, 0, stream>>>(doff, soff, pbufL, qbufL,
                                               xn, xnh);
  }
  colsum<<<200, 192, 0, stream>>>(xn, nodesum);
  project<<<1, 64, 0, stream>>>(nodesum, siT, (float*)d_out);
}

// Round 12
// 731.966 us; speedup vs baseline: 1.3956x; 1.1587x over previous
//
#include <hip/hip_runtime.h>
#include <hip/hip_bf16.h>

#define NN 20000
#define NE 320000
#define NT 2048            // filter LUT entries over len in [0, 1.7321]

typedef _Float16 h2f __attribute__((ext_vector_type(2)));
typedef _Float16 f16x8 __attribute__((ext_vector_type(8)));
typedef float f32x4 __attribute__((ext_vector_type(4)));

__device__ __forceinline__ h2f u2h(unsigned int u){
  union { unsigned int u; h2f h; } v; v.u = u; return v.h;
}
__device__ __forceinline__ unsigned int h2u(h2f h){
  union { h2f h; unsigned int u; } v; v.h = h; return v.u;
}
__device__ __forceinline__ unsigned int pack2(float a, float b){
  h2f h; h.x = (_Float16)a; h.y = (_Float16)b;
  union { h2f h; unsigned int u; } v; v.h = h; return v.u;
}
__device__ __forceinline__ unsigned short f16b(float a){
  union { _Float16 h; unsigned short u; } v; v.h = (_Float16)a; return v.u;
}
__device__ __forceinline__ f16x8 u4h8(uint4 u){
  union { uint4 u; f16x8 h; } v; v.u = u; return v.h;
}
// packed f16 lerp: a + t*(b-a)
__device__ __forceinline__ unsigned int lerp2(unsigned int a, unsigned int b, h2f t){
  h2f ha = u2h(a), hb = u2h(b);
  return h2u(ha + t * (hb - ha));
}

// jax.nn.gelu default (approximate=True): 0.5x(1+tanh(t)) == x*sigmoid(2t)
__device__ __forceinline__ float geluf(float x){
  float t = 0.7978845608028654f * x * (1.0f + 0.044715f * x * x);
  return x / (1.0f + __expf(-2.0f * t));
}

struct TEnt { const float* src; float* dst; int R; int C; int trans; };
struct TTab { TEnt e[8]; };

__device__ __forceinline__ void lut_basis(int ent, float* b){
  float len = fmaxf((float)ent * (1.7321f / (float)(NT - 1)), 1e-6f);
  float sc = 3.1622776601683795f / fmaxf(len, 1e-6f);  // sqrt(2/MAXR)*sqrt(B)/r
#pragma unroll
  for (int k = 0; k < 10; k++)
    b[k] = sinf((float)(k + 1) * 1.5707963267948966f * len) * sc;
}

// ---------------- merged weight prep ----------------------------------------
// blocks: [0,6) convw, 6 = B-fragment pack, [7,7+2NT) layer LUT, rest init LUT
// bf1 layout (uint): ly*3072 + ((kt*2+nt)*64 + lane)*4 + v
//   value = pack(dw1[k][col], dw1[k+1][col]), k=32kt+8(lane>>4)+2v, col=16nt+(lane&15)
// bf2 layout (uint): ly*3072 + (nt*64 + lane)*4 + v
//   value = pack(dw2[k][col], dw2[k+1][col]), k=8(lane>>4)+2v, col=16nt+(lane&15)
__global__ __launch_bounds__(384) void prep_k(
    TTab tb,
    const float* __restrict__ fABw1, const float* __restrict__ fABw2,
    const float* __restrict__ fCw1,  const float* __restrict__ fCw2,
    unsigned short* __restrict__ lutH,
    const float* __restrict__ f01w1, const float* __restrict__ f01w2,
    unsigned short* __restrict__ lut01H,
    const float* __restrict__ dlw1, const float* __restrict__ dlw2,
    unsigned int* __restrict__ bf1, unsigned int* __restrict__ bf2)
{
  int b = blockIdx.x;
  int t = threadIdx.x;
  if (b < 6){
    TEnt en = tb.e[b];
    int n = en.R * en.C;
    for (int i = t; i < n; i += 384){
      float v = en.src[i];
      if (en.trans){
        int r = i / en.C, c = i - r * en.C;
        en.dst[c * en.R + r] = v;
      } else {
        en.dst[i] = v;
      }
    }
    return;
  }
  if (b == 6){
    for (int i = t; i < 12288; i += 384){
      if (i < 6144){
        int v = i & 3, ln = (i >> 2) & 63;
        int nt = (i >> 8) & 1;
        int ktly = i >> 9;            // ly*6 + kt
        int kt = ktly % 6, ly = ktly / 6;
        int k = 32*kt + 8*(ln >> 4) + 2*v;
        int col = 16*nt + (ln & 15);
        const float* s = dlw1 + ly*6144;       // [192][32]
        bf1[i] = pack2(s[k*32 + col], s[(k+1)*32 + col]);
      } else {
        int j = i - 6144;
        int v = j & 3, ln = (j >> 2) & 63;
        int ntly = j >> 8;            // ly*12 + nt
        int nt = ntly % 12, ly = ntly / 12;
        int k = 8*(ln >> 4) + 2*v;
        int col = 16*nt + (ln & 15);
        const float* s = dlw2 + ly*6144;       // [32][192]
        bf2[j] = pack2(s[k*192 + col], s[(k+1)*192 + col]);
      }
    }
    return;
  }
  if (b < 7 + 2*NT){
    int bb = b - 7;
    int ent = bb & (NT - 1);
    int layer = bb >> 11;       // NT = 2048
    float bas[10];
    lut_basis(ent, bas);
    __shared__ float h[192];
    if (t < 192){
      int f = t >> 6, l = t & 63;       // f: 0=A, 1=B, 2=C
      const float* w1 = (f < 2) ? (fABw1 + (layer*2 + f) * 640)
                                : (fCw1 + layer * 640);
      float a = 0.f;
#pragma unroll
      for (int k = 0; k < 10; k++) a += bas[k] * w1[k*64 + l];
      h[t] = geluf(a);
    }
    __syncthreads();
    float a = 0.f;
    if (t < 192){
      int f = t / 96, j = t - 96 * f;
      const float* w2 = fABw2 + (layer*2 + f) * 6144;
      for (int l = 0; l < 64; l++) a += h[f*64 + l] * w2[l*96 + j];
    } else {
      int j = t - 192;
      const float* w2 = fCw2 + layer * 12288;
      for (int l = 0; l < 64; l++) a += h[128 + l] * w2[l*192 + j];
    }
    lutH[((long)(layer * NT + ent)) * 384 + t] = f16b(a);
    return;
  }
  // init LUT: 6 entries per block (384 = 6*64 threads)
  int blk = b - 7 - 2*NT;
  int ent = blk * 6 + (t >> 6);
  if (ent >= NT) return;
  int tl = t & 63;
  int p = tl >> 5, jj = tl & 31;
  float bas[10];
  lut_basis(ent, bas);
  const float* w1 = f01w1 + p * 640;
  const float* w2 = f01w2 + p * 2048;
  float W = 0.f;
  for (int l = 0; l < 64; l++){
    float a = 0.f;
#pragma unroll
    for (int k = 0; k < 10; k++) a += bas[k] * w1[k*64 + l];
    W += geluf(a) * w2[l*32 + jj];
  }
  lut01H[(long)ent * 64 + tl] = f16b(W);
}

// ---------------- merged: edge degree count + node init ---------------------
__global__ __launch_bounds__(256) void countnode_k(
    const int* __restrict__ esrc, const int* __restrict__ edst,
    int* __restrict__ cntd, int* __restrict__ cnts,
    const int* __restrict__ az, const float* __restrict__ embedF,
    const float* __restrict__ w1T /*[32][8]*/, const float* __restrict__ w2T /*[32][32]*/,
    float* __restrict__ xn)
{
  if (blockIdx.x < NE/256){
    int e = blockIdx.x * 256 + threadIdx.x;
    atomicAdd(cntd + edst[e], 1);
    atomicAdd(cnts + esrc[e], 1);
    return;
  }
  int n = (blockIdx.x - NE/256) * 256 + threadIdx.x;
  if (n >= NN) return;
  int z = az[n];
  float ee[8];
#pragma unroll
  for (int k = 0; k < 8; k++) ee[k] = embedF[z * 8 + k];
  float hid[32];
#pragma unroll
  for (int l = 0; l < 32; l++){
    float a = 0.f;
#pragma unroll
    for (int k = 0; k < 8; k++) a += ee[k] * w1T[l * 8 + k];
    hid[l] = geluf(a);
  }
  float* row = xn + (long)n * 96;
#pragma unroll
  for (int j = 0; j < 32; j++){
    float a = 0.f;
#pragma unroll
    for (int l = 0; l < 32; l++) a += hid[l] * w2T[j * 32 + l];
    row[j] = a;
  }
#pragma unroll
  for (int j = 32; j < 96; j++) row[j] = 0.f;
}

// ---------------- both prefix sums in one launch ----------------------------
__global__ __launch_bounds__(1024) void prefix_k(
    const int* __restrict__ cntd, int* __restrict__ doff, int* __restrict__ curd,
    const int* __restrict__ cnts, int* __restrict__ soff, int* __restrict__ curs)
{
  const int* cnt = blockIdx.x ? cnts : cntd;
  int* off = blockIdx.x ? soff : doff;
  int* cur = blockIdx.x ? curs : curd;
  __shared__ int part[1024];
  int t = threadIdx.x;
  int base = t * 20;
  int s = 0;
  for (int i = 0; i < 20; i++){ int idx = base + i; if (idx < NN) s += cnt[idx]; }
  part[t] = s; __syncthreads();
  for (int d = 1; d < 1024; d <<= 1){
    int v = (t >= d) ? part[t - d] : 0;
    __syncthreads();
    part[t] += v;
    __syncthreads();
  }
  int run = (t == 0) ? 0 : part[t - 1];
  for (int i = 0; i < 20; i++){
    int idx = base + i;
    if (idx < NN){ off[idx] = run; cur[idx] = run; run += cnt[idx]; }
  }
  if (t == 0) off[NN] = NE;
}

// p = dst-sorted slot of edge e; q = src-sorted slot; qpos[p]=q
__global__ void fill_comb(const int* __restrict__ esrc, const int* __restrict__ edst,
                          int* __restrict__ curd, int* __restrict__ curs,
                          int* __restrict__ srcS, int* __restrict__ dstS,
                          int* __restrict__ qpos){
  int e = blockIdx.x * 256 + threadIdx.x;
  if (e >= NE) return;
  int s = esrc[e], d = edst[e];
  int p = atomicAdd(curd + d, 1);
  srcS[p] = s; dstS[p] = d;
  int q = atomicAdd(curs + s, 1);
  qpos[p] = q;
}

// ---------------- edge init: p-row (dst side) + scattered q-row (src side) --
__global__ __launch_bounds__(256) void edge_init(
    const float* __restrict__ pos, const int* __restrict__ srcS,
    const int* __restrict__ dstS, const int* __restrict__ qpos,
    float* __restrict__ els,
    unsigned short* __restrict__ pbuf0, unsigned short* __restrict__ qbuf0,
    const float* __restrict__ w1T /*dl1w1T [32][4]*/, const float* __restrict__ w2T /*[32][32]*/,
    const unsigned int* __restrict__ lut01)
{
  int p = blockIdx.x * 256 + threadIdx.x;
  if (p >= NE) return;
  int s = srcS[p], d = dstS[p];
  float x = pos[s*3+0] - pos[d*3+0];
  float y = pos[s*3+1] - pos[d*3+1];
  float z = pos[s*3+2] - pos[d*3+2];
  float L = sqrtf(x*x + y*y + z*z + 1e-12f);
  float iv = 1.0f / fmaxf(L, 1e-6f);
  els[p] = L;

  float u = L - 2.0f;   // 2*(len/MAXR - 1), MAXR=2
  float cut = 0.5f * (1.0f - cosf(3.14159265358979323f * u));
  cut = (u > 0.0f) ? 0.0f : cut;
  cut = (u < -1.0f) ? 1.0f : cut;
  float xe0 = cut, cc = cut * 1.7320508075688772f * iv;
  float xe1 = cc*x, xe2 = cc*y, xe3 = cc*z;
  float hid[32];
#pragma unroll
  for (int l = 0; l < 32; l++){
    float a = xe0*w1T[l*4+0] + xe1*w1T[l*4+1] + xe2*w1T[l*4+2] + xe3*w1T[l*4+3];
    hid[l] = geluf(a);
  }
  float xeh[32];
#pragma unroll
  for (int j = 0; j < 32; j++){
    float a = 0.f;
#pragma unroll
    for (int l = 0; l < 32; l++) a += hid[l] * w2T[j*32 + l];
    xeh[j] = a;
  }
  float tt = fminf(L * ((float)(NT-1) / 1.7321f), (float)(NT-1) - 0.001f);
  int i0 = (int)tt; float tfv = tt - (float)i0;
  h2f tf2; tf2.x = (_Float16)tfv; tf2.y = tf2.x;
  h2f h05; h05.x = (_Float16)0.5f; h05.y = h05.x;
  const unsigned int* rA = lut01 + i0 * 32;
  const unsigned int* rB = rA + 32;

  unsigned int xp[16];
#pragma unroll
  for (int jp = 0; jp < 16; jp++)
    xp[jp] = pack2(xeh[2*jp] * 0.0625f, xeh[2*jp+1] * 0.0625f);

  unsigned int du[16], au[16];
#pragma unroll
  for (int q = 0; q < 4; q++){
    uint4 a = ((const uint4*)rA)[q];
    uint4 b = ((const uint4*)rB)[q];
    du[4*q+0] = h2u(u2h(lerp2(a.x, b.x, tf2)) * u2h(xp[4*q+0]));
    du[4*q+1] = h2u(u2h(lerp2(a.y, b.y, tf2)) * u2h(xp[4*q+1]));
    du[4*q+2] = h2u(u2h(lerp2(a.z, b.z, tf2)) * u2h(xp[4*q+2]));
    du[4*q+3] = h2u(u2h(lerp2(a.w, b.w, tf2)) * u2h(xp[4*q+3]));
  }
#pragma unroll
  for (int q = 0; q < 4; q++){
    uint4 a = ((const uint4*)(rA + 16))[q];
    uint4 b = ((const uint4*)(rB + 16))[q];
    au[4*q+0] = h2u(u2h(lerp2(a.x, b.x, tf2)) * u2h(xp[4*q+0]) * h05);
    au[4*q+1] = h2u(u2h(lerp2(a.y, b.y, tf2)) * u2h(xp[4*q+1]) * h05);
    au[4*q+2] = h2u(u2h(lerp2(a.z, b.z, tf2)) * u2h(xp[4*q+2]) * h05);
    au[4*q+3] = h2u(u2h(lerp2(a.w, b.w, tf2)) * u2h(xp[4*q+3]) * h05);
  }
  unsigned short* prow = pbuf0 + (long)p * 64;
  unsigned short* qrow = qbuf0 + (long)qpos[p] * 64;
#pragma unroll
  for (int q = 0; q < 4; q++){
    ((uint4*)prow)[q]      = ((uint4*)du)[q];
    ((uint4*)(prow+32))[q] = ((uint4*)au)[q];
  }
  unsigned int nd[16];
#pragma unroll
  for (int i = 0; i < 16; i++) nd[i] = du[i] ^ 0x80008000u;  // negate packed f16
#pragma unroll
  for (int q = 0; q < 4; q++){
    ((uint4*)qrow)[q]      = ((uint4*)nd)[q];
    ((uint4*)(qrow+32))[q] = ((uint4*)au)[q];
  }
}

// 4 nodes (4 waves) per 256-thread block; both roles stream contiguous rows;
// also packs the node's xnh f16 row
__global__ __launch_bounds__(256) void gather_init(
    const int* __restrict__ doff, const int* __restrict__ soff,
    const unsigned short* __restrict__ pbuf0, const unsigned short* __restrict__ qbuf0,
    float* __restrict__ xn, unsigned int* __restrict__ xnh)
{
  int n = blockIdx.x * 4 + (threadIdx.x >> 6);
  int c = threadIdx.x & 63;          // lane == c
  if (n >= NN) return;
  const _Float16* ph = (const _Float16*)pbuf0;
  const _Float16* qh = (const _Float16*)qbuf0;
  float acc = 0.f;
  int d1 = doff[n+1];
  for (int p = doff[n]; p < d1; p++) acc += (float)ph[(long)p * 64 + c];
  int s1 = soff[n+1];
  for (int q = soff[n]; q < s1; q++) acc += (float)qh[(long)q * 64 + c];
  float v = 16.f * acc;              // cols 32..95 (cols were zero)
  xn[(long)n * 96 + 32 + c] = v;
  float other = __shfl_xor(v, 1);
  if (!(c & 1)) xnh[n * 48 + 16 + (c >> 1)] = pack2(v, other);
  if (c < 16){
    float a = xn[(long)n * 96 + 2*c];
    float b = xn[(long)n * 96 + 2*c + 1];
    xnh[n * 48 + c] = pack2(a, b);
  }
}

// ---------------- conv layer via MFMA ---------------------------------------
// Per wave: 64 edges. pass1 hd[64][32] = G[64][192] @ dw1; pass2 d = hdg @ dw2.
// A-frag: lane -> row (lane&15)+16mt, k = 8*(lane>>4)+j
// B-frag: lane -> col (lane&15)+16nt, k = 8*(lane>>4)+j (pre-packed bf1/bf2)
// C/D:    lane -> col (lane&15), row = 4*(lane>>4)+reg  [HW-verified layout]
// p-row -> pbuf[p]; q-row -> qbuf[qpos[p]] (scatter; gather streams both sides)
// Scales: G grad 1/32, G ave 1/64 (0.5 folded); hdg 1/64; msgs true/64.
__global__ __launch_bounds__(256) void layer_k(
    const int* __restrict__ srcS, const int* __restrict__ dstS,
    const int* __restrict__ qpos,
    const float* __restrict__ els, const unsigned int* __restrict__ xnh,
    unsigned short* __restrict__ pbuf, unsigned short* __restrict__ qbuf,
    const unsigned int* __restrict__ lut,
    const unsigned int* __restrict__ bf1, const unsigned int* __restrict__ bf2)
{
  __shared__ unsigned int smem[4][1092];   // per-wave [64][17]-uint image
  int tid = threadIdx.x;
  int wid = tid >> 6, lane = tid & 63;
  int g = lane >> 4, r15 = lane & 15;
  unsigned int* wb = smem[wid];
  int wbase = blockIdx.x * 256 + wid * 64;

  // per-mt metadata (fragment-side edges: re = wbase + 16mt + r15)
  const unsigned int* xsP[4]; const unsigned int* xdP[4];
  const unsigned int* rAm[4]; const unsigned int* rBm[4];
  h2f tfm[4];
#pragma unroll
  for (int mt = 0; mt < 4; mt++){
    int re = wbase + 16*mt + r15;
    xsP[mt] = xnh + srcS[re] * 48;
    xdP[mt] = xnh + dstS[re] * 48;
    float L = els[re];
    float tt = fminf(L * ((float)(NT-1) / 1.7321f), (float)(NT-1) - 0.001f);
    int i0 = (int)tt; float tfv = tt - (float)i0;
    h2f tf; tf.x = (_Float16)tfv; tf.y = tf.x;
    tfm[mt] = tf;
    rAm[mt] = lut + (long)i0 * 192;
    rBm[mt] = rAm[mt] + 192;
  }
  // own-edge metadata (output row p = wbase + lane)
  int p = wbase + lane;
  int qq = qpos[p];
  const unsigned int *rAo, *rBo; h2f tfo;
  {
    float L = els[p];
    float tt = fminf(L * ((float)(NT-1) / 1.7321f), (float)(NT-1) - 0.001f);
    int i0 = (int)tt; float tfv = tt - (float)i0;
    tfo.x = (_Float16)tfv; tfo.y = tfo.x;
    rAo = lut + (long)i0 * 192;
    rBo = rAo + 192;
  }
  h2f c32; c32.x = (_Float16)0.03125f;  c32.y = c32.x;
  h2f c64; c64.x = (_Float16)0.015625f; c64.y = c64.x;
  h2f h05; h05.x = (_Float16)0.5f;      h05.y = h05.x;
  f32x4 zf = {0.f, 0.f, 0.f, 0.f};

  // ---- pass 1 ----
  f32x4 acc[4][2];
#pragma unroll
  for (int mt = 0; mt < 4; mt++){ acc[mt][0] = zf; acc[mt][1] = zf; }

#pragma unroll
  for (int ktp = 0; ktp < 3; ktp++){      // x-uint window 16*ktp..+16
    int off = 16*ktp + 4*g;
    uint4 bg0 = *(const uint4*)(bf1 + (((ktp  )*2 + 0)*64 + lane)*4);
    uint4 bg1 = *(const uint4*)(bf1 + (((ktp  )*2 + 1)*64 + lane)*4);
    uint4 ba0 = *(const uint4*)(bf1 + (((ktp+3)*2 + 0)*64 + lane)*4);
    uint4 ba1 = *(const uint4*)(bf1 + (((ktp+3)*2 + 1)*64 + lane)*4);
#pragma unroll
    for (int mt = 0; mt < 4; mt++){
      uint4 xs4 = *(const uint4*)(xsP[mt] + off);
      uint4 xd4 = *(const uint4*)(xdP[mt] + off);
      uint4 waA = *(const uint4*)(rAm[mt] + off);
      uint4 waB = *(const uint4*)(rBm[mt] + off);
      uint4 wbA = *(const uint4*)(rAm[mt] + 48 + off);
      uint4 wbB = *(const uint4*)(rBm[mt] + 48 + off);
      h2f tf = tfm[mt];
      uint4 fg, fa;
      fg.x = h2u(u2h(lerp2(waA.x, waB.x, tf)) * ((u2h(xd4.x) - u2h(xs4.x)) * c32));
      fg.y = h2u(u2h(lerp2(waA.y, waB.y, tf)) * ((u2h(xd4.y) - u2h(xs4.y)) * c32));
      fg.z = h2u(u2h(lerp2(waA.z, waB.z, tf)) * ((u2h(xd4.z) - u2h(xs4.z)) * c32));
      fg.w = h2u(u2h(lerp2(waA.w, waB.w, tf)) * ((u2h(xd4.w) - u2h(xs4.w)) * c32));
      fa.x = h2u(u2h(lerp2(wbA.x, wbB.x, tf)) * ((u2h(xd4.x) + u2h(xs4.x)) * c64));
      fa.y = h2u(u2h(lerp2(wbA.y, wbB.y, tf)) * ((u2h(xd4.y) + u2h(xs4.y)) * c64));
      fa.z = h2u(u2h(lerp2(wbA.z, wbB.z, tf)) * ((u2h(xd4.z) + u2h(xs4.z)) * c64));
      fa.w = h2u(u2h(lerp2(wbA.w, wbB.w, tf)) * ((u2h(xd4.w) + u2h(xs4.w)) * c64));
      acc[mt][0] = __builtin_amdgcn_mfma_f32_16x16x32_f16(u4h8(fg), u4h8(bg0), acc[mt][0], 0, 0, 0);
      acc[mt][1] = __builtin_amdgcn_mfma_f32_16x16x32_f16(u4h8(fg), u4h8(bg1), acc[mt][1], 0, 0, 0);
      acc[mt][0] = __builtin_amdgcn_mfma_f32_16x16x32_f16(u4h8(fa), u4h8(ba0), acc[mt][0], 0, 0, 0);
      acc[mt][1] = __builtin_amdgcn_mfma_f32_16x16x32_f16(u4h8(fa), u4h8(ba1), acc[mt][1], 0, 0, 0);
    }
  }

  // ---- gelu + transpose hdg (D layout -> row-major LDS -> A-frags) ----
#pragma unroll
  for (int mt = 0; mt < 4; mt++)
#pragma unroll
    for (int nt = 0; nt < 2; nt++)
#pragma unroll
      for (int i = 0; i < 4; i++){
        float v = geluf(32.f * acc[mt][nt][i]) * 0.015625f;
        float o = __shfl_xor(v, 1);
        if (!(lane & 1))
          wb[(16*mt + 4*g + i)*17 + 8*nt + (r15 >> 1)] = pack2(v, o);
      }
  __syncthreads();
  uint4 af[4];
#pragma unroll
  for (int mt = 0; mt < 4; mt++){
    int row = 16*mt + r15;
    af[mt].x = wb[row*17 + 4*g + 0];
    af[mt].y = wb[row*17 + 4*g + 1];
    af[mt].z = wb[row*17 + 4*g + 2];
    af[mt].w = wb[row*17 + 4*g + 3];
  }
  __syncthreads();

  // ---- pass 2: per 16-col block np (cols 16np.. and 96+16np..) ----
  unsigned int* prow = (unsigned int*)(pbuf + (long)p * 96);
  unsigned int* qrow = (unsigned int*)(qbuf + (long)qq * 96);
  for (int np = 0; np < 6; np++){
    uint4 b1 = *(const uint4*)(bf2 + ((np    )*64 + lane)*4);
    uint4 b2 = *(const uint4*)(bf2 + ((np + 6)*64 + lane)*4);
    f32x4 d1a[4], d2a[4];
#pragma unroll
    for (int mt = 0; mt < 4; mt++){
      d1a[mt] = __builtin_amdgcn_mfma_f32_16x16x32_f16(u4h8(af[mt]), u4h8(b1), zf, 0, 0, 0);
      d2a[mt] = __builtin_amdgcn_mfma_f32_16x16x32_f16(u4h8(af[mt]), u4h8(b2), zf, 0, 0, 0);
    }
#pragma unroll
    for (int mt = 0; mt < 4; mt++)
#pragma unroll
      for (int i = 0; i < 4; i++){
        float v1 = d1a[mt][i], v2 = d2a[mt][i];
        float o1 = __shfl_xor(v1, 1);
        float o2 = __shfl_xor(v2, 1);
        if (!(lane & 1)){
          int r = 16*mt + 4*g + i;
          wb[r*17 + (r15 >> 1)]     = pack2(v1, o1);
          wb[r*17 + 8 + (r15 >> 1)] = pack2(v2, o2);
        }
      }
    __syncthreads();
    unsigned int d1u[8], d2u[8];
#pragma unroll
    for (int u = 0; u < 8; u++){
      d1u[u] = wb[lane*17 + u];
      d2u[u] = wb[lane*17 + 8 + u];
    }
    __syncthreads();
    // Wc lerp for own edge: c1 = Wc[16np+..], c2 = Wc[96+16np+..]
    uint4 ca0 = *(const uint4*)(rAo + 96  + 8*np);
    uint4 ca1 = *(const uint4*)(rAo + 100 + 8*np);
    uint4 cb0 = *(const uint4*)(rBo + 96  + 8*np);
    uint4 cb1 = *(const uint4*)(rBo + 100 + 8*np);
    uint4 ka0 = *(const uint4*)(rAo + 144 + 8*np);
    uint4 ka1 = *(const uint4*)(rAo + 148 + 8*np);
    uint4 kb0 = *(const uint4*)(rBo + 144 + 8*np);
    uint4 kb1 = *(const uint4*)(rBo + 148 + 8*np);
    unsigned int c1u[8] = {lerp2(ca0.x,cb0.x,tfo), lerp2(ca0.y,cb0.y,tfo),
                           lerp2(ca0.z,cb0.z,tfo), lerp2(ca0.w,cb0.w,tfo),
                           lerp2(ca1.x,cb1.x,tfo), lerp2(ca1.y,cb1.y,tfo),
                           lerp2(ca1.z,cb1.z,tfo), lerp2(ca1.w,cb1.w,tfo)};
    unsigned int c2u[8] = {lerp2(ka0.x,kb0.x,tfo), lerp2(ka0.y,kb0.y,tfo),
                           lerp2(ka0.z,kb0.z,tfo), lerp2(ka0.w,kb0.w,tfo),
                           lerp2(ka1.x,kb1.x,tfo), lerp2(ka1.y,kb1.y,tfo),
                           lerp2(ka1.z,kb1.z,tfo), lerp2(ka1.w,kb1.w,tfo)};
    unsigned int pv[8], qv[8];
#pragma unroll
    for (int u = 0; u < 8; u++){
      h2f t1 = u2h(c1u[u]) * u2h(d1u[u]);            // dv (true/64)
      h2f t2 = (u2h(c2u[u]) * u2h(d2u[u])) * h05;    // av (true/64)
      pv[u] = h2u(t1 + t2);
      qv[u] = h2u(t2 - t1);
    }
    *(uint4*)(prow + 8*np)     = *(uint4*)(pv);
    *(uint4*)(prow + 8*np + 4) = *(uint4*)(pv + 4);
    *(uint4*)(qrow + 8*np)     = *(uint4*)(qv);
    *(uint4*)(qrow + 8*np + 4) = *(uint4*)(qv + 4);
  }
}

// fused gather + node update + xnh repack; 5 nodes per 512-thread block
// BOTH roles stream contiguous sorted rows (q scattered at write time)
__global__ __launch_bounds__(512) void gather_upd(
    const int* __restrict__ doff, const int* __restrict__ soff,
    const unsigned short* __restrict__ pbuf, const unsigned short* __restrict__ qbuf,
    float* __restrict__ xn, unsigned int* __restrict__ xnh)
{
  int g = threadIdx.x / 96;
  int c = threadIdx.x - 96 * g;
  if (g >= 5) return;
  int n = blockIdx.x * 5 + g;
  if (n >= NN) return;
  const _Float16* ph = (const _Float16*)pbuf;
  const _Float16* qh = (const _Float16*)qbuf;
  float acc = 0.f;
  int d1 = doff[n+1];
  for (int p = doff[n]; p < d1; p++) acc += (float)ph[(long)p * 96 + c];
  int s1 = soff[n+1];
  for (int q = soff[n]; q < s1; q++) acc += (float)qh[(long)q * 96 + c];
  long idx = (long)n * 96 + c;
  float x = xn[idx] - 6.4f * acc;     // 0.1 step * 64 msg scale
  xn[idx] = x;
  float other = __shfl_xor(x, 1);
  if (!(c & 1)) xnh[n * 48 + (c >> 1)] = pack2(x, other);
}

// ---------------- column sum over nodes -------------------------------------
__global__ void colsum(const float* __restrict__ xn, float* __restrict__ nodesum){
  int col = threadIdx.x % 96;
  int seg = threadIdx.x / 96;
  int stripe = blockIdx.x * 2 + seg;   // 0..399
  float acc = 0.f;
  for (int n = stripe; n < NN; n += 400) acc += xn[(long)n * 96 + col];
  unsafeAtomicAdd(nodesum + col, acc);
}

// ---------------- project to 16 outputs, scale, fp32 store ------------------
__global__ void project(const float* __restrict__ nodesum, const float* __restrict__ siT,
                        float* __restrict__ out){
  int j = threadIdx.x;
  if (j < 16){
    float a = 0.f;
#pragma unroll
    for (int c = 0; c < 96; c++) a += nodesum[c] * siT[j*96 + c];
    out[j] = a * 0.007071067811865475f;   // 1/sqrt(20000)
  }
}

// ---------------- host side -------------------------------------------------
extern "C" void kernel_launch(void* const* d_in, const int* in_sizes, int n_in,
                              void* d_out, int out_size, void* d_ws, size_t ws_size,
                              hipStream_t stream){
  const float* pos  = (const float*)d_in[0];
  const int* atom_z = (const int*)d_in[1];
  const int* esrc   = (const int*)d_in[2];
  const int* edst   = (const int*)d_in[3];

  float* ws      = (float*)d_ws;
  float* xn      = ws;                  // 1,920,000
  float* nodesum = ws + 1920000;        // 96
  float* WB      = ws + 1920096;        // 4,128 fp32 weights
  unsigned int* bf1   = (unsigned int*)(ws + 1924224);  // 6,144
  unsigned int* bf2   = (unsigned int*)(ws + 1930368);  // 6,144
  unsigned int* lutL  = (unsigned int*)(ws + 1936512);  // 786,432 (3 MB)
  unsigned int* lut01 = (unsigned int*)(ws + 2722944);  // 65,536
  unsigned int* xnh   = (unsigned int*)(ws + 2788480);  // 960,000 (f16 rows)
  float* els    = ws + 3748480;                 // 320,000 edge lengths
  int*   cntd   = (int*)(ws + 4068480);         // 20,000
  int*   cnts   = cntd + 20000;                 // 20,000 (contiguous for 1 memset)
  int*   curd   = cnts + 20000;                 // 20,000
  int*   curs   = curd + 20000;                 // 20,000
  int*   doff   = curs + 20000;                 // 20,004
  int*   soff   = doff + 20004;                 // 20,004  -> ends 4,188,488
  int*   srcS   = soff + 20004;                 // 320,000 -> ends 4,508,488
  int*   dstS   = srcS + 320000;                // 320,000 -> ends 4,828,488
  int*   qpos   = dstS + 320000;                // 320,000 -> ends 5,148,488
  // buffers at verified round-10/11 offsets (>= 5,468,496 > all int arrays):
  //   pbufL: [ 5,468,496 .. 20,828,496)   qbufL: [20,828,496 .. 36,188,496)
  //   pbuf0: [ 5,468,496 .. 15,708,496)   qbuf0: [15,708,496 .. 25,948,496)
  // (init aliases layer space CROSS-PHASE only; init-phase disjoint.)
  // end = 36,188,496 floats = 144.8 MB
  unsigned short* pbufL = (unsigned short*)(ws + 5468496);
  unsigned short* qbufL = (unsigned short*)(ws + 20828496);
  unsigned short* pbuf0 = (unsigned short*)(ws + 5468496);
  unsigned short* qbuf0 = (unsigned short*)(ws + 15708496);

  float* embedF = WB + 0;        // 160
  float* dl0w1T = WB + 160;      // 256   [32][8]
  float* dl0w2T = WB + 416;      // 1024  [32][32]
  float* dl1w1T = WB + 1440;     // 128   [32][4]
  float* dl1w2T = WB + 1568;     // 1024  [32][32]
  float* siT    = WB + 2592;     // 1536  [16][96]

  hipMemsetAsync(cntd, 0, 40000 * 4, stream);
  hipMemsetAsync(nodesum, 0, 96 * 4, stream);

  TTab tb;
  int ti = 0;
  auto add = [&](const void* s, float* dst, int R, int C, int tr){
    tb.e[ti].src = (const float*)s; tb.e[ti].dst = dst;
    tb.e[ti].R = R; tb.e[ti].C = C; tb.e[ti].trans = tr; ti++;
  };
  add(d_in[4],  embedF, 20, 8, 0);
  add(d_in[5],  dl0w1T, 8, 32, 1);
  add(d_in[6],  dl0w2T, 32, 32, 1);
  add(d_in[7],  dl1w1T, 4, 32, 1);
  add(d_in[8],  dl1w2T, 32, 32, 1);
  add(d_in[17], siT, 96, 16, 1);

  // weight prep (convw + MFMA B-fragment pack + both LUTs) in one launch
  prep_k<<<7 + 2*NT + (NT + 5)/6, 384, 0, stream>>>(
      tb, (const float*)d_in[11], (const float*)d_in[12],
      (const float*)d_in[13], (const float*)d_in[14], (unsigned short*)lutL,
      (const float*)d_in[9], (const float*)d_in[10], (unsigned short*)lut01,
      (const float*)d_in[15], (const float*)d_in[16], bf1, bf2);
  countnode_k<<<NE/256 + (NN + 255)/256, 256, 0, stream>>>(
      esrc, edst, cntd, cnts, atom_z, embedF, dl0w1T, dl0w2T, xn);
  prefix_k<<<2, 1024, 0, stream>>>(cntd, doff, curd, cnts, soff, curs);
  fill_comb<<<(NE + 255)/256, 256, 0, stream>>>(esrc, edst, curd, curs,
                                                srcS, dstS, qpos);
  edge_init<<<(NE + 255)/256, 256, 0, stream>>>(
      pos, srcS, dstS, qpos, els, pbuf0, qbuf0, dl1w1T, dl1w2T, lut01);
  gather_init<<<(NN + 3)/4, 256, 0, stream>>>(doff, soff, pbuf0, qbuf0, xn, xnh);

  for (int i = 0; i < 2; i++){
    layer_k<<<NE/256, 256, 0, stream>>>(
        srcS, dstS, qpos, els, xnh, pbufL, qbufL,
        lutL + (long)i * NT * 192, bf1 + i*3072, bf2 + i*3072);
    gather_upd<<<(NN + 4)/5, 512, 0, stream>>>(doff, soff, pbufL, qbufL,
                                               xn, xnh);
  }
  colsum<<<200, 192, 0, stream>>>(xn, nodesum);
  project<<<1, 64, 0, stream>>>(nodesum, siT, (float*)d_out);
}

// Round 13
// 650.623 us; speedup vs baseline: 1.5701x; 1.1250x over previous
//
#include <hip/hip_runtime.h>
#include <hip/hip_bf16.h>

#define NN 20000
#define NE 320000
#define NT 2048            // filter LUT entries over len in [0, 1.7321]

typedef _Float16 h2f __attribute__((ext_vector_type(2)));
typedef _Float16 f16x8 __attribute__((ext_vector_type(8)));
typedef float f32x4 __attribute__((ext_vector_type(4)));

__device__ __forceinline__ h2f u2h(unsigned int u){
  union { unsigned int u; h2f h; } v; v.u = u; return v.h;
}
__device__ __forceinline__ unsigned int h2u(h2f h){
  union { h2f h; unsigned int u; } v; v.h = h; return v.u;
}
__device__ __forceinline__ unsigned int pack2(float a, float b){
  h2f h; h.x = (_Float16)a; h.y = (_Float16)b;
  union { h2f h; unsigned int u; } v; v.h = h; return v.u;
}
__device__ __forceinline__ unsigned short f16b(float a){
  union { _Float16 h; unsigned short u; } v; v.h = (_Float16)a; return v.u;
}
__device__ __forceinline__ f16x8 u4h8(uint4 u){
  union { uint4 u; f16x8 h; } v; v.u = u; return v.h;
}
// packed f16 lerp: a + t*(b-a)
__device__ __forceinline__ unsigned int lerp2(unsigned int a, unsigned int b, h2f t){
  h2f ha = u2h(a), hb = u2h(b);
  return h2u(ha + t * (hb - ha));
}

// jax.nn.gelu default (approximate=True): 0.5x(1+tanh(t)) == x*sigmoid(2t)
__device__ __forceinline__ float geluf(float x){
  float t = 0.7978845608028654f * x * (1.0f + 0.044715f * x * x);
  return x / (1.0f + __expf(-2.0f * t));
}

// wave-local LDS fence: each wave owns its smem slice; DS ops from one wave
// execute in issue order, so only COMPILER reordering must be prevented.
__device__ __forceinline__ void wsync(){
  asm volatile("" ::: "memory");
  __builtin_amdgcn_sched_barrier(0);
}

struct TEnt { const float* src; float* dst; int R; int C; int trans; };
struct TTab { TEnt e[8]; };

__device__ __forceinline__ void lut_basis(int ent, float* b){
  float len = fmaxf((float)ent * (1.7321f / (float)(NT - 1)), 1e-6f);
  float sc = 3.1622776601683795f / fmaxf(len, 1e-6f);  // sqrt(2/MAXR)*sqrt(B)/r
#pragma unroll
  for (int k = 0; k < 10; k++)
    b[k] = sinf((float)(k + 1) * 1.5707963267948966f * len) * sc;
}

// ---------------- merged weight prep ----------------------------------------
// blocks: [0,6) convw, 6 = B-fragment pack, [7,7+2NT) layer LUT, rest init LUT
__global__ __launch_bounds__(384) void prep_k(
    TTab tb,
    const float* __restrict__ fABw1, const float* __restrict__ fABw2,
    const float* __restrict__ fCw1,  const float* __restrict__ fCw2,
    unsigned short* __restrict__ lutH,
    const float* __restrict__ f01w1, const float* __restrict__ f01w2,
    unsigned short* __restrict__ lut01H,
    const float* __restrict__ dlw1, const float* __restrict__ dlw2,
    unsigned int* __restrict__ bf1, unsigned int* __restrict__ bf2)
{
  int b = blockIdx.x;
  int t = threadIdx.x;
  if (b < 6){
    TEnt en = tb.e[b];
    int n = en.R * en.C;
    for (int i = t; i < n; i += 384){
      float v = en.src[i];
      if (en.trans){
        int r = i / en.C, c = i - r * en.C;
        en.dst[c * en.R + r] = v;
      } else {
        en.dst[i] = v;
      }
    }
    return;
  }
  if (b == 6){
    for (int i = t; i < 12288; i += 384){
      if (i < 6144){
        int v = i & 3, ln = (i >> 2) & 63;
        int nt = (i >> 8) & 1;
        int ktly = i >> 9;            // ly*6 + kt
        int kt = ktly % 6, ly = ktly / 6;
        int k = 32*kt + 8*(ln >> 4) + 2*v;
        int col = 16*nt + (ln & 15);
        const float* s = dlw1 + ly*6144;       // [192][32]
        bf1[i] = pack2(s[k*32 + col], s[(k+1)*32 + col]);
      } else {
        int j = i - 6144;
        int v = j & 3, ln = (j >> 2) & 63;
        int ntly = j >> 8;            // ly*12 + nt
        int nt = ntly % 12, ly = ntly / 12;
        int k = 8*(ln >> 4) + 2*v;
        int col = 16*nt + (ln & 15);
        const float* s = dlw2 + ly*6144;       // [32][192]
        bf2[j] = pack2(s[k*192 + col], s[(k+1)*192 + col]);
      }
    }
    return;
  }
  if (b < 7 + 2*NT){
    int bb = b - 7;
    int ent = bb & (NT - 1);
    int layer = bb >> 11;       // NT = 2048
    float bas[10];
    lut_basis(ent, bas);
    __shared__ float h[192];
    if (t < 192){
      int f = t >> 6, l = t & 63;       // f: 0=A, 1=B, 2=C
      const float* w1 = (f < 2) ? (fABw1 + (layer*2 + f) * 640)
                                : (fCw1 + layer * 640);
      float a = 0.f;
#pragma unroll
      for (int k = 0; k < 10; k++) a += bas[k] * w1[k*64 + l];
      h[t] = geluf(a);
    }
    __syncthreads();
    float a = 0.f;
    if (t < 192){
      int f = t / 96, j = t - 96 * f;
      const float* w2 = fABw2 + (layer*2 + f) * 6144;
      for (int l = 0; l < 64; l++) a += h[f*64 + l] * w2[l*96 + j];
    } else {
      int j = t - 192;
      const float* w2 = fCw2 + layer * 12288;
      for (int l = 0; l < 64; l++) a += h[128 + l] * w2[l*192 + j];
    }
    lutH[((long)(layer * NT + ent)) * 384 + t] = f16b(a);
    return;
  }
  // init LUT: 6 entries per block (384 = 6*64 threads)
  int blk = b - 7 - 2*NT;
  int ent = blk * 6 + (t >> 6);
  if (ent >= NT) return;
  int tl = t & 63;
  int p = tl >> 5, jj = tl & 31;
  float bas[10];
  lut_basis(ent, bas);
  const float* w1 = f01w1 + p * 640;
  const float* w2 = f01w2 + p * 2048;
  float W = 0.f;
  for (int l = 0; l < 64; l++){
    float a = 0.f;
#pragma unroll
    for (int k = 0; k < 10; k++) a += bas[k] * w1[k*64 + l];
    W += geluf(a) * w2[l*32 + jj];
  }
  lut01H[(long)ent * 64 + tl] = f16b(W);
}

// ---------------- merged: edge degree count + node init ---------------------
__global__ __launch_bounds__(256) void countnode_k(
    const int* __restrict__ esrc, const int* __restrict__ edst,
    int* __restrict__ cntd, int* __restrict__ cnts,
    const int* __restrict__ az, const float* __restrict__ embedF,
    const float* __restrict__ w1T /*[32][8]*/, const float* __restrict__ w2T /*[32][32]*/,
    float* __restrict__ xn)
{
  if (blockIdx.x < NE/256){
    int e = blockIdx.x * 256 + threadIdx.x;
    atomicAdd(cntd + edst[e], 1);
    atomicAdd(cnts + esrc[e], 1);
    return;
  }
  int n = (blockIdx.x - NE/256) * 256 + threadIdx.x;
  if (n >= NN) return;
  int z = az[n];
  float ee[8];
#pragma unroll
  for (int k = 0; k < 8; k++) ee[k] = embedF[z * 8 + k];
  float hid[32];
#pragma unroll
  for (int l = 0; l < 32; l++){
    float a = 0.f;
#pragma unroll
    for (int k = 0; k < 8; k++) a += ee[k] * w1T[l * 8 + k];
    hid[l] = geluf(a);
  }
  float* row = xn + (long)n * 96;
#pragma unroll
  for (int j = 0; j < 32; j++){
    float a = 0.f;
#pragma unroll
    for (int l = 0; l < 32; l++) a += hid[l] * w2T[j * 32 + l];
    row[j] = a;
  }
#pragma unroll
  for (int j = 32; j < 96; j++) row[j] = 0.f;
}

// ---------------- both prefix sums in one launch ----------------------------
__global__ __launch_bounds__(1024) void prefix_k(
    const int* __restrict__ cntd, int* __restrict__ doff, int* __restrict__ curd,
    const int* __restrict__ cnts, int* __restrict__ soff, int* __restrict__ curs)
{
  const int* cnt = blockIdx.x ? cnts : cntd;
  int* off = blockIdx.x ? soff : doff;
  int* cur = blockIdx.x ? curs : curd;
  __shared__ int part[1024];
  int t = threadIdx.x;
  int base = t * 20;
  int s = 0;
  for (int i = 0; i < 20; i++){ int idx = base + i; if (idx < NN) s += cnt[idx]; }
  part[t] = s; __syncthreads();
  for (int d = 1; d < 1024; d <<= 1){
    int v = (t >= d) ? part[t - d] : 0;
    __syncthreads();
    part[t] += v;
    __syncthreads();
  }
  int run = (t == 0) ? 0 : part[t - 1];
  for (int i = 0; i < 20; i++){
    int idx = base + i;
    if (idx < NN){ off[idx] = run; cur[idx] = run; run += cnt[idx]; }
  }
  if (t == 0) off[NN] = NE;
}

// p = dst-sorted slot of edge e; q = src-sorted slot; qpos[p]=q
__global__ void fill_comb(const int* __restrict__ esrc, const int* __restrict__ edst,
                          int* __restrict__ curd, int* __restrict__ curs,
                          int* __restrict__ srcS, int* __restrict__ dstS,
                          int* __restrict__ qpos){
  int e = blockIdx.x * 256 + threadIdx.x;
  if (e >= NE) return;
  int s = esrc[e], d = edst[e];
  int p = atomicAdd(curd + d, 1);
  srcS[p] = s; dstS[p] = d;
  int q = atomicAdd(curs + s, 1);
  qpos[p] = q;
}

// ---------------- edge init: p-row (dst side) + scattered q-row (src side) --
__global__ __launch_bounds__(256) void edge_init(
    const float* __restrict__ pos, const int* __restrict__ srcS,
    const int* __restrict__ dstS, const int* __restrict__ qpos,
    float* __restrict__ els,
    unsigned short* __restrict__ pbuf0, unsigned short* __restrict__ qbuf0,
    const float* __restrict__ w1T /*dl1w1T [32][4]*/, const float* __restrict__ w2T /*[32][32]*/,
    const unsigned int* __restrict__ lut01)
{
  int p = blockIdx.x * 256 + threadIdx.x;
  if (p >= NE) return;
  int s = srcS[p], d = dstS[p];
  float x = pos[s*3+0] - pos[d*3+0];
  float y = pos[s*3+1] - pos[d*3+1];
  float z = pos[s*3+2] - pos[d*3+2];
  float L = sqrtf(x*x + y*y + z*z + 1e-12f);
  float iv = 1.0f / fmaxf(L, 1e-6f);
  els[p] = L;

  float u = L - 2.0f;   // 2*(len/MAXR - 1), MAXR=2
  float cut = 0.5f * (1.0f - cosf(3.14159265358979323f * u));
  cut = (u > 0.0f) ? 0.0f : cut;
  cut = (u < -1.0f) ? 1.0f : cut;
  float xe0 = cut, cc = cut * 1.7320508075688772f * iv;
  float xe1 = cc*x, xe2 = cc*y, xe3 = cc*z;
  float hid[32];
#pragma unroll
  for (int l = 0; l < 32; l++){
    float a = xe0*w1T[l*4+0] + xe1*w1T[l*4+1] + xe2*w1T[l*4+2] + xe3*w1T[l*4+3];
    hid[l] = geluf(a);
  }
  float xeh[32];
#pragma unroll
  for (int j = 0; j < 32; j++){
    float a = 0.f;
#pragma unroll
    for (int l = 0; l < 32; l++) a += hid[l] * w2T[j*32 + l];
    xeh[j] = a;
  }
  float tt = fminf(L * ((float)(NT-1) / 1.7321f), (float)(NT-1) - 0.001f);
  int i0 = (int)tt; float tfv = tt - (float)i0;
  h2f tf2; tf2.x = (_Float16)tfv; tf2.y = tf2.x;
  h2f h05; h05.x = (_Float16)0.5f; h05.y = h05.x;
  const unsigned int* rA = lut01 + i0 * 32;
  const unsigned int* rB = rA + 32;

  unsigned int xp[16];
#pragma unroll
  for (int jp = 0; jp < 16; jp++)
    xp[jp] = pack2(xeh[2*jp] * 0.0625f, xeh[2*jp+1] * 0.0625f);

  unsigned int du[16], au[16];
#pragma unroll
  for (int q = 0; q < 4; q++){
    uint4 a = ((const uint4*)rA)[q];
    uint4 b = ((const uint4*)rB)[q];
    du[4*q+0] = h2u(u2h(lerp2(a.x, b.x, tf2)) * u2h(xp[4*q+0]));
    du[4*q+1] = h2u(u2h(lerp2(a.y, b.y, tf2)) * u2h(xp[4*q+1]));
    du[4*q+2] = h2u(u2h(lerp2(a.z, b.z, tf2)) * u2h(xp[4*q+2]));
    du[4*q+3] = h2u(u2h(lerp2(a.w, b.w, tf2)) * u2h(xp[4*q+3]));
  }
#pragma unroll
  for (int q = 0; q < 4; q++){
    uint4 a = ((const uint4*)(rA + 16))[q];
    uint4 b = ((const uint4*)(rB + 16))[q];
    au[4*q+0] = h2u(u2h(lerp2(a.x, b.x, tf2)) * u2h(xp[4*q+0]) * h05);
    au[4*q+1] = h2u(u2h(lerp2(a.y, b.y, tf2)) * u2h(xp[4*q+1]) * h05);
    au[4*q+2] = h2u(u2h(lerp2(a.z, b.z, tf2)) * u2h(xp[4*q+2]) * h05);
    au[4*q+3] = h2u(u2h(lerp2(a.w, b.w, tf2)) * u2h(xp[4*q+3]) * h05);
  }
  unsigned short* prow = pbuf0 + (long)p * 64;
  unsigned short* qrow = qbuf0 + (long)qpos[p] * 64;
#pragma unroll
  for (int q = 0; q < 4; q++){
    ((uint4*)prow)[q]      = ((uint4*)du)[q];
    ((uint4*)(prow+32))[q] = ((uint4*)au)[q];
  }
  unsigned int nd[16];
#pragma unroll
  for (int i = 0; i < 16; i++) nd[i] = du[i] ^ 0x80008000u;  // negate packed f16
#pragma unroll
  for (int q = 0; q < 4; q++){
    ((uint4*)qrow)[q]      = ((uint4*)nd)[q];
    ((uint4*)(qrow+32))[q] = ((uint4*)au)[q];
  }
}

// 16 nodes per 256-thread block, 16 threads/node, uint2-vectorized streams
__global__ __launch_bounds__(256) void gather_init(
    const int* __restrict__ doff, const int* __restrict__ soff,
    const unsigned short* __restrict__ pbuf0, const unsigned short* __restrict__ qbuf0,
    float* __restrict__ xn, unsigned int* __restrict__ xnh)
{
  int g = threadIdx.x >> 4;          // 0..15
  int c4 = threadIdx.x & 15;         // 4-half group within 64-half row
  int n = blockIdx.x * 16 + g;
  if (n >= NN) return;
  const uint2* p2 = (const uint2*)pbuf0;   // row = 16 uint2
  const uint2* q2 = (const uint2*)qbuf0;
  float a0 = 0.f, a1 = 0.f, a2 = 0.f, a3 = 0.f;
  int d1 = doff[n+1];
  for (int p = doff[n]; p < d1; p++){
    uint2 v = p2[(long)p * 16 + c4];
    h2f lo = u2h(v.x), hi = u2h(v.y);
    a0 += (float)lo.x; a1 += (float)lo.y; a2 += (float)hi.x; a3 += (float)hi.y;
  }
  int s1 = soff[n+1];
  for (int q = soff[n]; q < s1; q++){
    uint2 v = q2[(long)q * 16 + c4];
    h2f lo = u2h(v.x), hi = u2h(v.y);
    a0 += (float)lo.x; a1 += (float)lo.y; a2 += (float)hi.x; a3 += (float)hi.y;
  }
  float4 v4; v4.x = 16.f*a0; v4.y = 16.f*a1; v4.z = 16.f*a2; v4.w = 16.f*a3;
  *(float4*)(xn + (long)n * 96 + 32 + 4*c4) = v4;   // cols 32..95
  uint2 w; w.x = pack2(v4.x, v4.y); w.y = pack2(v4.z, v4.w);
  *(uint2*)(xnh + n * 48 + 16 + 2*c4) = w;
  if (c4 < 8){
    float4 t = *(const float4*)(xn + (long)n * 96 + 4*c4);
    uint2 w0; w0.x = pack2(t.x, t.y); w0.y = pack2(t.z, t.w);
    *(uint2*)(xnh + n * 48 + 2*c4) = w0;
  }
}

// ---------------- conv layer via MFMA (wave-local sync) ---------------------
// Per wave: 64 edges. pass1 hd[64][32] = G[64][192] @ dw1; pass2 d = hdg @ dw2.
// A-frag: lane -> row (lane&15)+16mt, k = 8*(lane>>4)+j
// B-frag: lane -> col (lane&15)+16nt, k = 8*(lane>>4)+j (pre-packed bf1/bf2)
// C/D:    lane -> col (lane&15), row = 4*(lane>>4)+reg
// p-row -> pbuf[p]; q-row -> qbuf[qpos[p]] (scatter; gather streams both sides)
// LDS transposes are INTRA-WAVE (smem[wid] private per wave) -> no barriers;
// wsync() is a compile-time fence only (DS ops per wave execute in order).
__global__ __launch_bounds__(256) void layer_k(
    const int* __restrict__ srcS, const int* __restrict__ dstS,
    const int* __restrict__ qpos,
    const float* __restrict__ els, const unsigned int* __restrict__ xnh,
    unsigned short* __restrict__ pbuf, unsigned short* __restrict__ qbuf,
    const unsigned int* __restrict__ lut,
    const unsigned int* __restrict__ bf1, const unsigned int* __restrict__ bf2)
{
  __shared__ unsigned int smem[4][1092];   // per-wave [64][17]-uint image
  int tid = threadIdx.x;
  int wid = tid >> 6, lane = tid & 63;
  int g = lane >> 4, r15 = lane & 15;
  unsigned int* wb = smem[wid];
  int wbase = blockIdx.x * 256 + wid * 64;

  // per-mt metadata (fragment-side edges: re = wbase + 16mt + r15)
  const unsigned int* xsP[4]; const unsigned int* xdP[4];
  const unsigned int* rAm[4]; const unsigned int* rBm[4];
  h2f tfm[4];
#pragma unroll
  for (int mt = 0; mt < 4; mt++){
    int re = wbase + 16*mt + r15;
    xsP[mt] = xnh + srcS[re] * 48;
    xdP[mt] = xnh + dstS[re] * 48;
    float L = els[re];
    float tt = fminf(L * ((float)(NT-1) / 1.7321f), (float)(NT-1) - 0.001f);
    int i0 = (int)tt; float tfv = tt - (float)i0;
    h2f tf; tf.x = (_Float16)tfv; tf.y = tf.x;
    tfm[mt] = tf;
    rAm[mt] = lut + (long)i0 * 192;
    rBm[mt] = rAm[mt] + 192;
  }
  // own-edge metadata (output row p = wbase + lane)
  int p = wbase + lane;
  int qq = qpos[p];
  const unsigned int *rAo, *rBo; h2f tfo;
  {
    float L = els[p];
    float tt = fminf(L * ((float)(NT-1) / 1.7321f), (float)(NT-1) - 0.001f);
    int i0 = (int)tt; float tfv = tt - (float)i0;
    tfo.x = (_Float16)tfv; tfo.y = tfo.x;
    rAo = lut + (long)i0 * 192;
    rBo = rAo + 192;
  }
  h2f c32; c32.x = (_Float16)0.03125f;  c32.y = c32.x;
  h2f c64; c64.x = (_Float16)0.015625f; c64.y = c64.x;
  h2f h05; h05.x = (_Float16)0.5f;      h05.y = h05.x;
  f32x4 zf = {0.f, 0.f, 0.f, 0.f};

  // ---- pass 1 ----
  f32x4 acc[4][2];
#pragma unroll
  for (int mt = 0; mt < 4; mt++){ acc[mt][0] = zf; acc[mt][1] = zf; }

#pragma unroll
  for (int ktp = 0; ktp < 3; ktp++){      // x-uint window 16*ktp..+16
    int off = 16*ktp + 4*g;
    uint4 bg0 = *(const uint4*)(bf1 + (((ktp  )*2 + 0)*64 + lane)*4);
    uint4 bg1 = *(const uint4*)(bf1 + (((ktp  )*2 + 1)*64 + lane)*4);
    uint4 ba0 = *(const uint4*)(bf1 + (((ktp+3)*2 + 0)*64 + lane)*4);
    uint4 ba1 = *(const uint4*)(bf1 + (((ktp+3)*2 + 1)*64 + lane)*4);
#pragma unroll
    for (int mt = 0; mt < 4; mt++){
      uint4 xs4 = *(const uint4*)(xsP[mt] + off);
      uint4 xd4 = *(const uint4*)(xdP[mt] + off);
      uint4 waA = *(const uint4*)(rAm[mt] + off);
      uint4 waB = *(const uint4*)(rBm[mt] + off);
      uint4 wbA = *(const uint4*)(rAm[mt] + 48 + off);
      uint4 wbB = *(const uint4*)(rBm[mt] + 48 + off);
      h2f tf = tfm[mt];
      uint4 fg, fa;
      fg.x = h2u(u2h(lerp2(waA.x, waB.x, tf)) * ((u2h(xd4.x) - u2h(xs4.x)) * c32));
      fg.y = h2u(u2h(lerp2(waA.y, waB.y, tf)) * ((u2h(xd4.y) - u2h(xs4.y)) * c32));
      fg.z = h2u(u2h(lerp2(waA.z, waB.z, tf)) * ((u2h(xd4.z) - u2h(xs4.z)) * c32));
      fg.w = h2u(u2h(lerp2(waA.w, waB.w, tf)) * ((u2h(xd4.w) - u2h(xs4.w)) * c32));
      fa.x = h2u(u2h(lerp2(wbA.x, wbB.x, tf)) * ((u2h(xd4.x) + u2h(xs4.x)) * c64));
      fa.y = h2u(u2h(lerp2(wbA.y, wbB.y, tf)) * ((u2h(xd4.y) + u2h(xs4.y)) * c64));
      fa.z = h2u(u2h(lerp2(wbA.z, wbB.z, tf)) * ((u2h(xd4.z) + u2h(xs4.z)) * c64));
      fa.w = h2u(u2h(lerp2(wbA.w, wbB.w, tf)) * ((u2h(xd4.w) + u2h(xs4.w)) * c64));
      acc[mt][0] = __builtin_amdgcn_mfma_f32_16x16x32_f16(u4h8(fg), u4h8(bg0), acc[mt][0], 0, 0, 0);
      acc[mt][1] = __builtin_amdgcn_mfma_f32_16x16x32_f16(u4h8(fg), u4h8(bg1), acc[mt][1], 0, 0, 0);
      acc[mt][0] = __builtin_amdgcn_mfma_f32_16x16x32_f16(u4h8(fa), u4h8(ba0), acc[mt][0], 0, 0, 0);
      acc[mt][1] = __builtin_amdgcn_mfma_f32_16x16x32_f16(u4h8(fa), u4h8(ba1), acc[mt][1], 0, 0, 0);
    }
  }

  // ---- gelu + transpose hdg (D layout -> row-major LDS -> A-frags) ----
#pragma unroll
  for (int mt = 0; mt < 4; mt++)
#pragma unroll
    for (int nt = 0; nt < 2; nt++)
#pragma unroll
      for (int i = 0; i < 4; i++){
        float v = geluf(32.f * acc[mt][nt][i]) * 0.015625f;
        float o = __shfl_xor(v, 1);
        if (!(lane & 1))
          wb[(16*mt + 4*g + i)*17 + 8*nt + (r15 >> 1)] = pack2(v, o);
      }
  wsync();
  uint4 af[4];
#pragma unroll
  for (int mt = 0; mt < 4; mt++){
    int row = 16*mt + r15;
    af[mt].x = wb[row*17 + 4*g + 0];
    af[mt].y = wb[row*17 + 4*g + 1];
    af[mt].z = wb[row*17 + 4*g + 2];
    af[mt].w = wb[row*17 + 4*g + 3];
  }
  wsync();

  // ---- pass 2: per 16-col block np (cols 16np.. and 96+16np..) ----
  unsigned int* prow = (unsigned int*)(pbuf + (long)p * 96);
  unsigned int* qrow = (unsigned int*)(qbuf + (long)qq * 96);
  for (int np = 0; np < 6; np++){
    uint4 b1 = *(const uint4*)(bf2 + ((np    )*64 + lane)*4);
    uint4 b2 = *(const uint4*)(bf2 + ((np + 6)*64 + lane)*4);
    f32x4 d1a[4], d2a[4];
#pragma unroll
    for (int mt = 0; mt < 4; mt++){
      d1a[mt] = __builtin_amdgcn_mfma_f32_16x16x32_f16(u4h8(af[mt]), u4h8(b1), zf, 0, 0, 0);
      d2a[mt] = __builtin_amdgcn_mfma_f32_16x16x32_f16(u4h8(af[mt]), u4h8(b2), zf, 0, 0, 0);
    }
#pragma unroll
    for (int mt = 0; mt < 4; mt++)
#pragma unroll
      for (int i = 0; i < 4; i++){
        float v1 = d1a[mt][i], v2 = d2a[mt][i];
        float o1 = __shfl_xor(v1, 1);
        float o2 = __shfl_xor(v2, 1);
        if (!(lane & 1)){
          int r = 16*mt + 4*g + i;
          wb[r*17 + (r15 >> 1)]     = pack2(v1, o1);
          wb[r*17 + 8 + (r15 >> 1)] = pack2(v2, o2);
        }
      }
    wsync();
    unsigned int d1u[8], d2u[8];
#pragma unroll
    for (int u = 0; u < 8; u++){
      d1u[u] = wb[lane*17 + u];
      d2u[u] = wb[lane*17 + 8 + u];
    }
    wsync();
    // Wc lerp for own edge: c1 = Wc[16np+..], c2 = Wc[96+16np+..]
    uint4 ca0 = *(const uint4*)(rAo + 96  + 8*np);
    uint4 ca1 = *(const uint4*)(rAo + 100 + 8*np);
    uint4 cb0 = *(const uint4*)(rBo + 96  + 8*np);
    uint4 cb1 = *(const uint4*)(rBo + 100 + 8*np);
    uint4 ka0 = *(const uint4*)(rAo + 144 + 8*np);
    uint4 ka1 = *(const uint4*)(rAo + 148 + 8*np);
    uint4 kb0 = *(const uint4*)(rBo + 144 + 8*np);
    uint4 kb1 = *(const uint4*)(rBo + 148 + 8*np);
    unsigned int c1u[8] = {lerp2(ca0.x,cb0.x,tfo), lerp2(ca0.y,cb0.y,tfo),
                           lerp2(ca0.z,cb0.z,tfo), lerp2(ca0.w,cb0.w,tfo),
                           lerp2(ca1.x,cb1.x,tfo), lerp2(ca1.y,cb1.y,tfo),
                           lerp2(ca1.z,cb1.z,tfo), lerp2(ca1.w,cb1.w,tfo)};
    unsigned int c2u[8] = {lerp2(ka0.x,kb0.x,tfo), lerp2(ka0.y,kb0.y,tfo),
                           lerp2(ka0.z,kb0.z,tfo), lerp2(ka0.w,kb0.w,tfo),
                           lerp2(ka1.x,kb1.x,tfo), lerp2(ka1.y,kb1.y,tfo),
                           lerp2(ka1.z,kb1.z,tfo), lerp2(ka1.w,kb1.w,tfo)};
    unsigned int pv[8], qv[8];
#pragma unroll
    for (int u = 0; u < 8; u++){
      h2f t1 = u2h(c1u[u]) * u2h(d1u[u]);            // dv (true/64)
      h2f t2 = (u2h(c2u[u]) * u2h(d2u[u])) * h05;    // av (true/64)
      pv[u] = h2u(t1 + t2);
      qv[u] = h2u(t2 - t1);
    }
    *(uint4*)(prow + 8*np)     = *(uint4*)(pv);
    *(uint4*)(prow + 8*np + 4) = *(uint4*)(pv + 4);
    *(uint4*)(qrow + 8*np)     = *(uint4*)(qv);
    *(uint4*)(qrow + 8*np + 4) = *(uint4*)(qv + 4);
  }
}

// fused gather + node update + xnh repack; uint2-vectorized, 10 nodes/block
__global__ __launch_bounds__(256) void gather_upd(
    const int* __restrict__ doff, const int* __restrict__ soff,
    const unsigned short* __restrict__ pbuf, const unsigned short* __restrict__ qbuf,
    float* __restrict__ xn, unsigned int* __restrict__ xnh)
{
  int g = threadIdx.x / 24;
  int c4 = threadIdx.x - 24 * g;     // 4-half group within 96-half row
  if (g >= 10) return;
  int n = blockIdx.x * 10 + g;
  if (n >= NN) return;
  const uint2* p2 = (const uint2*)pbuf;   // row = 24 uint2
  const uint2* q2 = (const uint2*)qbuf;
  float a0 = 0.f, a1 = 0.f, a2 = 0.f, a3 = 0.f;
  int d1 = doff[n+1];
  for (int p = doff[n]; p < d1; p++){
    uint2 v = p2[(long)p * 24 + c4];
    h2f lo = u2h(v.x), hi = u2h(v.y);
    a0 += (float)lo.x; a1 += (float)lo.y; a2 += (float)hi.x; a3 += (float)hi.y;
  }
  int s1 = soff[n+1];
  for (int q = soff[n]; q < s1; q++){
    uint2 v = q2[(long)q * 24 + c4];
    h2f lo = u2h(v.x), hi = u2h(v.y);
    a0 += (float)lo.x; a1 += (float)lo.y; a2 += (float)hi.x; a3 += (float)hi.y;
  }
  float4 xo = *(float4*)(xn + (long)n * 96 + 4*c4);
  xo.x -= 6.4f * a0; xo.y -= 6.4f * a1; xo.z -= 6.4f * a2; xo.w -= 6.4f * a3;
  *(float4*)(xn + (long)n * 96 + 4*c4) = xo;
  uint2 w; w.x = pack2(xo.x, xo.y); w.y = pack2(xo.z, xo.w);
  *(uint2*)(xnh + n * 48 + 2*c4) = w;
}

// ---------------- column sum over nodes -------------------------------------
__global__ void colsum(const float* __restrict__ xn, float* __restrict__ nodesum){
  int col = threadIdx.x % 96;
  int seg = threadIdx.x / 96;
  int stripe = blockIdx.x * 2 + seg;   // 0..399
  float acc = 0.f;
  for (int n = stripe; n < NN; n += 400) acc += xn[(long)n * 96 + col];
  unsafeAtomicAdd(nodesum + col, acc);
}

// ---------------- project to 16 outputs, scale, fp32 store ------------------
__global__ void project(const float* __restrict__ nodesum, const float* __restrict__ siT,
                        float* __restrict__ out){
  int j = threadIdx.x;
  if (j < 16){
    float a = 0.f;
#pragma unroll
    for (int c = 0; c < 96; c++) a += nodesum[c] * siT[j*96 + c];
    out[j] = a * 0.007071067811865475f;   // 1/sqrt(20000)
  }
}

// ---------------- host side -------------------------------------------------
extern "C" void kernel_launch(void* const* d_in, const int* in_sizes, int n_in,
                              void* d_out, int out_size, void* d_ws, size_t ws_size,
                              hipStream_t stream){
  const float* pos  = (const float*)d_in[0];
  const int* atom_z = (const int*)d_in[1];
  const int* esrc   = (const int*)d_in[2];
  const int* edst   = (const int*)d_in[3];

  float* ws      = (float*)d_ws;
  float* xn      = ws;                  // 1,920,000
  float* nodesum = ws + 1920000;        // 96
  float* WB      = ws + 1920096;        // 4,128 fp32 weights
  unsigned int* bf1   = (unsigned int*)(ws + 1924224);  // 6,144
  unsigned int* bf2   = (unsigned int*)(ws + 1930368);  // 6,144
  unsigned int* lutL  = (unsigned int*)(ws + 1936512);  // 786,432 (3 MB)
  unsigned int* lut01 = (unsigned int*)(ws + 2722944);  // 65,536
  unsigned int* xnh   = (unsigned int*)(ws + 2788480);  // 960,000 (f16 rows)
  float* els    = ws + 3748480;                 // 320,000 edge lengths
  int*   cntd   = (int*)(ws + 4068480);         // 20,000
  int*   cnts   = cntd + 20000;                 // 20,000 (contiguous for 1 memset)
  int*   curd   = cnts + 20000;                 // 20,000
  int*   curs   = curd + 20000;                 // 20,000
  int*   doff   = curs + 20000;                 // 20,004
  int*   soff   = doff + 20004;                 // 20,004  -> ends 4,188,488
  int*   srcS   = soff + 20004;                 // 320,000 -> ends 4,508,488
  int*   dstS   = srcS + 320000;                // 320,000 -> ends 4,828,488
  int*   qpos   = dstS + 320000;                // 320,000 -> ends 5,148,488
  // buffers at verified round-10/11/12 offsets (>= 5,468,496 > int arrays):
  //   pbufL: [ 5,468,496 .. 20,828,496)   qbufL: [20,828,496 .. 36,188,496)
  //   pbuf0: [ 5,468,496 .. 15,708,496)   qbuf0: [15,708,496 .. 25,948,496)
  // (init aliases layer space CROSS-PHASE only; init-phase disjoint.)
  // end = 36,188,496 floats = 144.8 MB
  unsigned short* pbufL = (unsigned short*)(ws + 5468496);
  unsigned short* qbufL = (unsigned short*)(ws + 20828496);
  unsigned short* pbuf0 = (unsigned short*)(ws + 5468496);
  unsigned short* qbuf0 = (unsigned short*)(ws + 15708496);

  float* embedF = WB + 0;        // 160
  float* dl0w1T = WB + 160;      // 256   [32][8]
  float* dl0w2T = WB + 416;      // 1024  [32][32]
  float* dl1w1T = WB + 1440;     // 128   [32][4]
  float* dl1w2T = WB + 1568;     // 1024  [32][32]
  float* siT    = WB + 2592;     // 1536  [16][96]

  hipMemsetAsync(cntd, 0, 40000 * 4, stream);
  hipMemsetAsync(nodesum, 0, 96 * 4, stream);

  TTab tb;
  int ti = 0;
  auto add = [&](const void* s, float* dst, int R, int C, int tr){
    tb.e[ti].src = (const float*)s; tb.e[ti].dst = dst;
    tb.e[ti].R = R; tb.e[ti].C = C; tb.e[ti].trans = tr; ti++;
  };
  add(d_in[4],  embedF, 20, 8, 0);
  add(d_in[5],  dl0w1T, 8, 32, 1);
  add(d_in[6],  dl0w2T, 32, 32, 1);
  add(d_in[7],  dl1w1T, 4, 32, 1);
  add(d_in[8],  dl1w2T, 32, 32, 1);
  add(d_in[17], siT, 96, 16, 1);

  // weight prep (convw + MFMA B-fragment pack + both LUTs) in one launch
  prep_k<<<7 + 2*NT + (NT + 5)/6, 384, 0, stream>>>(
      tb, (const float*)d_in[11], (const float*)d_in[12],
      (const float*)d_in[13], (const float*)d_in[14], (unsigned short*)lutL,
      (const float*)d_in[9], (const float*)d_in[10], (unsigned short*)lut01,
      (const float*)d_in[15], (const float*)d_in[16], bf1, bf2);
  countnode_k<<<NE/256 + (NN + 255)/256, 256, 0, stream>>>(
      esrc, edst, cntd, cnts, atom_z, embedF, dl0w1T, dl0w2T, xn);
  prefix_k<<<2, 1024, 0, stream>>>(cntd, doff, curd, cnts, soff, curs);
  fill_comb<<<(NE + 255)/256, 256, 0, stream>>>(esrc, edst, curd, curs,
                                                srcS, dstS, qpos);
  edge_init<<<(NE + 255)/256, 256, 0, stream>>>(
      pos, srcS, dstS, qpos, els, pbuf0, qbuf0, dl1w1T, dl1w2T, lut01);
  gather_init<<<(NN + 15)/16, 256, 0, stream>>>(doff, soff, pbuf0, qbuf0, xn, xnh);

  for (int i = 0; i < 2; i++){
    layer_k<<<NE/256, 256, 0, stream>>>(
        srcS, dstS, qpos, els, xnh, pbufL, qbufL,
        lutL + (long)i * NT * 192, bf1 + i*3072, bf2 + i*3072);
    gather_upd<<<(NN + 9)/10, 256, 0, stream>>>(doff, soff, pbufL, qbufL,
                                                xn, xnh);
  }
  colsum<<<200, 192, 0, stream>>>(xn, nodesum);
  project<<<1, 64, 0, stream>>>(nodesum, siT, (float*)d_out);
}

// Round 14
// 646.667 us; speedup vs baseline: 1.5797x; 1.0061x over previous
//
#include <hip/hip_runtime.h>
#include <hip/hip_bf16.h>

#define NN 20000
#define NE 320000
#define NT 2048            // filter LUT entries over len in [0, 1.7321]

typedef _Float16 h2f __attribute__((ext_vector_type(2)));
typedef _Float16 f16x8 __attribute__((ext_vector_type(8)));
typedef float f32x4 __attribute__((ext_vector_type(4)));

__device__ __forceinline__ h2f u2h(unsigned int u){
  union { unsigned int u; h2f h; } v; v.u = u; return v.h;
}
__device__ __forceinline__ unsigned int h2u(h2f h){
  union { h2f h; unsigned int u; } v; v.h = h; return v.u;
}
__device__ __forceinline__ unsigned int pack2(float a, float b){
  h2f h; h.x = (_Float16)a; h.y = (_Float16)b;
  union { h2f h; unsigned int u; } v; v.h = h; return v.u;
}
__device__ __forceinline__ unsigned short f16b(float a){
  union { _Float16 h; unsigned short u; } v; v.h = (_Float16)a; return v.u;
}
__device__ __forceinline__ f16x8 u4h8(uint4 u){
  union { uint4 u; f16x8 h; } v; v.u = u; return v.h;
}
// packed f16 lerp: a + t*(b-a)
__device__ __forceinline__ unsigned int lerp2(unsigned int a, unsigned int b, h2f t){
  h2f ha = u2h(a), hb = u2h(b);
  return h2u(ha + t * (hb - ha));
}

// jax.nn.gelu default (approximate=True): 0.5x(1+tanh(t)) == x*sigmoid(2t)
__device__ __forceinline__ float geluf(float x){
  float t = 0.7978845608028654f * x * (1.0f + 0.044715f * x * x);
  return x / (1.0f + __expf(-2.0f * t));
}

// wave-local LDS fence: wave owns its smem; DS ops per wave execute in issue
// order, so only COMPILER reordering must be prevented.
__device__ __forceinline__ void wsync(){
  asm volatile("" ::: "memory");
  __builtin_amdgcn_sched_barrier(0);
}

struct TEnt { const float* src; float* dst; int R; int C; int trans; };
struct TTab { TEnt e[8]; };

__device__ __forceinline__ void lut_basis(int ent, float* b){
  float len = fmaxf((float)ent * (1.7321f / (float)(NT - 1)), 1e-6f);
  float sc = 3.1622776601683795f / fmaxf(len, 1e-6f);  // sqrt(2/MAXR)*sqrt(B)/r
#pragma unroll
  for (int k = 0; k < 10; k++)
    b[k] = sinf((float)(k + 1) * 1.5707963267948966f * len) * sc;
}

// ---------------- merged weight prep ----------------------------------------
// blocks: [0,6) convw, 6 = B-fragment pack, [7,7+2NT) layer LUT, rest init LUT
__global__ __launch_bounds__(384) void prep_k(
    TTab tb,
    const float* __restrict__ fABw1, const float* __restrict__ fABw2,
    const float* __restrict__ fCw1,  const float* __restrict__ fCw2,
    unsigned short* __restrict__ lutH,
    const float* __restrict__ f01w1, const float* __restrict__ f01w2,
    unsigned short* __restrict__ lut01H,
    const float* __restrict__ dlw1, const float* __restrict__ dlw2,
    unsigned int* __restrict__ bf1, unsigned int* __restrict__ bf2)
{
  int b = blockIdx.x;
  int t = threadIdx.x;
  if (b < 6){
    TEnt en = tb.e[b];
    int n = en.R * en.C;
    for (int i = t; i < n; i += 384){
      float v = en.src[i];
      if (en.trans){
        int r = i / en.C, c = i - r * en.C;
        en.dst[c * en.R + r] = v;
      } else {
        en.dst[i] = v;
      }
    }
    return;
  }
  if (b == 6){
    for (int i = t; i < 12288; i += 384){
      if (i < 6144){
        int v = i & 3, ln = (i >> 2) & 63;
        int nt = (i >> 8) & 1;
        int ktly = i >> 9;            // ly*6 + kt
        int kt = ktly % 6, ly = ktly / 6;
        int k = 32*kt + 8*(ln >> 4) + 2*v;
        int col = 16*nt + (ln & 15);
        const float* s = dlw1 + ly*6144;       // [192][32]
        bf1[i] = pack2(s[k*32 + col], s[(k+1)*32 + col]);
      } else {
        int j = i - 6144;
        int v = j & 3, ln = (j >> 2) & 63;
        int ntly = j >> 8;            // ly*12 + nt
        int nt = ntly % 12, ly = ntly / 12;
        int k = 8*(ln >> 4) + 2*v;
        int col = 16*nt + (ln & 15);
        const float* s = dlw2 + ly*6144;       // [32][192]
        bf2[j] = pack2(s[k*192 + col], s[(k+1)*192 + col]);
      }
    }
    return;
  }
  if (b < 7 + 2*NT){
    int bb = b - 7;
    int ent = bb & (NT - 1);
    int layer = bb >> 11;       // NT = 2048
    float bas[10];
    lut_basis(ent, bas);
    __shared__ float h[192];
    if (t < 192){
      int f = t >> 6, l = t & 63;       // f: 0=A, 1=B, 2=C
      const float* w1 = (f < 2) ? (fABw1 + (layer*2 + f) * 640)
                                : (fCw1 + layer * 640);
      float a = 0.f;
#pragma unroll
      for (int k = 0; k < 10; k++) a += bas[k] * w1[k*64 + l];
      h[t] = geluf(a);
    }
    __syncthreads();
    float a = 0.f;
    if (t < 192){
      int f = t / 96, j = t - 96 * f;
      const float* w2 = fABw2 + (layer*2 + f) * 6144;
      for (int l = 0; l < 64; l++) a += h[f*64 + l] * w2[l*96 + j];
    } else {
      int j = t - 192;
      const float* w2 = fCw2 + layer * 12288;
      for (int l = 0; l < 64; l++) a += h[128 + l] * w2[l*192 + j];
    }
    lutH[((long)(layer * NT + ent)) * 384 + t] = f16b(a);
    return;
  }
  // init LUT: 6 entries per block (384 = 6*64 threads)
  int blk = b - 7 - 2*NT;
  int ent = blk * 6 + (t >> 6);
  if (ent >= NT) return;
  int tl = t & 63;
  int p = tl >> 5, jj = tl & 31;
  float bas[10];
  lut_basis(ent, bas);
  const float* w1 = f01w1 + p * 640;
  const float* w2 = f01w2 + p * 2048;
  float W = 0.f;
  for (int l = 0; l < 64; l++){
    float a = 0.f;
#pragma unroll
    for (int k = 0; k < 10; k++) a += bas[k] * w1[k*64 + l];
    W += geluf(a) * w2[l*32 + jj];
  }
  lut01H[(long)ent * 64 + tl] = f16b(W);
}

// ---------------- merged: edge degree count + node init ---------------------
__global__ __launch_bounds__(256) void countnode_k(
    const int* __restrict__ esrc, const int* __restrict__ edst,
    int* __restrict__ cntd, int* __restrict__ cnts,
    const int* __restrict__ az, const float* __restrict__ embedF,
    const float* __restrict__ w1T /*[32][8]*/, const float* __restrict__ w2T /*[32][32]*/,
    float* __restrict__ xn)
{
  if (blockIdx.x < NE/256){
    int e = blockIdx.x * 256 + threadIdx.x;
    atomicAdd(cntd + edst[e], 1);
    atomicAdd(cnts + esrc[e], 1);
    return;
  }
  int n = (blockIdx.x - NE/256) * 256 + threadIdx.x;
  if (n >= NN) return;
  int z = az[n];
  float ee[8];
#pragma unroll
  for (int k = 0; k < 8; k++) ee[k] = embedF[z * 8 + k];
  float hid[32];
#pragma unroll
  for (int l = 0; l < 32; l++){
    float a = 0.f;
#pragma unroll
    for (int k = 0; k < 8; k++) a += ee[k] * w1T[l * 8 + k];
    hid[l] = geluf(a);
  }
  float* row = xn + (long)n * 96;
#pragma unroll
  for (int j = 0; j < 32; j++){
    float a = 0.f;
#pragma unroll
    for (int l = 0; l < 32; l++) a += hid[l] * w2T[j * 32 + l];
    row[j] = a;
  }
#pragma unroll
  for (int j = 32; j < 96; j++) row[j] = 0.f;
}

// ---------------- both prefix sums in one launch ----------------------------
__global__ __launch_bounds__(1024) void prefix_k(
    const int* __restrict__ cntd, int* __restrict__ doff, int* __restrict__ curd,
    const int* __restrict__ cnts, int* __restrict__ soff, int* __restrict__ curs)
{
  const int* cnt = blockIdx.x ? cnts : cntd;
  int* off = blockIdx.x ? soff : doff;
  int* cur = blockIdx.x ? curs : curd;
  __shared__ int part[1024];
  int t = threadIdx.x;
  int base = t * 20;
  int s = 0;
  for (int i = 0; i < 20; i++){ int idx = base + i; if (idx < NN) s += cnt[idx]; }
  part[t] = s; __syncthreads();
  for (int d = 1; d < 1024; d <<= 1){
    int v = (t >= d) ? part[t - d] : 0;
    __syncthreads();
    part[t] += v;
    __syncthreads();
  }
  int run = (t == 0) ? 0 : part[t - 1];
  for (int i = 0; i < 20; i++){
    int idx = base + i;
    if (idx < NN){ off[idx] = run; cur[idx] = run; run += cnt[idx]; }
  }
  if (t == 0) off[NN] = NE;
}

// p = dst-sorted slot of edge e; q = src-sorted slot; qpos[p]=q
__global__ void fill_comb(const int* __restrict__ esrc, const int* __restrict__ edst,
                          int* __restrict__ curd, int* __restrict__ curs,
                          int* __restrict__ srcS, int* __restrict__ dstS,
                          int* __restrict__ qpos){
  int e = blockIdx.x * 256 + threadIdx.x;
  if (e >= NE) return;
  int s = esrc[e], d = edst[e];
  int p = atomicAdd(curd + d, 1);
  srcS[p] = s; dstS[p] = d;
  int q = atomicAdd(curs + s, 1);
  qpos[p] = q;
}

// ---------------- edge init: p-row (dst side) + scattered q-row (src side) --
__global__ __launch_bounds__(256) void edge_init(
    const float* __restrict__ pos, const int* __restrict__ srcS,
    const int* __restrict__ dstS, const int* __restrict__ qpos,
    float* __restrict__ els,
    unsigned short* __restrict__ pbuf0, unsigned short* __restrict__ qbuf0,
    const float* __restrict__ w1T /*dl1w1T [32][4]*/, const float* __restrict__ w2T /*[32][32]*/,
    const unsigned int* __restrict__ lut01)
{
  int p = blockIdx.x * 256 + threadIdx.x;
  if (p >= NE) return;
  int s = srcS[p], d = dstS[p];
  float x = pos[s*3+0] - pos[d*3+0];
  float y = pos[s*3+1] - pos[d*3+1];
  float z = pos[s*3+2] - pos[d*3+2];
  float L = sqrtf(x*x + y*y + z*z + 1e-12f);
  float iv = 1.0f / fmaxf(L, 1e-6f);
  els[p] = L;

  float u = L - 2.0f;   // 2*(len/MAXR - 1), MAXR=2
  float cut = 0.5f * (1.0f - cosf(3.14159265358979323f * u));
  cut = (u > 0.0f) ? 0.0f : cut;
  cut = (u < -1.0f) ? 1.0f : cut;
  float xe0 = cut, cc = cut * 1.7320508075688772f * iv;
  float xe1 = cc*x, xe2 = cc*y, xe3 = cc*z;
  float hid[32];
#pragma unroll
  for (int l = 0; l < 32; l++){
    float a = xe0*w1T[l*4+0] + xe1*w1T[l*4+1] + xe2*w1T[l*4+2] + xe3*w1T[l*4+3];
    hid[l] = geluf(a);
  }
  float xeh[32];
#pragma unroll
  for (int j = 0; j < 32; j++){
    float a = 0.f;
#pragma unroll
    for (int l = 0; l < 32; l++) a += hid[l] * w2T[j*32 + l];
    xeh[j] = a;
  }
  float tt = fminf(L * ((float)(NT-1) / 1.7321f), (float)(NT-1) - 0.001f);
  int i0 = (int)tt; float tfv = tt - (float)i0;
  h2f tf2; tf2.x = (_Float16)tfv; tf2.y = tf2.x;
  h2f h05; h05.x = (_Float16)0.5f; h05.y = h05.x;
  const unsigned int* rA = lut01 + i0 * 32;
  const unsigned int* rB = rA + 32;

  unsigned int xp[16];
#pragma unroll
  for (int jp = 0; jp < 16; jp++)
    xp[jp] = pack2(xeh[2*jp] * 0.0625f, xeh[2*jp+1] * 0.0625f);

  unsigned int du[16], au[16];
#pragma unroll
  for (int q = 0; q < 4; q++){
    uint4 a = ((const uint4*)rA)[q];
    uint4 b = ((const uint4*)rB)[q];
    du[4*q+0] = h2u(u2h(lerp2(a.x, b.x, tf2)) * u2h(xp[4*q+0]));
    du[4*q+1] = h2u(u2h(lerp2(a.y, b.y, tf2)) * u2h(xp[4*q+1]));
    du[4*q+2] = h2u(u2h(lerp2(a.z, b.z, tf2)) * u2h(xp[4*q+2]));
    du[4*q+3] = h2u(u2h(lerp2(a.w, b.w, tf2)) * u2h(xp[4*q+3]));
  }
#pragma unroll
  for (int q = 0; q < 4; q++){
    uint4 a = ((const uint4*)(rA + 16))[q];
    uint4 b = ((const uint4*)(rB + 16))[q];
    au[4*q+0] = h2u(u2h(lerp2(a.x, b.x, tf2)) * u2h(xp[4*q+0]) * h05);
    au[4*q+1] = h2u(u2h(lerp2(a.y, b.y, tf2)) * u2h(xp[4*q+1]) * h05);
    au[4*q+2] = h2u(u2h(lerp2(a.z, b.z, tf2)) * u2h(xp[4*q+2]) * h05);
    au[4*q+3] = h2u(u2h(lerp2(a.w, b.w, tf2)) * u2h(xp[4*q+3]) * h05);
  }
  unsigned short* prow = pbuf0 + (long)p * 64;
  unsigned short* qrow = qbuf0 + (long)qpos[p] * 64;
#pragma unroll
  for (int q = 0; q < 4; q++){
    ((uint4*)prow)[q]      = ((uint4*)du)[q];
    ((uint4*)(prow+32))[q] = ((uint4*)au)[q];
  }
  unsigned int nd[16];
#pragma unroll
  for (int i = 0; i < 16; i++) nd[i] = du[i] ^ 0x80008000u;  // negate packed f16
#pragma unroll
  for (int q = 0; q < 4; q++){
    ((uint4*)qrow)[q]      = ((uint4*)nd)[q];
    ((uint4*)(qrow+32))[q] = ((uint4*)au)[q];
  }
}

// 16 nodes per 256-thread block, 16 threads/node, uint2-vectorized streams
__global__ __launch_bounds__(256) void gather_init(
    const int* __restrict__ doff, const int* __restrict__ soff,
    const unsigned short* __restrict__ pbuf0, const unsigned short* __restrict__ qbuf0,
    float* __restrict__ xn, unsigned int* __restrict__ xnh)
{
  int g = threadIdx.x >> 4;          // 0..15
  int c4 = threadIdx.x & 15;         // 4-half group within 64-half row
  int n = blockIdx.x * 16 + g;
  if (n >= NN) return;
  const uint2* p2 = (const uint2*)pbuf0;   // row = 16 uint2
  const uint2* q2 = (const uint2*)qbuf0;
  float a0 = 0.f, a1 = 0.f, a2 = 0.f, a3 = 0.f;
  int d1 = doff[n+1];
  for (int p = doff[n]; p < d1; p++){
    uint2 v = p2[(long)p * 16 + c4];
    h2f lo = u2h(v.x), hi = u2h(v.y);
    a0 += (float)lo.x; a1 += (float)lo.y; a2 += (float)hi.x; a3 += (float)hi.y;
  }
  int s1 = soff[n+1];
  for (int q = soff[n]; q < s1; q++){
    uint2 v = q2[(long)q * 16 + c4];
    h2f lo = u2h(v.x), hi = u2h(v.y);
    a0 += (float)lo.x; a1 += (float)lo.y; a2 += (float)hi.x; a3 += (float)hi.y;
  }
  float4 v4; v4.x = 16.f*a0; v4.y = 16.f*a1; v4.z = 16.f*a2; v4.w = 16.f*a3;
  *(float4*)(xn + (long)n * 96 + 32 + 4*c4) = v4;   // cols 32..95
  uint2 w; w.x = pack2(v4.x, v4.y); w.y = pack2(v4.z, v4.w);
  *(uint2*)(xnh + n * 48 + 16 + 2*c4) = w;
  if (c4 < 8){
    float4 t = *(const float4*)(xn + (long)n * 96 + 4*c4);
    uint2 w0; w0.x = pack2(t.x, t.y); w0.y = pack2(t.z, t.w);
    *(uint2*)(xnh + n * 48 + 2*c4) = w0;
  }
}

// ---------------- conv layer via MFMA: ONE WAVE PER BLOCK -------------------
// r14 change: 64-thread blocks (grid NE/64). Waves are fully independent
// (wave-local smem + wsync), so 1-wave blocks let the CU scheduler pack
// occupancy without 4-wave block granularity/tail effects.
// Per wave: 64 edges. pass1 hd[64][32] = G[64][192] @ dw1; pass2 d = hdg @ dw2.
// A-frag: lane -> row (lane&15)+16mt, k = 8*(lane>>4)+j
// B-frag: lane -> col (lane&15)+16nt, k = 8*(lane>>4)+j (pre-packed bf1/bf2)
// C/D:    lane -> col (lane&15), row = 4*(lane>>4)+reg
// p-row -> pbuf[p]; q-row -> qbuf[qpos[p]] (scatter; gather streams both sides)
__global__ __launch_bounds__(64) void layer_k(
    const int* __restrict__ srcS, const int* __restrict__ dstS,
    const int* __restrict__ qpos,
    const float* __restrict__ els, const unsigned int* __restrict__ xnh,
    unsigned short* __restrict__ pbuf, unsigned short* __restrict__ qbuf,
    const unsigned int* __restrict__ lut,
    const unsigned int* __restrict__ bf1, const unsigned int* __restrict__ bf2)
{
  __shared__ unsigned int wb[1092];   // [64][17]-uint image, one wave
  int lane = threadIdx.x;
  int g = lane >> 4, r15 = lane & 15;
  int wbase = blockIdx.x * 64;

  // per-mt metadata (fragment-side edges: re = wbase + 16mt + r15)
  const unsigned int* xsP[4]; const unsigned int* xdP[4];
  const unsigned int* rAm[4]; const unsigned int* rBm[4];
  h2f tfm[4];
#pragma unroll
  for (int mt = 0; mt < 4; mt++){
    int re = wbase + 16*mt + r15;
    xsP[mt] = xnh + srcS[re] * 48;
    xdP[mt] = xnh + dstS[re] * 48;
    float L = els[re];
    float tt = fminf(L * ((float)(NT-1) / 1.7321f), (float)(NT-1) - 0.001f);
    int i0 = (int)tt; float tfv = tt - (float)i0;
    h2f tf; tf.x = (_Float16)tfv; tf.y = tf.x;
    tfm[mt] = tf;
    rAm[mt] = lut + (long)i0 * 192;
    rBm[mt] = rAm[mt] + 192;
  }
  // own-edge metadata (output row p = wbase + lane)
  int p = wbase + lane;
  int qq = qpos[p];
  const unsigned int *rAo, *rBo; h2f tfo;
  {
    float L = els[p];
    float tt = fminf(L * ((float)(NT-1) / 1.7321f), (float)(NT-1) - 0.001f);
    int i0 = (int)tt; float tfv = tt - (float)i0;
    tfo.x = (_Float16)tfv; tfo.y = tfo.x;
    rAo = lut + (long)i0 * 192;
    rBo = rAo + 192;
  }
  h2f c32; c32.x = (_Float16)0.03125f;  c32.y = c32.x;
  h2f c64; c64.x = (_Float16)0.015625f; c64.y = c64.x;
  h2f h05; h05.x = (_Float16)0.5f;      h05.y = h05.x;
  f32x4 zf = {0.f, 0.f, 0.f, 0.f};

  // ---- pass 1 ----
  f32x4 acc[4][2];
#pragma unroll
  for (int mt = 0; mt < 4; mt++){ acc[mt][0] = zf; acc[mt][1] = zf; }

#pragma unroll
  for (int ktp = 0; ktp < 3; ktp++){      // x-uint window 16*ktp..+16
    int off = 16*ktp + 4*g;
    uint4 bg0 = *(const uint4*)(bf1 + (((ktp  )*2 + 0)*64 + lane)*4);
    uint4 bg1 = *(const uint4*)(bf1 + (((ktp  )*2 + 1)*64 + lane)*4);
    uint4 ba0 = *(const uint4*)(bf1 + (((ktp+3)*2 + 0)*64 + lane)*4);
    uint4 ba1 = *(const uint4*)(bf1 + (((ktp+3)*2 + 1)*64 + lane)*4);
#pragma unroll
    for (int mt = 0; mt < 4; mt++){
      uint4 xs4 = *(const uint4*)(xsP[mt] + off);
      uint4 xd4 = *(const uint4*)(xdP[mt] + off);
      uint4 waA = *(const uint4*)(rAm[mt] + off);
      uint4 waB = *(const uint4*)(rBm[mt] + off);
      uint4 wbA = *(const uint4*)(rAm[mt] + 48 + off);
      uint4 wbB = *(const uint4*)(rBm[mt] + 48 + off);
      h2f tf = tfm[mt];
      uint4 fg, fa;
      fg.x = h2u(u2h(lerp2(waA.x, waB.x, tf)) * ((u2h(xd4.x) - u2h(xs4.x)) * c32));
      fg.y = h2u(u2h(lerp2(waA.y, waB.y, tf)) * ((u2h(xd4.y) - u2h(xs4.y)) * c32));
      fg.z = h2u(u2h(lerp2(waA.z, waB.z, tf)) * ((u2h(xd4.z) - u2h(xs4.z)) * c32));
      fg.w = h2u(u2h(lerp2(waA.w, waB.w, tf)) * ((u2h(xd4.w) - u2h(xs4.w)) * c32));
      fa.x = h2u(u2h(lerp2(wbA.x, wbB.x, tf)) * ((u2h(xd4.x) + u2h(xs4.x)) * c64));
      fa.y = h2u(u2h(lerp2(wbA.y, wbB.y, tf)) * ((u2h(xd4.y) + u2h(xs4.y)) * c64));
      fa.z = h2u(u2h(lerp2(wbA.z, wbB.z, tf)) * ((u2h(xd4.z) + u2h(xs4.z)) * c64));
      fa.w = h2u(u2h(lerp2(wbA.w, wbB.w, tf)) * ((u2h(xd4.w) + u2h(xs4.w)) * c64));
      acc[mt][0] = __builtin_amdgcn_mfma_f32_16x16x32_f16(u4h8(fg), u4h8(bg0), acc[mt][0], 0, 0, 0);
      acc[mt][1] = __builtin_amdgcn_mfma_f32_16x16x32_f16(u4h8(fg), u4h8(bg1), acc[mt][1], 0, 0, 0);
      acc[mt][0] = __builtin_amdgcn_mfma_f32_16x16x32_f16(u4h8(fa), u4h8(ba0), acc[mt][0], 0, 0, 0);
      acc[mt][1] = __builtin_amdgcn_mfma_f32_16x16x32_f16(u4h8(fa), u4h8(ba1), acc[mt][1], 0, 0, 0);
    }
  }

  // ---- gelu + transpose hdg (D layout -> row-major LDS -> A-frags) ----
#pragma unroll
  for (int mt = 0; mt < 4; mt++)
#pragma unroll
    for (int nt = 0; nt < 2; nt++)
#pragma unroll
      for (int i = 0; i < 4; i++){
        float v = geluf(32.f * acc[mt][nt][i]) * 0.015625f;
        float o = __shfl_xor(v, 1);
        if (!(lane & 1))
          wb[(16*mt + 4*g + i)*17 + 8*nt + (r15 >> 1)] = pack2(v, o);
      }
  wsync();
  uint4 af[4];
#pragma unroll
  for (int mt = 0; mt < 4; mt++){
    int row = 16*mt + r15;
    af[mt].x = wb[row*17 + 4*g + 0];
    af[mt].y = wb[row*17 + 4*g + 1];
    af[mt].z = wb[row*17 + 4*g + 2];
    af[mt].w = wb[row*17 + 4*g + 3];
  }
  wsync();

  // ---- pass 2: per 16-col block np (cols 16np.. and 96+16np..) ----
  unsigned int* prow = (unsigned int*)(pbuf + (long)p * 96);
  unsigned int* qrow = (unsigned int*)(qbuf + (long)qq * 96);
  for (int np = 0; np < 6; np++){
    uint4 b1 = *(const uint4*)(bf2 + ((np    )*64 + lane)*4);
    uint4 b2 = *(const uint4*)(bf2 + ((np + 6)*64 + lane)*4);
    f32x4 d1a[4], d2a[4];
#pragma unroll
    for (int mt = 0; mt < 4; mt++){
      d1a[mt] = __builtin_amdgcn_mfma_f32_16x16x32_f16(u4h8(af[mt]), u4h8(b1), zf, 0, 0, 0);
      d2a[mt] = __builtin_amdgcn_mfma_f32_16x16x32_f16(u4h8(af[mt]), u4h8(b2), zf, 0, 0, 0);
    }
#pragma unroll
    for (int mt = 0; mt < 4; mt++)
#pragma unroll
      for (int i = 0; i < 4; i++){
        float v1 = d1a[mt][i], v2 = d2a[mt][i];
        float o1 = __shfl_xor(v1, 1);
        float o2 = __shfl_xor(v2, 1);
        if (!(lane & 1)){
          int r = 16*mt + 4*g + i;
          wb[r*17 + (r15 >> 1)]     = pack2(v1, o1);
          wb[r*17 + 8 + (r15 >> 1)] = pack2(v2, o2);
        }
      }
    wsync();
    unsigned int d1u[8], d2u[8];
#pragma unroll
    for (int u = 0; u < 8; u++){
      d1u[u] = wb[lane*17 + u];
      d2u[u] = wb[lane*17 + 8 + u];
    }
    wsync();
    // Wc lerp for own edge: c1 = Wc[16np+..], c2 = Wc[96+16np+..]
    uint4 ca0 = *(const uint4*)(rAo + 96  + 8*np);
    uint4 ca1 = *(const uint4*)(rAo + 100 + 8*np);
    uint4 cb0 = *(const uint4*)(rBo + 96  + 8*np);
    uint4 cb1 = *(const uint4*)(rBo + 100 + 8*np);
    uint4 ka0 = *(const uint4*)(rAo + 144 + 8*np);
    uint4 ka1 = *(const uint4*)(rAo + 148 + 8*np);
    uint4 kb0 = *(const uint4*)(rBo + 144 + 8*np);
    uint4 kb1 = *(const uint4*)(rBo + 148 + 8*np);
    unsigned int c1u[8] = {lerp2(ca0.x,cb0.x,tfo), lerp2(ca0.y,cb0.y,tfo),
                           lerp2(ca0.z,cb0.z,tfo), lerp2(ca0.w,cb0.w,tfo),
                           lerp2(ca1.x,cb1.x,tfo), lerp2(ca1.y,cb1.y,tfo),
                           lerp2(ca1.z,cb1.z,tfo), lerp2(ca1.w,cb1.w,tfo)};
    unsigned int c2u[8] = {lerp2(ka0.x,kb0.x,tfo), lerp2(ka0.y,kb0.y,tfo),
                           lerp2(ka0.z,kb0.z,tfo), lerp2(ka0.w,kb0.w,tfo),
                           lerp2(ka1.x,kb1.x,tfo), lerp2(ka1.y,kb1.y,tfo),
                           lerp2(ka1.z,kb1.z,tfo), lerp2(ka1.w,kb1.w,tfo)};
    unsigned int pv[8], qv[8];
#pragma unroll
    for (int u = 0; u < 8; u++){
      h2f t1 = u2h(c1u[u]) * u2h(d1u[u]);            // dv (true/64)
      h2f t2 = (u2h(c2u[u]) * u2h(d2u[u])) * h05;    // av (true/64)
      pv[u] = h2u(t1 + t2);
      qv[u] = h2u(t2 - t1);
    }
    *(uint4*)(prow + 8*np)     = *(uint4*)(pv);
    *(uint4*)(prow + 8*np + 4) = *(uint4*)(pv + 4);
    *(uint4*)(qrow + 8*np)     = *(uint4*)(qv);
    *(uint4*)(qrow + 8*np + 4) = *(uint4*)(qv + 4);
  }
}

// fused gather + node update + xnh repack; uint2-vectorized, 10 nodes/block
__global__ __launch_bounds__(256) void gather_upd(
    const int* __restrict__ doff, const int* __restrict__ soff,
    const unsigned short* __restrict__ pbuf, const unsigned short* __restrict__ qbuf,
    float* __restrict__ xn, unsigned int* __restrict__ xnh)
{
  int g = threadIdx.x / 24;
  int c4 = threadIdx.x - 24 * g;     // 4-half group within 96-half row
  if (g >= 10) return;
  int n = blockIdx.x * 10 + g;
  if (n >= NN) return;
  const uint2* p2 = (const uint2*)pbuf;   // row = 24 uint2
  const uint2* q2 = (const uint2*)qbuf;
  float a0 = 0.f, a1 = 0.f, a2 = 0.f, a3 = 0.f;
  int d1 = doff[n+1];
  for (int p = doff[n]; p < d1; p++){
    uint2 v = p2[(long)p * 24 + c4];
    h2f lo = u2h(v.x), hi = u2h(v.y);
    a0 += (float)lo.x; a1 += (float)lo.y; a2 += (float)hi.x; a3 += (float)hi.y;
  }
  int s1 = soff[n+1];
  for (int q = soff[n]; q < s1; q++){
    uint2 v = q2[(long)q * 24 + c4];
    h2f lo = u2h(v.x), hi = u2h(v.y);
    a0 += (float)lo.x; a1 += (float)lo.y; a2 += (float)hi.x; a3 += (float)hi.y;
  }
  float4 xo = *(float4*)(xn + (long)n * 96 + 4*c4);
  xo.x -= 6.4f * a0; xo.y -= 6.4f * a1; xo.z -= 6.4f * a2; xo.w -= 6.4f * a3;
  *(float4*)(xn + (long)n * 96 + 4*c4) = xo;
  uint2 w; w.x = pack2(xo.x, xo.y); w.y = pack2(xo.z, xo.w);
  *(uint2*)(xnh + n * 48 + 2*c4) = w;
}

// ---------------- column sum over nodes -------------------------------------
__global__ void colsum(const float* __restrict__ xn, float* __restrict__ nodesum){
  int col = threadIdx.x % 96;
  int seg = threadIdx.x / 96;
  int stripe = blockIdx.x * 2 + seg;   // 0..399
  float acc = 0.f;
  for (int n = stripe; n < NN; n += 400) acc += xn[(long)n * 96 + col];
  unsafeAtomicAdd(nodesum + col, acc);
}

// ---------------- project to 16 outputs, scale, fp32 store ------------------
__global__ void project(const float* __restrict__ nodesum, const float* __restrict__ siT,
                        float* __restrict__ out){
  int j = threadIdx.x;
  if (j < 16){
    float a = 0.f;
#pragma unroll
    for (int c = 0; c < 96; c++) a += nodesum[c] * siT[j*96 + c];
    out[j] = a * 0.007071067811865475f;   // 1/sqrt(20000)
  }
}

// ---------------- host side -------------------------------------------------
extern "C" void kernel_launch(void* const* d_in, const int* in_sizes, int n_in,
                              void* d_out, int out_size, void* d_ws, size_t ws_size,
                              hipStream_t stream){
  const float* pos  = (const float*)d_in[0];
  const int* atom_z = (const int*)d_in[1];
  const int* esrc   = (const int*)d_in[2];
  const int* edst   = (const int*)d_in[3];

  float* ws      = (float*)d_ws;
  float* xn      = ws;                  // 1,920,000
  float* nodesum = ws + 1920000;        // 96
  float* WB      = ws + 1920096;        // 4,128 fp32 weights
  unsigned int* bf1   = (unsigned int*)(ws + 1924224);  // 6,144
  unsigned int* bf2   = (unsigned int*)(ws + 1930368);  // 6,144
  unsigned int* lutL  = (unsigned int*)(ws + 1936512);  // 786,432 (3 MB)
  unsigned int* lut01 = (unsigned int*)(ws + 2722944);  // 65,536
  unsigned int* xnh   = (unsigned int*)(ws + 2788480);  // 960,000 (f16 rows)
  float* els    = ws + 3748480;                 // 320,000 edge lengths
  int*   cntd   = (int*)(ws + 4068480);         // 20,000
  int*   cnts   = cntd + 20000;                 // 20,000 (contiguous for 1 memset)
  int*   curd   = cnts + 20000;                 // 20,000
  int*   curs   = curd + 20000;                 // 20,000
  int*   doff   = curs + 20000;                 // 20,004
  int*   soff   = doff + 20004;                 // 20,004  -> ends 4,188,488
  int*   srcS   = soff + 20004;                 // 320,000 -> ends 4,508,488
  int*   dstS   = srcS + 320000;                // 320,000 -> ends 4,828,488
  int*   qpos   = dstS + 320000;                // 320,000 -> ends 5,148,488
  // buffers at verified round-10..13 offsets (>= 5,468,496 > int arrays):
  //   pbufL: [ 5,468,496 .. 20,828,496)   qbufL: [20,828,496 .. 36,188,496)
  //   pbuf0: [ 5,468,496 .. 15,708,496)   qbuf0: [15,708,496 .. 25,948,496)
  // (init aliases layer space CROSS-PHASE only; init-phase disjoint.)
  // end = 36,188,496 floats = 144.8 MB
  unsigned short* pbufL = (unsigned short*)(ws + 5468496);
  unsigned short* qbufL = (unsigned short*)(ws + 20828496);
  unsigned short* pbuf0 = (unsigned short*)(ws + 5468496);
  unsigned short* qbuf0 = (unsigned short*)(ws + 15708496);

  float* embedF = WB + 0;        // 160
  float* dl0w1T = WB + 160;      // 256   [32][8]
  float* dl0w2T = WB + 416;      // 1024  [32][32]
  float* dl1w1T = WB + 1440;     // 128   [32][4]
  float* dl1w2T = WB + 1568;     // 1024  [32][32]
  float* siT    = WB + 2592;     // 1536  [16][96]

  hipMemsetAsync(cntd, 0, 40000 * 4, stream);
  hipMemsetAsync(nodesum, 0, 96 * 4, stream);

  TTab tb;
  int ti = 0;
  auto add = [&](const void* s, float* dst, int R, int C, int tr){
    tb.e[ti].src = (const float*)s; tb.e[ti].dst = dst;
    tb.e[ti].R = R; tb.e[ti].C = C; tb.e[ti].trans = tr; ti++;
  };
  add(d_in[4],  embedF, 20, 8, 0);
  add(d_in[5],  dl0w1T, 8, 32, 1);
  add(d_in[6],  dl0w2T, 32, 32, 1);
  add(d_in[7],  dl1w1T, 4, 32, 1);
  add(d_in[8],  dl1w2T, 32, 32, 1);
  add(d_in[17], siT, 96, 16, 1);

  // weight prep (convw + MFMA B-fragment pack + both LUTs) in one launch
  prep_k<<<7 + 2*NT + (NT + 5)/6, 384, 0, stream>>>(
      tb, (const float*)d_in[11], (const float*)d_in[12],
      (const float*)d_in[13], (const float*)d_in[14], (unsigned short*)lutL,
      (const float*)d_in[9], (const float*)d_in[10], (unsigned short*)lut01,
      (const float*)d_in[15], (const float*)d_in[16], bf1, bf2);
  countnode_k<<<NE/256 + (NN + 255)/256, 256, 0, stream>>>(
      esrc, edst, cntd, cnts, atom_z, embedF, dl0w1T, dl0w2T, xn);
  prefix_k<<<2, 1024, 0, stream>>>(cntd, doff, curd, cnts, soff, curs);
  fill_comb<<<(NE + 255)/256, 256, 0, stream>>>(esrc, edst, curd, curs,
                                                srcS, dstS, qpos);
  edge_init<<<(NE + 255)/256, 256, 0, stream>>>(
      pos, srcS, dstS, qpos, els, pbuf0, qbuf0, dl1w1T, dl1w2T, lut01);
  gather_init<<<(NN + 15)/16, 256, 0, stream>>>(doff, soff, pbuf0, qbuf0, xn, xnh);

  for (int i = 0; i < 2; i++){
    layer_k<<<NE/64, 64, 0, stream>>>(
        srcS, dstS, qpos, els, xnh, pbufL, qbufL,
        lutL + (long)i * NT * 192, bf1 + i*3072, bf2 + i*3072);
    gather_upd<<<(NN + 9)/10, 256, 0, stream>>>(doff, soff, pbufL, qbufL,
                                                xn, xnh);
  }
  colsum<<<200, 192, 0, stream>>>(xn, nodesum);
  project<<<1, 64, 0, stream>>>(nodesum, siT, (float*)d_out);
}